// Round 8
// baseline (708.562 us; speedup 1.0000x reference)
//
#include <hip/hip_runtime.h>
#include <math.h>

// ---------------------------------------------------------------------------
// FastImageMamba forward. R21: R20 (verified 577us) + dwconv fused into the
// xproj GEMM's A-staging (xproj reads each xlb element exactly once, so the
// conv is computed on the fly from xib, used as the MFMA A operand, and
// side-stored to xlb for the scans). dwconv dispatch deleted (4 fewer
// dispatches + one 20MB round-trip per layer gone).
// B=4, DM=256, NL=4, NC=1000, DI=512, NS=16, DTR=32, K=4, L=1024, H=W=64
// ---------------------------------------------------------------------------

#define BN_RSQ 0.99999500003749969f   // 1/sqrt(1+1e-5)

typedef unsigned int uint;
typedef unsigned short ushort;
typedef __bf16 bf16x8 __attribute__((ext_vector_type(8)));
typedef float floatx4 __attribute__((ext_vector_type(4)));

__device__ __forceinline__ float gelu_f(float v) {
    return 0.5f * v * (1.0f + erff(v * 0.70710678118654752f));
}
__device__ __forceinline__ float softplus_f(float v) {
    return (v > 20.f) ? v : log1pf(expf(v));
}
__device__ __forceinline__ ushort f2bf(float f) {
    uint x = __float_as_uint(f);
    x += 0x7fffu + ((x >> 16) & 1u);
    return (ushort)(x >> 16);
}
__device__ __forceinline__ float bf2f(ushort u) {
    return __uint_as_float((uint)u << 16);
}

// DPP row_shr:N add step: after N=1,2,4,8 lane 15 of each 16-lane row holds
// the row sum (bound_ctrl=1 -> out-of-row sources read 0).
#define DPP_ROW_SHR_ADD(x, N)                                               \
    x += __int_as_float(__builtin_amdgcn_update_dpp(                        \
        0, __float_as_int(x), 0x110 + (N), 0xf, 0xf, true))

// ---------------------------------------------------------------------------
// Fused weight prep: all fp32->bf16 weight conversions in one dispatch.
// ---------------------------------------------------------------------------
__global__ void wprep(const float* __restrict__ ipw, const float* __restrict__ opw,
                      const float* __restrict__ c2w, const float* __restrict__ pw,
                      const float* __restrict__ xpw,
                      ushort* __restrict__ ipwb, ushort* __restrict__ opwb,
                      ushort* __restrict__ w2b, ushort* __restrict__ pwTb,
                      ushort* __restrict__ xpwb)
{
    int idx = blockIdx.x * 256 + threadIdx.x;
    if (idx < 1048576) {
        ipwb[idx] = f2bf(ipw[idx]);
    } else if (idx < 1572864) {
        int i = idx - 1048576;
        opwb[i] = f2bf(opw[i]);
    } else if (idx < 1867776) {
        int i = idx - 1572864;
        int oc = i / 1152, k = i % 1152;
        int s = k >> 7, ic = k & 127;
        w2b[i] = f2bf(c2w[(size_t)(oc * 128 + ic) * 9 + s]);
    } else if (idx < 2129920) {
        int i = idx - 1867776;
        int oc = i >> 10, k = i & 1023;
        int s = k >> 8, ic = k & 255;
        int ky = s >> 1, kx = s & 1;
        pwTb[i] = f2bf(pw[((size_t)(oc * 256 + ic) * 2 + ky) * 2 + kx]);
    } else if (idx < 2260992) {
        int i = idx - 2129920;
        xpwb[i] = f2bf(xpw[i]);
    }
}

// ---------------------------------------------------------------------------
// conv1: 3x3 s1p1, IC=3 -> OC=128, NCHW fp32 in, NHWC bf16 out (+bias+BN+GELU)
// ---------------------------------------------------------------------------
__global__ __launch_bounds__(256) void conv1_nhwc(
    const float* __restrict__ x, const float* __restrict__ w,
    const float* __restrict__ cb, const float* __restrict__ g,
    const float* __restrict__ bb, ushort* __restrict__ out)
{
    __shared__ float tin[3][3][64];
    __shared__ float ws[3456];
    int t = threadIdx.x;
    int b = blockIdx.x >> 6, y = blockIdx.x & 63;
    for (int i = t; i < 3456; i += 256) ws[i] = w[i];
    for (int i = t; i < 576; i += 256) {
        int ic = i / 192, r = (i >> 6) % 3, xx = i & 63;
        int gy = y + r - 1;
        tin[ic][r][xx] = ((unsigned)gy < 64u) ? x[((b * 3 + ic) * 64 + gy) * 64 + xx] : 0.f;
    }
    __syncthreads();
    int tx = t & 15, ty = t >> 4;
    int oc0 = tx * 8, px0 = ty * 4;
    float acc[4][8];
    #pragma unroll
    for (int p = 0; p < 4; ++p)
        #pragma unroll
        for (int o = 0; o < 8; ++o) acc[p][o] = 0.f;
    for (int ic = 0; ic < 3; ++ic)
        #pragma unroll
        for (int ky = 0; ky < 3; ++ky)
            #pragma unroll
            for (int kx = 0; kx < 3; ++kx) {
                float av[4];
                #pragma unroll
                for (int p = 0; p < 4; ++p) {
                    int xx = px0 + p + kx - 1;
                    av[p] = ((unsigned)xx < 64u) ? tin[ic][ky][xx] : 0.f;
                }
                #pragma unroll
                for (int o = 0; o < 8; ++o) {
                    float wv = ws[(oc0 + o) * 27 + ic * 9 + ky * 3 + kx];
                    #pragma unroll
                    for (int p = 0; p < 4; ++p) acc[p][o] = fmaf(av[p], wv, acc[p][o]);
                }
            }
    #pragma unroll
    for (int p = 0; p < 4; ++p) {
        uint pk[4];
        #pragma unroll
        for (int o2 = 0; o2 < 4; ++o2) {
            int oc = oc0 + o2 * 2;
            float v0 = gelu_f((acc[p][o2 * 2] + cb[oc]) * (g[oc] * BN_RSQ) + bb[oc]);
            float v1 = gelu_f((acc[p][o2 * 2 + 1] + cb[oc + 1]) * (g[oc + 1] * BN_RSQ) + bb[oc + 1]);
            pk[o2] = (uint)f2bf(v0) | ((uint)f2bf(v1) << 16);
        }
        uint4 vv = make_uint4(pk[0], pk[1], pk[2], pk[3]);
        *(uint4*)(out + ((size_t)((b * 64 + y) * 64 + px0 + p)) * 128 + oc0) = vv;
    }
}

// ---------------------------------------------------------------------------
// bf16 MFMA GEMM (A @ W^T), BMxBN tile, BK=32, 4 waves (2x2), reg dbuf.
// EPI: 0 = +bias -> fp32 Cf[ldc]
//      2 = +bias,BN,GELU -> fp32 Cf + bf16 Cb (same ldc)
//      3 = in_proj: n<512 -> bf16 Cb[m*512+n]; n>=512 -> bf16 silu -> Cb2
// ---------------------------------------------------------------------------
template<int BM, int BN, int EPI>
__global__ __launch_bounds__(256, 2) void mfma_gemm_bt(
    const ushort* __restrict__ A, int lda,
    const ushort* __restrict__ W, int ldw,
    const float* __restrict__ bias,
    const float* __restrict__ bnG, const float* __restrict__ bnB,
    float* __restrict__ Cf, ushort* __restrict__ Cb, ushort* __restrict__ Cb2,
    int ldc, int K)
{
    constexpr int PAD = 40;
    constexpr int AP = BM / 64;
    constexpr int BP = BN / 64;
    constexpr int FM = BM / 32;
    constexpr int FN = BN / 32;
    __shared__ __align__(16) ushort As[BM * PAD];
    __shared__ __align__(16) ushort Bs[BN * PAD];
    int t = threadIdx.x;
    int m0 = blockIdx.x * BM, n0 = blockIdx.y * BN;
    int lane = t & 63, wid = t >> 6;
    int wm = (wid & 1) * (BM / 2), wn = (wid >> 1) * (BN / 2);
    int fr = lane & 15, fk = (lane >> 4) * 8;
    int r0 = t >> 2, c0 = (t & 3) * 8;
    floatx4 acc[FM][FN];
    #pragma unroll
    for (int i = 0; i < FM; ++i)
        #pragma unroll
        for (int j = 0; j < FN; ++j) acc[i][j] = {0.f, 0.f, 0.f, 0.f};
    uint4 ra[AP], rb[BP];
    #pragma unroll
    for (int p = 0; p < AP; ++p)
        ra[p] = *(const uint4*)(A + (size_t)(m0 + r0 + p * 64) * lda + c0);
    #pragma unroll
    for (int p = 0; p < BP; ++p)
        rb[p] = *(const uint4*)(W + (size_t)(n0 + r0 + p * 64) * ldw + c0);
    for (int k0 = 0; k0 < K; k0 += 32) {
        __syncthreads();
        #pragma unroll
        for (int p = 0; p < AP; ++p) *(uint4*)&As[(r0 + p * 64) * PAD + c0] = ra[p];
        #pragma unroll
        for (int p = 0; p < BP; ++p) *(uint4*)&Bs[(r0 + p * 64) * PAD + c0] = rb[p];
        __syncthreads();
        if (k0 + 32 < K) {
            #pragma unroll
            for (int p = 0; p < AP; ++p)
                ra[p] = *(const uint4*)(A + (size_t)(m0 + r0 + p * 64) * lda + k0 + 32 + c0);
            #pragma unroll
            for (int p = 0; p < BP; ++p)
                rb[p] = *(const uint4*)(W + (size_t)(n0 + r0 + p * 64) * ldw + k0 + 32 + c0);
        }
        bf16x8 af[FM], bw[FN];
        #pragma unroll
        for (int i = 0; i < FM; ++i)
            af[i] = *(const bf16x8*)&As[(wm + i * 16 + fr) * PAD + fk];
        #pragma unroll
        for (int j = 0; j < FN; ++j)
            bw[j] = *(const bf16x8*)&Bs[(wn + j * 16 + fr) * PAD + fk];
        #pragma unroll
        for (int i = 0; i < FM; ++i)
            #pragma unroll
            for (int j = 0; j < FN; ++j)
                acc[i][j] = __builtin_amdgcn_mfma_f32_16x16x32_bf16(af[i], bw[j], acc[i][j], 0, 0, 0);
    }
    int rbase = (lane >> 4) * 4, cc = lane & 15;
    #pragma unroll
    for (int j = 0; j < FN; ++j) {
        int n = n0 + wn + j * 16 + cc;
        float bv = bias ? bias[n] : 0.f;
        float scl = 0.f, shf = 0.f;
        if (EPI == 2) { scl = bnG[n] * BN_RSQ; shf = bnB[n]; }
        #pragma unroll
        for (int i = 0; i < FM; ++i) {
            #pragma unroll
            for (int r = 0; r < 4; ++r) {
                int m = m0 + wm + i * 16 + rbase + r;
                float v = acc[i][j][r] + bv;
                if (EPI == 2) v = gelu_f(v * scl + shf);
                if (EPI == 0) {
                    Cf[(size_t)m * ldc + n] = v;
                } else if (EPI == 2) {
                    Cf[(size_t)m * ldc + n] = v;
                    Cb[(size_t)m * ldc + n] = f2bf(v);
                } else {
                    if (n < 512) Cb[(size_t)m * 512 + n] = f2bf(v);
                    else Cb2[(size_t)m * 512 + (n - 512)] = f2bf(v / (1.f + __expf(-v)));
                }
            }
        }
    }
}

// ---------------------------------------------------------------------------
// xproj GEMM with FUSED depthwise conv1d (K=4, pad(1,2)) in A-staging.
// A[m][c] = f2bf( cb[c] + sum_k cw[c*4+k]*bf2f(xib[m+k-1][c]) ) -- the exact
// dwconv output, side-stored to xlb (each element staged exactly once).
// BM=BN=64, BK=32, grid (64,1), 4 waves. Output xdbl fp32 [4096][64].
// ---------------------------------------------------------------------------
__global__ __launch_bounds__(256, 2) void xproj_conv_gemm(
    const ushort* __restrict__ xib, const float* __restrict__ cw,
    const float* __restrict__ cbp, const ushort* __restrict__ W,
    ushort* __restrict__ xlb, float* __restrict__ Cf)
{
    constexpr int PAD = 40;
    __shared__ __align__(16) ushort As[64 * PAD];
    __shared__ __align__(16) ushort Bs[64 * PAD];
    int t = threadIdx.x;
    int m0 = blockIdx.x * 64;
    int lane = t & 63, wid = t >> 6;
    int wm = (wid & 1) * 32, wn = (wid >> 1) * 32;
    int fr = lane & 15, fk = (lane >> 4) * 8;
    int r0 = t >> 2, c0 = (t & 3) * 8;
    int m = m0 + r0;
    int l = m & 1023;
    floatx4 acc[2][2];
    #pragma unroll
    for (int i = 0; i < 2; ++i)
        #pragma unroll
        for (int j = 0; j < 2; ++j) acc[i][j] = {0.f, 0.f, 0.f, 0.f};

    uint4 ra, rb;
    // conv-compute the 8-channel A slice at k-offset cb0, side-store to xlb.
    auto conv8 = [&](int cb0) -> uint4 {
        uint4 xr0, xr1, xr2, xr3;
        uint4 zz = make_uint4(0u, 0u, 0u, 0u);
        xr0 = ((unsigned)(l - 1) < 1024u) ? *(const uint4*)(xib + (size_t)(m - 1) * 512 + cb0) : zz;
        xr1 = *(const uint4*)(xib + (size_t)m * 512 + cb0);                 // tap1 always valid
        xr2 = ((unsigned)(l + 1) < 1024u) ? *(const uint4*)(xib + (size_t)(m + 1) * 512 + cb0) : zz;
        xr3 = ((unsigned)(l + 2) < 1024u) ? *(const uint4*)(xib + (size_t)(m + 2) * 512 + cb0) : zz;
        float4 cbv0 = *(const float4*)(cbp + cb0);
        float4 cbv1 = *(const float4*)(cbp + cb0 + 4);
        ushort o8[8];
        const uint* p0 = (const uint*)&xr0;
        const uint* p1 = (const uint*)&xr1;
        const uint* p2 = (const uint*)&xr2;
        const uint* p3 = (const uint*)&xr3;
        #pragma unroll
        for (int j = 0; j < 8; ++j) {
            float4 wv = *(const float4*)(cw + (cb0 + j) * 4);
            float a = (j < 4) ? ((const float*)&cbv0)[j] : ((const float*)&cbv1)[j - 4];
            uint w0 = p0[j >> 1], w1 = p1[j >> 1], w2 = p2[j >> 1], w3 = p3[j >> 1];
            ushort h0 = (j & 1) ? (ushort)(w0 >> 16) : (ushort)(w0 & 0xffffu);
            ushort h1 = (j & 1) ? (ushort)(w1 >> 16) : (ushort)(w1 & 0xffffu);
            ushort h2 = (j & 1) ? (ushort)(w2 >> 16) : (ushort)(w2 & 0xffffu);
            ushort h3 = (j & 1) ? (ushort)(w3 >> 16) : (ushort)(w3 & 0xffffu);
            a = fmaf(bf2f(h0), wv.x, a);
            a = fmaf(bf2f(h1), wv.y, a);
            a = fmaf(bf2f(h2), wv.z, a);
            a = fmaf(bf2f(h3), wv.w, a);
            o8[j] = f2bf(a);
        }
        uint4 r;
        r.x = (uint)o8[0] | ((uint)o8[1] << 16);
        r.y = (uint)o8[2] | ((uint)o8[3] << 16);
        r.z = (uint)o8[4] | ((uint)o8[5] << 16);
        r.w = (uint)o8[6] | ((uint)o8[7] << 16);
        *(uint4*)(xlb + (size_t)m * 512 + cb0) = r;   // side-store (once/elem)
        return r;
    };

    ra = conv8(c0);
    rb = *(const uint4*)(W + (size_t)r0 * 512 + c0);
    for (int k0 = 0; k0 < 512; k0 += 32) {
        __syncthreads();
        *(uint4*)&As[r0 * PAD + c0] = ra;
        *(uint4*)&Bs[r0 * PAD + c0] = rb;
        __syncthreads();
        if (k0 + 32 < 512) {
            ra = conv8(k0 + 32 + c0);
            rb = *(const uint4*)(W + (size_t)r0 * 512 + k0 + 32 + c0);
        }
        bf16x8 af[2], bw[2];
        #pragma unroll
        for (int i = 0; i < 2; ++i)
            af[i] = *(const bf16x8*)&As[(wm + i * 16 + fr) * PAD + fk];
        #pragma unroll
        for (int j = 0; j < 2; ++j)
            bw[j] = *(const bf16x8*)&Bs[(wn + j * 16 + fr) * PAD + fk];
        #pragma unroll
        for (int i = 0; i < 2; ++i)
            #pragma unroll
            for (int j = 0; j < 2; ++j)
                acc[i][j] = __builtin_amdgcn_mfma_f32_16x16x32_bf16(af[i], bw[j], acc[i][j], 0, 0, 0);
    }
    int rbase = (lane >> 4) * 4, cc = lane & 15;
    #pragma unroll
    for (int j = 0; j < 2; ++j) {
        int n = wn + j * 16 + cc;
        #pragma unroll
        for (int i = 0; i < 2; ++i) {
            #pragma unroll
            for (int r = 0; r < 4; ++r) {
                int mm = m0 + wm + i * 16 + rbase + r;
                Cf[(size_t)mm * 64 + n] = acc[i][j][r];
            }
        }
    }
}

// ---------------------------------------------------------------------------
// conv2: 9-shift implicit MFMA GEMM, 128px x 64oc tile, BK=64 (18 steps),
// reg dbuf with EXPLICIT SCALAR uint4s (array-by-ref spills to scratch).
// Writes DIRECTLY in im2col/Apb layout (im2col kernel deleted).
// ---------------------------------------------------------------------------
#define C2_LOAD(step)                                                            \
    {                                                                            \
        int s_ = (step) >> 1, ich_ = ((step) & 1) * 64;                          \
        int ky_ = s_ / 3, kx_ = s_ % 3;                                          \
        int sy_ = y0 + (ra_row >> 6) + ky_ - 1;                                  \
        int sx_ = (ra_row & 63) + kx_ - 1;                                       \
        bool v_ = ((unsigned)sy_ < 64u) && ((unsigned)sx_ < 64u);                \
        const ushort* ap_ = hb + ((size_t)(sy_ * 64 + sx_)) * 128 + ich_ + ra_c; \
        uint4 zz_ = make_uint4(0u, 0u, 0u, 0u);                                  \
        ra0 = v_ ? *(const uint4*)(ap_ + 0)  : zz_;                              \
        ra1 = v_ ? *(const uint4*)(ap_ + 8)  : zz_;                              \
        ra2 = v_ ? *(const uint4*)(ap_ + 16) : zz_;                              \
        ra3 = v_ ? *(const uint4*)(ap_ + 24) : zz_;                              \
        const ushort* wp_ = w2b + (size_t)(n0 + rb_row) * 1152 + s_ * 128 + ich_ + rb_c; \
        rb0 = *(const uint4*)(wp_ + 0);                                          \
        rb1 = *(const uint4*)(wp_ + 8);                                          \
    }

__global__ __launch_bounds__(256, 2) void conv2_mfma(
    const ushort* __restrict__ h1b, const ushort* __restrict__ w2b,
    const float* __restrict__ cb, const float* __restrict__ g,
    const float* __restrict__ bb, ushort* __restrict__ Apb)
{
    constexpr int PAD = 72;
    __shared__ __align__(16) ushort As[128 * PAD];
    __shared__ __align__(16) ushort Bs[64 * PAD];
    int t = threadIdx.x;
    int m0 = blockIdx.x * 128, n0 = blockIdx.y * 64;
    int b = m0 >> 12;
    int y0 = (m0 & 4095) >> 6;
    int lane = t & 63, wid = t >> 6;
    int wm = (wid & 1) * 64, wn = (wid >> 1) * 32;
    int fr = lane & 15, fk = (lane >> 4) * 8;
    int ra_row = t >> 1, ra_c = (t & 1) * 32;
    int rb_row = t >> 2, rb_c = (t & 3) * 16;
    floatx4 acc[4][2];
    #pragma unroll
    for (int i = 0; i < 4; ++i)
        #pragma unroll
        for (int j = 0; j < 2; ++j) acc[i][j] = {0.f, 0.f, 0.f, 0.f};
    const ushort* hb = h1b + (size_t)b * 4096 * 128;

    uint4 ra0, ra1, ra2, ra3, rb0, rb1;
    C2_LOAD(0);
    for (int step = 0; step < 18; ++step) {
        __syncthreads();
        *(uint4*)&As[ra_row * PAD + ra_c + 0]  = ra0;
        *(uint4*)&As[ra_row * PAD + ra_c + 8]  = ra1;
        *(uint4*)&As[ra_row * PAD + ra_c + 16] = ra2;
        *(uint4*)&As[ra_row * PAD + ra_c + 24] = ra3;
        *(uint4*)&Bs[rb_row * PAD + rb_c + 0]  = rb0;
        *(uint4*)&Bs[rb_row * PAD + rb_c + 8]  = rb1;
        __syncthreads();
        if (step + 1 < 18) C2_LOAD(step + 1);
        #pragma unroll
        for (int ks = 0; ks < 64; ks += 32) {
            bf16x8 af[4], bw[2];
            #pragma unroll
            for (int i = 0; i < 4; ++i)
                af[i] = *(const bf16x8*)&As[(wm + i * 16 + fr) * PAD + ks + fk];
            #pragma unroll
            for (int j = 0; j < 2; ++j)
                bw[j] = *(const bf16x8*)&Bs[(wn + j * 16 + fr) * PAD + ks + fk];
            #pragma unroll
            for (int i = 0; i < 4; ++i)
                #pragma unroll
                for (int j = 0; j < 2; ++j)
                    acc[i][j] = __builtin_amdgcn_mfma_f32_16x16x32_bf16(af[i], bw[j], acc[i][j], 0, 0, 0);
        }
    }
    int rbase = (lane >> 4) * 4, cc = lane & 15;
    #pragma unroll
    for (int j = 0; j < 2; ++j) {
        int n = n0 + wn + j * 16 + cc;
        float scl = g[n] * BN_RSQ, shf = bb[n], bv2 = cb[n];
        #pragma unroll
        for (int i = 0; i < 4; ++i) {
            #pragma unroll
            for (int r = 0; r < 4; ++r) {
                int m = m0 + wm + i * 16 + rbase + r;   // b*4096 + y*64 + x
                float v = gelu_f((acc[i][j][r] + bv2) * scl + shf);
                int yy = (m >> 6) & 63, xx = m & 63;
                int arow = (m >> 12) * 1024 + (yy >> 1) * 32 + (xx >> 1);
                int acol = ((yy & 1) * 2 + (xx & 1)) * 256 + n;
                Apb[(size_t)arow * 1024 + acol] = f2bf(v);
            }
        }
    }
}

// ---------------------------------------------------------------------------
// fp32 tiled GEMM (reg dbuf): head FC only.
// ---------------------------------------------------------------------------
template<int BM, int BN, int BK, int TM, int TN>
__global__ __launch_bounds__(256) void gemm_kernel(
    const float* __restrict__ A, int lda,
    const float* __restrict__ W, int ldw,
    const float* __restrict__ bias,
    float* __restrict__ C, int ldc,
    int M, int N, int K, int act)
{
    static_assert(BM * BK / 4 == 256 && BN * BK / 4 == 256, "staging shape");
    __shared__ float As[BK][BM + 4];
    __shared__ float Bs[BK][BN + 4];
    int t = threadIdx.x;
    int m0 = blockIdx.x * BM, n0 = blockIdx.y * BN;
    float acc[TM][TN];
    #pragma unroll
    for (int i = 0; i < TM; i++)
        #pragma unroll
        for (int j = 0; j < TN; j++) acc[i][j] = 0.f;
    const int LPR = BK / 4;
    int lr = t / LPR, lc4 = (t % LPR) * 4;
    int ty = t >> 4, tx = t & 15;
    int ma = m0 + lr, nb = n0 + lr;
    float4 va = make_float4(0.f, 0.f, 0.f, 0.f);
    float4 vb = make_float4(0.f, 0.f, 0.f, 0.f);
    if (ma < M) va = *(const float4*)(A + (size_t)ma * lda + lc4);
    if (nb < N) vb = *(const float4*)(W + (size_t)nb * ldw + lc4);
    for (int k0 = 0; k0 < K; k0 += BK) {
        __syncthreads();
        As[lc4 + 0][lr] = va.x; As[lc4 + 1][lr] = va.y;
        As[lc4 + 2][lr] = va.z; As[lc4 + 3][lr] = va.w;
        Bs[lc4 + 0][lr] = vb.x; Bs[lc4 + 1][lr] = vb.y;
        Bs[lc4 + 2][lr] = vb.z; Bs[lc4 + 3][lr] = vb.w;
        __syncthreads();
        if (k0 + BK < K) {
            if (ma < M) va = *(const float4*)(A + (size_t)ma * lda + k0 + BK + lc4);
            if (nb < N) vb = *(const float4*)(W + (size_t)nb * ldw + k0 + BK + lc4);
        }
        #pragma unroll
        for (int kk = 0; kk < BK; ++kk) {
            float a[TM], bfr[TN];
            #pragma unroll
            for (int i = 0; i < TM; i += 4)
                *(float4*)&a[i] = *(const float4*)&As[kk][ty * TM + i];
            #pragma unroll
            for (int j = 0; j < TN; j += 4)
                *(float4*)&bfr[j] = *(const float4*)&Bs[kk][tx * TN + j];
            #pragma unroll
            for (int i = 0; i < TM; i++)
                #pragma unroll
                for (int j = 0; j < TN; j++) acc[i][j] = fmaf(a[i], bfr[j], acc[i][j]);
        }
    }
    #pragma unroll
    for (int i = 0; i < TM; i++) {
        int m = m0 + ty * TM + i;
        if (m >= M) continue;
        #pragma unroll
        for (int j = 0; j < TN; j++) {
            int n = n0 + tx * TN + j;
            if (n >= N) continue;
            float v = acc[i][j];
            if (bias) v += bias[n];
            if (act == 2) v = softplus_f(v);
            C[(size_t)m * ldc + n] = v;
        }
    }
}

// ---------------------------------------------------------------------------
// Chunked scan pass 1 (fused dt_proj, 4-step composition, fp32 LDS staging).
// 15 chunks of 64 timesteps (chunk 15's summary is never read): grid 960.
// dt_proj: xd as float4 broadcast, dpw_s stride 34 as float2 (2-way = free).
// ~34.5KB LDS -> 4 blocks/CU.
// ---------------------------------------------------------------------------
__global__ __launch_bounds__(512, 8) void scan_part1(
    const float* __restrict__ xdbl, const ushort* __restrict__ xlb,
    const float* __restrict__ dpw, const float* __restrict__ dpb,
    const float* __restrict__ alog,
    float* __restrict__ Psum, float* __restrict__ hFsum)
{
    __shared__ __align__(16) float Td[32][68];
    __shared__ __align__(16) float Tu[32][68];
    __shared__ __align__(16) float TB[16][68];
    __shared__ __align__(16) float xd[64][32];
    __shared__ __align__(16) float dpw_s[32][34];
    __shared__ float dpb_s[32];
    int t = threadIdx.x;
    int bid = blockIdx.x;                 // 960 = b(4) x dgG(16) x ch(15)
    int ch = bid % 15;
    int gq = bid / 15;
    int dgG = gq & 15, b = gq >> 4;
    int d0 = dgG * 32;
    int bl0 = b * 1024 + ch * 64;
    {   // xd: 64 l x 32 k, one float4/thread
        int l = t >> 3, k4 = (t & 7) * 4;
        float4 v = *(const float4*)(xdbl + (size_t)(bl0 + l) * 64 + k4);
        *(float4*)&xd[l][k4] = v;
    }
    if (t < 256) {   // Tu: 64 l x 32 d (bf16 -> fp32 at stage time)
        int l = t >> 2, d8 = (t & 3) * 8;
        uint4 p = *(const uint4*)(xlb + (size_t)(bl0 + l) * 512 + d0 + d8);
        Tu[d8 + 0][l] = bf2f((ushort)(p.x & 0xffffu));
        Tu[d8 + 1][l] = bf2f((ushort)(p.x >> 16));
        Tu[d8 + 2][l] = bf2f((ushort)(p.y & 0xffffu));
        Tu[d8 + 3][l] = bf2f((ushort)(p.y >> 16));
        Tu[d8 + 4][l] = bf2f((ushort)(p.z & 0xffffu));
        Tu[d8 + 5][l] = bf2f((ushort)(p.z >> 16));
        Tu[d8 + 6][l] = bf2f((ushort)(p.w & 0xffffu));
        Tu[d8 + 7][l] = bf2f((ushort)(p.w >> 16));
    } else {         // TB: 64 l x 16 n, fp32
        int tt = t - 256;
        int l = tt >> 2, n4 = (tt & 3) * 4;
        float4 bv = *(const float4*)(xdbl + (size_t)(bl0 + l) * 64 + 32 + n4);
        TB[n4 + 0][l] = bv.x; TB[n4 + 1][l] = bv.y;
        TB[n4 + 2][l] = bv.z; TB[n4 + 3][l] = bv.w;
    }
    #pragma unroll
    for (int r = 0; r < 2; ++r) {
        int idx = r * 512 + t;
        int dd = idx >> 5, kk = idx & 31;
        dpw_s[dd][kk] = dpw[(size_t)(d0 + dd) * 32 + kk];
    }
    if (t < 32) dpb_s[t] = dpb[d0 + t];
    __syncthreads();
    {   // fused dt_proj: 32 dd x 64 l, 4 entries/thread (vectorized reads)
        int dd = t & 31, lb = (t >> 5) * 4;
        #pragma unroll
        for (int j = 0; j < 4; ++j) {
            int l = lb + j;
            float s = dpb_s[dd];
            #pragma unroll
            for (int k4 = 0; k4 < 8; ++k4) {
                float4 xv = *(const float4*)&xd[l][k4 * 4];
                float2 wa = *(const float2*)&dpw_s[dd][k4 * 4];
                float2 wb = *(const float2*)&dpw_s[dd][k4 * 4 + 2];
                s = fmaf(xv.x, wa.x, s);
                s = fmaf(xv.y, wa.y, s);
                s = fmaf(xv.z, wb.x, s);
                s = fmaf(xv.w, wb.y, s);
            }
            Td[dd][l] = softplus_f(s);
        }
    }
    __syncthreads();
    int w = t >> 6, lane = t & 63;
    int dl = lane >> 4, n = lane & 15;
    int col = w * 4 + dl;
    int d = d0 + col;
    float Ac = -__expf(alog[d * 16 + n]);
    float h = 0.f, P = 1.f;
    for (int l4 = 0; l4 < 16; ++l4) {
        float4 de = *(const float4*)&Td[col][l4 * 4];
        float4 uu = *(const float4*)&Tu[col][l4 * 4];
        float4 Bv = *(const float4*)&TB[n][l4 * 4];
        float a1 = __expf(de.x * Ac), a2 = __expf(de.y * Ac);
        float a3 = __expf(de.z * Ac), a4 = __expf(de.w * Ac);
        float b1 = de.x * Bv.x * uu.x, b2 = de.y * Bv.y * uu.y;
        float b3 = de.z * Bv.z * uu.z, b4 = de.w * Bv.w * uu.w;
        float a21 = a2 * a1,     b21 = fmaf(a2, b1, b2);
        float a321 = a3 * a21,   b321 = fmaf(a3, b21, b3);
        float a4321 = a4 * a321, b4321 = fmaf(a4, b321, b4);
        h = fmaf(a4321, h, b4321);
        P *= a4321;
    }
    size_t si = ((size_t)(b * 128 + dgG * 8 + w) * 16 + ch) * 64 + lane;
    Psum[si] = P;
    hFsum[si] = h;
}

// ---------------------------------------------------------------------------
// Chunked scan pass 2 (fused dt_proj, 4-step composition, fp32 LDS staging,
// DPP row_shr n-reduction, packed yb2, xd overlaid on TB/TC/yb2 union,
// masked-unrolled chunk-prefix loads). ~34.5KB LDS -> 4 blocks/CU.
// ---------------------------------------------------------------------------
__global__ __launch_bounds__(512, 8) void scan_part2(
    const float* __restrict__ xdbl, const ushort* __restrict__ xlb,
    const float* __restrict__ dpw, const float* __restrict__ dpb,
    const float* __restrict__ alog, const float* __restrict__ dssm,
    const ushort* __restrict__ resb, ushort* __restrict__ ybb,
    const float* __restrict__ Psum, const float* __restrict__ hFsum)
{
    __shared__ __align__(16) float Td[32][68];
    __shared__ __align__(16) float Tu[32][68];
    // union: xd fp32[64][32] (8192B) overlays TB(4352)+TC(4352)+yb2(4224)=12928B
    __shared__ __align__(16) unsigned char uni[12928];
    __shared__ __align__(16) float dpw_s[32][34];
    __shared__ float dpb_s[32];
    float* xd = (float*)uni;                          // [64][32]
    float (*TB)[68] = (float(*)[68])uni;              // [16][68]
    float (*TC)[68] = (float(*)[68])(uni + 4352);     // [16][68]
    uint (*yb2)[33] = (uint(*)[33])(uni + 8704);      // [32][33]
    int t = threadIdx.x;
    int bid = blockIdx.x;                 // 1024 = b(4) x dgG(16) x ch(16)
    int ch = bid & 15, dgG = (bid >> 4) & 15, b = bid >> 8;
    int d0 = dgG * 32;
    int bl0 = b * 1024 + ch * 64;
    {   // xd into union
        int l = t >> 3, k4 = (t & 7) * 4;
        float4 v = *(const float4*)(xdbl + (size_t)(bl0 + l) * 64 + k4);
        *(float4*)&xd[l * 32 + k4] = v;
    }
    if (t < 256) {   // Tu (bf16 -> fp32 at stage time)
        int l = t >> 2, d8 = (t & 3) * 8;
        uint4 p = *(const uint4*)(xlb + (size_t)(bl0 + l) * 512 + d0 + d8);
        Tu[d8 + 0][l] = bf2f((ushort)(p.x & 0xffffu));
        Tu[d8 + 1][l] = bf2f((ushort)(p.x >> 16));
        Tu[d8 + 2][l] = bf2f((ushort)(p.y & 0xffffu));
        Tu[d8 + 3][l] = bf2f((ushort)(p.y >> 16));
        Tu[d8 + 4][l] = bf2f((ushort)(p.z & 0xffffu));
        Tu[d8 + 5][l] = bf2f((ushort)(p.z >> 16));
        Tu[d8 + 6][l] = bf2f((ushort)(p.w & 0xffffu));
        Tu[d8 + 7][l] = bf2f((ushort)(p.w >> 16));
    }
    #pragma unroll
    for (int r = 0; r < 2; ++r) {
        int idx = r * 512 + t;
        int dd = idx >> 5, kk = idx & 31;
        dpw_s[dd][kk] = dpw[(size_t)(d0 + dd) * 32 + kk];
    }
    if (t < 32) dpb_s[t] = dpb[d0 + t];
    __syncthreads();
    {   // fused dt_proj (reads xd, vectorized)
        int dd = t & 31, lb = (t >> 5) * 4;
        #pragma unroll
        for (int j = 0; j < 4; ++j) {
            int l = lb + j;
            float s = dpb_s[dd];
            #pragma unroll
            for (int k4 = 0; k4 < 8; ++k4) {
                float4 xv = *(const float4*)&xd[l * 32 + k4 * 4];
                float2 wa = *(const float2*)&dpw_s[dd][k4 * 4];
                float2 wb = *(const float2*)&dpw_s[dd][k4 * 4 + 2];
                s = fmaf(xv.x, wa.x, s);
                s = fmaf(xv.y, wa.y, s);
                s = fmaf(xv.z, wb.x, s);
                s = fmaf(xv.w, wb.y, s);
            }
            Td[dd][l] = softplus_f(s);
        }
    }
    __syncthreads();   // xd dead; Td visible
    if (t < 256) {     // TB/TC over dead xd, fp32
        int l = t >> 2, n4 = (t & 3) * 4;
        float4 bv = *(const float4*)(xdbl + (size_t)(bl0 + l) * 64 + 32 + n4);
        float4 cv = *(const float4*)(xdbl + (size_t)(bl0 + l) * 64 + 48 + n4);
        TB[n4 + 0][l] = bv.x; TB[n4 + 1][l] = bv.y;
        TB[n4 + 2][l] = bv.z; TB[n4 + 3][l] = bv.w;
        TC[n4 + 0][l] = cv.x; TC[n4 + 1][l] = cv.y;
        TC[n4 + 2][l] = cv.z; TC[n4 + 3][l] = cv.w;
    }
    int w = t >> 6, lane = t & 63;
    int dl = lane >> 4, n = lane & 15;
    int col = w * 4 + dl;
    int d = d0 + col;
    float Ac = -__expf(alog[d * 16 + n]);
    float Dd = dssm[d];
    float h = 0.f;
    {   // chunk-prefix: fully unrolled, masked -> all loads issue in parallel
        size_t sbase = (size_t)(b * 128 + dgG * 8 + w) * 1024 + lane;
        #pragma unroll
        for (int cc = 0; cc < 15; ++cc) {
            float Pv = Psum[sbase + (size_t)cc * 64];
            float hv = hFsum[sbase + (size_t)cc * 64];
            bool use = cc < ch;
            Pv = use ? Pv : 1.f;
            hv = use ? hv : 0.f;
            h = fmaf(Pv, h, hv);
        }
    }
    __syncthreads();   // TB/TC visible
    for (int l4 = 0; l4 < 16; ++l4) {
        float4 de = *(const float4*)&Td[col][l4 * 4];
        float4 uu = *(const float4*)&Tu[col][l4 * 4];
        float4 Bv = *(const float4*)&TB[n][l4 * 4];
        float4 Cv = *(const float4*)&TC[n][l4 * 4];
        float a1 = __expf(de.x * Ac), a2 = __expf(de.y * Ac);
        float a3 = __expf(de.z * Ac), a4 = __expf(de.w * Ac);
        float b1 = de.x * Bv.x * uu.x, b2 = de.y * Bv.y * uu.y;
        float b3 = de.z * Bv.z * uu.z, b4 = de.w * Bv.w * uu.w;
        float a21 = a2 * a1,     b21 = fmaf(a2, b1, b2);
        float a321 = a3 * a21,   b321 = fmaf(a3, b21, b3);
        float a4321 = a4 * a321, b4321 = fmaf(a4, b321, b4);
        float h1 = fmaf(a1, h, b1);
        float h2 = fmaf(a21, h, b21);
        float h3 = fmaf(a321, h, b321);
        float h4 = fmaf(a4321, h, b4321);
        h = h4;
        float p0 = h1 * Cv.x, p1 = h2 * Cv.y, p2 = h3 * Cv.z, p3 = h4 * Cv.w;
        // 16-lane n-reduction via DPP row_shr: sum lands in lane n==15.
        DPP_ROW_SHR_ADD(p0, 1); DPP_ROW_SHR_ADD(p0, 2);
        DPP_ROW_SHR_ADD(p0, 4); DPP_ROW_SHR_ADD(p0, 8);
        DPP_ROW_SHR_ADD(p1, 1); DPP_ROW_SHR_ADD(p1, 2);
        DPP_ROW_SHR_ADD(p1, 4); DPP_ROW_SHR_ADD(p1, 8);
        DPP_ROW_SHR_ADD(p2, 1); DPP_ROW_SHR_ADD(p2, 2);
        DPP_ROW_SHR_ADD(p2, 4); DPP_ROW_SHR_ADD(p2, 8);
        DPP_ROW_SHR_ADD(p3, 1); DPP_ROW_SHR_ADD(p3, 2);
        DPP_ROW_SHR_ADD(p3, 4); DPP_ROW_SHR_ADD(p3, 8);
        if (n == 15) {
            int l2 = l4 * 2;
            float y0 = fmaf(uu.x, Dd, p0), y1 = fmaf(uu.y, Dd, p1);
            float y2 = fmaf(uu.z, Dd, p2), y3 = fmaf(uu.w, Dd, p3);
            yb2[l2 + 0][col] = (uint)f2bf(y0) | ((uint)f2bf(y1) << 16);
            yb2[l2 + 1][col] = (uint)f2bf(y2) | ((uint)f2bf(y3) << 16);
        }
    }
    __syncthreads();
    // gated store: 32 l2 x 32 col = 1024 items over 512 threads x 2
    size_t base = ((size_t)(b * 1024 + ch * 64)) * 512 + d0;   // ushort offset
    #pragma unroll
    for (int j = 0; j < 2; ++j) {
        int idx = j * 512 + t;
        int l2 = idx >> 5, col2 = idx & 31;
        uint yv = yb2[l2][col2];
        int l0 = l2 * 2;
        float r0 = bf2f(resb[base + (size_t)l0 * 512 + col2]);
        float r1 = bf2f(resb[base + (size_t)(l0 + 1) * 512 + col2]);
        float y0 = bf2f((ushort)(yv & 0xffffu)) * r0;
        float y1 = bf2f((ushort)(yv >> 16)) * r1;
        ybb[base + (size_t)l0 * 512 + col2] = f2bf(y0);
        ybb[base + (size_t)(l0 + 1) * 512 + col2] = f2bf(y1);
    }
}

// s[row] = LN(o[row])*g + b + s[row]; also writes bf16 copy sb. One wave/row.
__global__ __launch_bounds__(256) void ln_res_kernel(
    const float* __restrict__ o, const float* __restrict__ g,
    const float* __restrict__ bb, float* __restrict__ s, ushort* __restrict__ sb)
{
    int row = blockIdx.x * 4 + (threadIdx.x >> 6);
    int lane = threadIdx.x & 63;
    const float4* orow = (const float4*)(o + (size_t)row * 256);
    float4 v = orow[lane];
    float sum = v.x + v.y + v.z + v.w;
    float sq = v.x * v.x + v.y * v.y + v.z * v.z + v.w * v.w;
    #pragma unroll
    for (int off = 1; off < 64; off <<= 1) {
        sum += __shfl_xor(sum, off);
        sq += __shfl_xor(sq, off);
    }
    float m = sum * (1.f / 256.f);
    float var = sq * (1.f / 256.f) - m * m;
    float rstd = rsqrtf(var + 1e-5f);
    float4 gg = ((const float4*)g)[lane];
    float4 bv = ((const float4*)bb)[lane];
    float4* srow = (float4*)(s + (size_t)row * 256);
    float4 sv = srow[lane];
    sv.x += (v.x - m) * rstd * gg.x + bv.x;
    sv.y += (v.y - m) * rstd * gg.y + bv.y;
    sv.z += (v.z - m) * rstd * gg.z + bv.z;
    sv.w += (v.w - m) * rstd * gg.w + bv.w;
    srow[lane] = sv;
    uint2 pk;
    pk.x = (uint)f2bf(sv.x) | ((uint)f2bf(sv.y) << 16);
    pk.y = (uint)f2bf(sv.z) | ((uint)f2bf(sv.w) << 16);
    *(uint2*)(sb + (size_t)row * 256 + lane * 4) = pk;
}

// mean over l then LN over 256 channels. grid 4 x 256.
__global__ __launch_bounds__(256) void pool_ln_kernel(
    const float* __restrict__ s, const float* __restrict__ nw,
    const float* __restrict__ nb, float* __restrict__ sln)
{
    int b = blockIdx.x, c = threadIdx.x;
    const float* p = s + (size_t)b * 262144 + c;
    float acc = 0.f;
    for (int l = 0; l < 1024; ++l) acc += p[(size_t)l * 256];
    float pooled = acc * (1.f / 1024.f);
    __shared__ float rs[4], rq[4];
    float sum = pooled, sq = pooled * pooled;
    #pragma unroll
    for (int off = 1; off < 64; off <<= 1) {
        sum += __shfl_xor(sum, off);
        sq += __shfl_xor(sq, off);
    }
    int w = threadIdx.x >> 6;
    if ((threadIdx.x & 63) == 0) { rs[w] = sum; rq[w] = sq; }
    __syncthreads();
    sum = rs[0] + rs[1] + rs[2] + rs[3];
    sq = rq[0] + rq[1] + rq[2] + rq[3];
    float m = sum * (1.f / 256.f);
    float var = sq * (1.f / 256.f) - m * m;
    float rstd = rsqrtf(var + 1e-5f);
    sln[b * 256 + c] = (pooled - m) * rstd * nw[c] + nb[c];
}

// softmax over 1000 logits per b
__global__ __launch_bounds__(256) void softmax_kernel(float* __restrict__ out)
{
    int b = threadIdx.x >> 6, lane = threadIdx.x & 63;
    const float* lg = out + b * 1000;
    float v[16];
    float mx = -1e30f;
    #pragma unroll
    for (int j = 0; j < 16; ++j) {
        int i = lane + j * 64;
        v[j] = (i < 1000) ? lg[i] : -1e30f;
        mx = fmaxf(mx, v[j]);
    }
    #pragma unroll
    for (int off = 1; off < 64; off <<= 1) mx = fmaxf(mx, __shfl_xor(mx, off));
    float sum = 0.f;
    #pragma unroll
    for (int j = 0; j < 16; ++j) {
        int i = lane + j * 64;
        if (i < 1000) { v[j] = __expf(v[j] - mx); sum += v[j]; }
    }
    #pragma unroll
    for (int off = 1; off < 64; off <<= 1) sum += __shfl_xor(sum, off);
    float inv = 1.f / sum;
    float* so = out + 4000 + b * 1000;
    #pragma unroll
    for (int j = 0; j < 16; ++j) {
        int i = lane + j * 64;
        if (i < 1000) so[i] = v[j] * inv;
    }
}

// ---------------------------------------------------------------------------
extern "C" void kernel_launch(void* const* d_in, const int* in_sizes, int n_in,
                              void* d_out, int out_size, void* d_ws, size_t ws_size,
                              hipStream_t stream)
{
    const float* x    = (const float*)d_in[0];
    const float* c1w  = (const float*)d_in[1];
    const float* c1b  = (const float*)d_in[2];
    const float* g1   = (const float*)d_in[3];
    const float* b1   = (const float*)d_in[4];
    const float* c2w  = (const float*)d_in[5];
    const float* c2b  = (const float*)d_in[6];
    const float* g2   = (const float*)d_in[7];
    const float* b2   = (const float*)d_in[8];
    const float* pw   = (const float*)d_in[9];
    const float* pb   = (const float*)d_in[10];
    const float* g3   = (const float*)d_in[11];
    const float* b3   = (const float*)d_in[12];
    const float* ipw  = (const float*)d_in[13];
    const float* ipb  = (const float*)d_in[14];
    const float* cw   = (const float*)d_in[15];
    const float* cb   = (const float*)d_in[16];
    const float* xpw  = (const float*)d_in[17];
    const float* dpw  = (const float*)d_in[18];
    const float* dpb  = (const float*)d_in[19];
    const float* alog = (const float*)d_in[20];
    const float* dssm = (const float*)d_in[21];
    const float* opw  = (const float*)d_in[22];
    const float* opb  = (const float*)d_in[23];
    const float* lnw  = (const float*)d_in[24];
    const float* lnb  = (const float*)d_in[25];
    const float* nw   = (const float*)d_in[26];
    const float* nb   = (const float*)d_in[27];
    const float* fcw  = (const float*)d_in[28];
    const float* fcb  = (const float*)d_in[29];
    float* out = (float*)d_out;
    float* wsf = (float*)d_ws;

    float*  s_   = wsf;
    ushort* sb   = (ushort*)(wsf + 1048576);
    ushort* xib  = (ushort*)(wsf + 1572864);
    float*  obuf = wsf + 1572864;
    ushort* resb = (ushort*)(wsf + 3670016);
    ushort* xlb  = (ushort*)(wsf + 4718592);   // == u == ybb (in-place gate)
    ushort* ybb  = (ushort*)(wsf + 4718592);
    ushort* h1b  = (ushort*)(wsf + 4718592);
    ushort* Apb  = (ushort*)(wsf + 6815744);
    float*  xdbl = wsf + 8912896;
    ushort* ipwb = (ushort*)(wsf + 9175040);
    ushort* opwb = (ushort*)(wsf + 9699328);
    ushort* w2b  = (ushort*)(wsf + 9961472);
    ushort* pwTb = (ushort*)(wsf + 10108928);
    float*  sln  = wsf + 10240000;
    float*  Psum = wsf + 10241024;             // [4][128][16][64] = 524288 fl
    float*  hFsum= wsf + 10765312;             // 524288 fl
    ushort* xpwb = (ushort*)(wsf + 11289600);  // 131072 ushorts; end 11355136 fl

    // --- fused weight prep (1 dispatch) ---
    hipLaunchKernelGGL(wprep, dim3(8832), dim3(256), 0, stream,
                       ipw, opw, c2w, pw, xpw, ipwb, opwb, w2b, pwTb, xpwb);

    // --- conv stem ---
    hipLaunchKernelGGL(conv1_nhwc, dim3(256), dim3(256), 0, stream, x, c1w, c1b, g1, b1, h1b);
    hipLaunchKernelGGL(conv2_mfma, dim3(128, 4), dim3(256), 0, stream, h1b, w2b, c2b, g2, b2, Apb);
    hipLaunchKernelGGL((mfma_gemm_bt<64, 64, 2>), dim3(64, 4), dim3(256), 0, stream,
                       Apb, 1024, pwTb, 1024, pb, g3, b3, s_, sb, nullptr, 256, 1024);

    // --- mamba blocks ---
    for (int i = 0; i < 4; ++i) {
        const ushort* ipwb_i = ipwb + (size_t)i * 1024 * 256;
        const float*  ipb_i  = ipb + i * 1024;
        const float*  cw_i   = cw + i * 512 * 4;
        const float*  cb_i   = cb + i * 512;
        const ushort* xpwb_i = xpwb + (size_t)i * 64 * 512;
        const float*  dpw_i  = dpw + (size_t)i * 512 * 32;
        const float*  dpb_i  = dpb + i * 512;
        const float*  alog_i = alog + (size_t)i * 512 * 16;
        const float*  dssm_i = dssm + i * 512;
        const ushort* opwb_i = opwb + (size_t)i * 256 * 512;
        const float*  opb_i  = opb + i * 256;
        const float*  lnw_i  = lnw + i * 256;
        const float*  lnb_i  = lnb + i * 256;

        hipLaunchKernelGGL((mfma_gemm_bt<64, 128, 3>), dim3(64, 8), dim3(256), 0, stream,
                           sb, 256, ipwb_i, 256, ipb_i, nullptr, nullptr,
                           nullptr, xib, resb, 0, 256);
        hipLaunchKernelGGL(xproj_conv_gemm, dim3(64), dim3(256), 0, stream,
                           xib, cw_i, cb_i, xpwb_i, xlb, xdbl);
        hipLaunchKernelGGL(scan_part1, dim3(960), dim3(512), 0, stream,
                           xdbl, xlb, dpw_i, dpb_i, alog_i, Psum, hFsum);
        hipLaunchKernelGGL(scan_part2, dim3(1024), dim3(512), 0, stream,
                           xdbl, xlb, dpw_i, dpb_i, alog_i, dssm_i, resb, ybb, Psum, hFsum);
        hipLaunchKernelGGL((mfma_gemm_bt<64, 64, 0>), dim3(64, 4), dim3(256), 0, stream,
                           ybb, 512, opwb_i, 512, opb_i, nullptr, nullptr,
                           obuf, nullptr, nullptr, 256, 512);
        hipLaunchKernelGGL(ln_res_kernel, dim3(1024), dim3(256), 0, stream,
                           obuf, lnw_i, lnb_i, s_, sb);
    }

    // --- head ---
    hipLaunchKernelGGL(pool_ln_kernel, dim3(4), dim3(256), 0, stream, s_, nw, nb, sln);
    hipLaunchKernelGGL((gemm_kernel<64, 64, 16, 4, 4>), dim3(1, 16), dim3(256), 0, stream,
                       sln, 256, fcw, 256, fcb, out, 1000, 4, 1000, 256, 0);
    hipLaunchKernelGGL(softmax_kernel, dim3(1), dim3(256), 0, stream, out);
}

// Round 9
// 578.872 us; speedup vs baseline: 1.2240x; 1.2240x over previous
//
#include <hip/hip_runtime.h>
#include <math.h>

// ---------------------------------------------------------------------------
// FastImageMamba forward. R22 = R20 exact revert (verified 577.0us).
// R21's dwconv-into-xproj fusion collapsed: grid-64 xproj has ~1 wave/SIMD,
// so the conv's 4-dependent-load chain in A-staging was fully exposed
// (49us/dispatch, occ 2.5%). dwconv stays a separate 2048-block dispatch.
// B=4, DM=256, NL=4, NC=1000, DI=512, NS=16, DTR=32, K=4, L=1024, H=W=64
// ---------------------------------------------------------------------------

#define BN_RSQ 0.99999500003749969f   // 1/sqrt(1+1e-5)

typedef unsigned int uint;
typedef unsigned short ushort;
typedef __bf16 bf16x8 __attribute__((ext_vector_type(8)));
typedef float floatx4 __attribute__((ext_vector_type(4)));

__device__ __forceinline__ float gelu_f(float v) {
    return 0.5f * v * (1.0f + erff(v * 0.70710678118654752f));
}
__device__ __forceinline__ float softplus_f(float v) {
    return (v > 20.f) ? v : log1pf(expf(v));
}
__device__ __forceinline__ ushort f2bf(float f) {
    uint x = __float_as_uint(f);
    x += 0x7fffu + ((x >> 16) & 1u);
    return (ushort)(x >> 16);
}
__device__ __forceinline__ float bf2f(ushort u) {
    return __uint_as_float((uint)u << 16);
}

// DPP row_shr:N add step: after N=1,2,4,8 lane 15 of each 16-lane row holds
// the row sum (bound_ctrl=1 -> out-of-row sources read 0).
#define DPP_ROW_SHR_ADD(x, N)                                               \
    x += __int_as_float(__builtin_amdgcn_update_dpp(                        \
        0, __float_as_int(x), 0x110 + (N), 0xf, 0xf, true))

// ---------------------------------------------------------------------------
// Fused weight prep: all fp32->bf16 weight conversions in one dispatch.
// ---------------------------------------------------------------------------
__global__ void wprep(const float* __restrict__ ipw, const float* __restrict__ opw,
                      const float* __restrict__ c2w, const float* __restrict__ pw,
                      const float* __restrict__ xpw,
                      ushort* __restrict__ ipwb, ushort* __restrict__ opwb,
                      ushort* __restrict__ w2b, ushort* __restrict__ pwTb,
                      ushort* __restrict__ xpwb)
{
    int idx = blockIdx.x * 256 + threadIdx.x;
    if (idx < 1048576) {
        ipwb[idx] = f2bf(ipw[idx]);
    } else if (idx < 1572864) {
        int i = idx - 1048576;
        opwb[i] = f2bf(opw[i]);
    } else if (idx < 1867776) {
        int i = idx - 1572864;
        int oc = i / 1152, k = i % 1152;
        int s = k >> 7, ic = k & 127;
        w2b[i] = f2bf(c2w[(size_t)(oc * 128 + ic) * 9 + s]);
    } else if (idx < 2129920) {
        int i = idx - 1867776;
        int oc = i >> 10, k = i & 1023;
        int s = k >> 8, ic = k & 255;
        int ky = s >> 1, kx = s & 1;
        pwTb[i] = f2bf(pw[((size_t)(oc * 256 + ic) * 2 + ky) * 2 + kx]);
    } else if (idx < 2260992) {
        int i = idx - 2129920;
        xpwb[i] = f2bf(xpw[i]);
    }
}

// ---------------------------------------------------------------------------
// conv1: 3x3 s1p1, IC=3 -> OC=128, NCHW fp32 in, NHWC bf16 out (+bias+BN+GELU)
// ---------------------------------------------------------------------------
__global__ __launch_bounds__(256) void conv1_nhwc(
    const float* __restrict__ x, const float* __restrict__ w,
    const float* __restrict__ cb, const float* __restrict__ g,
    const float* __restrict__ bb, ushort* __restrict__ out)
{
    __shared__ float tin[3][3][64];
    __shared__ float ws[3456];
    int t = threadIdx.x;
    int b = blockIdx.x >> 6, y = blockIdx.x & 63;
    for (int i = t; i < 3456; i += 256) ws[i] = w[i];
    for (int i = t; i < 576; i += 256) {
        int ic = i / 192, r = (i >> 6) % 3, xx = i & 63;
        int gy = y + r - 1;
        tin[ic][r][xx] = ((unsigned)gy < 64u) ? x[((b * 3 + ic) * 64 + gy) * 64 + xx] : 0.f;
    }
    __syncthreads();
    int tx = t & 15, ty = t >> 4;
    int oc0 = tx * 8, px0 = ty * 4;
    float acc[4][8];
    #pragma unroll
    for (int p = 0; p < 4; ++p)
        #pragma unroll
        for (int o = 0; o < 8; ++o) acc[p][o] = 0.f;
    for (int ic = 0; ic < 3; ++ic)
        #pragma unroll
        for (int ky = 0; ky < 3; ++ky)
            #pragma unroll
            for (int kx = 0; kx < 3; ++kx) {
                float av[4];
                #pragma unroll
                for (int p = 0; p < 4; ++p) {
                    int xx = px0 + p + kx - 1;
                    av[p] = ((unsigned)xx < 64u) ? tin[ic][ky][xx] : 0.f;
                }
                #pragma unroll
                for (int o = 0; o < 8; ++o) {
                    float wv = ws[(oc0 + o) * 27 + ic * 9 + ky * 3 + kx];
                    #pragma unroll
                    for (int p = 0; p < 4; ++p) acc[p][o] = fmaf(av[p], wv, acc[p][o]);
                }
            }
    #pragma unroll
    for (int p = 0; p < 4; ++p) {
        uint pk[4];
        #pragma unroll
        for (int o2 = 0; o2 < 4; ++o2) {
            int oc = oc0 + o2 * 2;
            float v0 = gelu_f((acc[p][o2 * 2] + cb[oc]) * (g[oc] * BN_RSQ) + bb[oc]);
            float v1 = gelu_f((acc[p][o2 * 2 + 1] + cb[oc + 1]) * (g[oc + 1] * BN_RSQ) + bb[oc + 1]);
            pk[o2] = (uint)f2bf(v0) | ((uint)f2bf(v1) << 16);
        }
        uint4 vv = make_uint4(pk[0], pk[1], pk[2], pk[3]);
        *(uint4*)(out + ((size_t)((b * 64 + y) * 64 + px0 + p)) * 128 + oc0) = vv;
    }
}

// ---------------------------------------------------------------------------
// bf16 MFMA GEMM (A @ W^T), BMxBN tile, BK=32, 4 waves (2x2), reg dbuf.
// EPI: 0 = +bias -> fp32 Cf[ldc]
//      2 = +bias,BN,GELU -> fp32 Cf + bf16 Cb (same ldc)
//      3 = in_proj: n<512 -> bf16 Cb[m*512+n]; n>=512 -> bf16 silu -> Cb2
// ---------------------------------------------------------------------------
template<int BM, int BN, int EPI>
__global__ __launch_bounds__(256, 2) void mfma_gemm_bt(
    const ushort* __restrict__ A, int lda,
    const ushort* __restrict__ W, int ldw,
    const float* __restrict__ bias,
    const float* __restrict__ bnG, const float* __restrict__ bnB,
    float* __restrict__ Cf, ushort* __restrict__ Cb, ushort* __restrict__ Cb2,
    int ldc, int K)
{
    constexpr int PAD = 40;
    constexpr int AP = BM / 64;
    constexpr int BP = BN / 64;
    constexpr int FM = BM / 32;
    constexpr int FN = BN / 32;
    __shared__ __align__(16) ushort As[BM * PAD];
    __shared__ __align__(16) ushort Bs[BN * PAD];
    int t = threadIdx.x;
    int m0 = blockIdx.x * BM, n0 = blockIdx.y * BN;
    int lane = t & 63, wid = t >> 6;
    int wm = (wid & 1) * (BM / 2), wn = (wid >> 1) * (BN / 2);
    int fr = lane & 15, fk = (lane >> 4) * 8;
    int r0 = t >> 2, c0 = (t & 3) * 8;
    floatx4 acc[FM][FN];
    #pragma unroll
    for (int i = 0; i < FM; ++i)
        #pragma unroll
        for (int j = 0; j < FN; ++j) acc[i][j] = {0.f, 0.f, 0.f, 0.f};
    uint4 ra[AP], rb[BP];
    #pragma unroll
    for (int p = 0; p < AP; ++p)
        ra[p] = *(const uint4*)(A + (size_t)(m0 + r0 + p * 64) * lda + c0);
    #pragma unroll
    for (int p = 0; p < BP; ++p)
        rb[p] = *(const uint4*)(W + (size_t)(n0 + r0 + p * 64) * ldw + c0);
    for (int k0 = 0; k0 < K; k0 += 32) {
        __syncthreads();
        #pragma unroll
        for (int p = 0; p < AP; ++p) *(uint4*)&As[(r0 + p * 64) * PAD + c0] = ra[p];
        #pragma unroll
        for (int p = 0; p < BP; ++p) *(uint4*)&Bs[(r0 + p * 64) * PAD + c0] = rb[p];
        __syncthreads();
        if (k0 + 32 < K) {
            #pragma unroll
            for (int p = 0; p < AP; ++p)
                ra[p] = *(const uint4*)(A + (size_t)(m0 + r0 + p * 64) * lda + k0 + 32 + c0);
            #pragma unroll
            for (int p = 0; p < BP; ++p)
                rb[p] = *(const uint4*)(W + (size_t)(n0 + r0 + p * 64) * ldw + k0 + 32 + c0);
        }
        bf16x8 af[FM], bw[FN];
        #pragma unroll
        for (int i = 0; i < FM; ++i)
            af[i] = *(const bf16x8*)&As[(wm + i * 16 + fr) * PAD + fk];
        #pragma unroll
        for (int j = 0; j < FN; ++j)
            bw[j] = *(const bf16x8*)&Bs[(wn + j * 16 + fr) * PAD + fk];
        #pragma unroll
        for (int i = 0; i < FM; ++i)
            #pragma unroll
            for (int j = 0; j < FN; ++j)
                acc[i][j] = __builtin_amdgcn_mfma_f32_16x16x32_bf16(af[i], bw[j], acc[i][j], 0, 0, 0);
    }
    int rbase = (lane >> 4) * 4, cc = lane & 15;
    #pragma unroll
    for (int j = 0; j < FN; ++j) {
        int n = n0 + wn + j * 16 + cc;
        float bv = bias ? bias[n] : 0.f;
        float scl = 0.f, shf = 0.f;
        if (EPI == 2) { scl = bnG[n] * BN_RSQ; shf = bnB[n]; }
        #pragma unroll
        for (int i = 0; i < FM; ++i) {
            #pragma unroll
            for (int r = 0; r < 4; ++r) {
                int m = m0 + wm + i * 16 + rbase + r;
                float v = acc[i][j][r] + bv;
                if (EPI == 2) v = gelu_f(v * scl + shf);
                if (EPI == 0) {
                    Cf[(size_t)m * ldc + n] = v;
                } else if (EPI == 2) {
                    Cf[(size_t)m * ldc + n] = v;
                    Cb[(size_t)m * ldc + n] = f2bf(v);
                } else {
                    if (n < 512) Cb[(size_t)m * 512 + n] = f2bf(v);
                    else Cb2[(size_t)m * 512 + (n - 512)] = f2bf(v / (1.f + __expf(-v)));
                }
            }
        }
    }
}

// ---------------------------------------------------------------------------
// conv2: 9-shift implicit MFMA GEMM, 128px x 64oc tile, BK=64 (18 steps),
// reg dbuf with EXPLICIT SCALAR uint4s (array-by-ref spills to scratch).
// Writes DIRECTLY in im2col/Apb layout (im2col kernel deleted).
// ---------------------------------------------------------------------------
#define C2_LOAD(step)                                                            \
    {                                                                            \
        int s_ = (step) >> 1, ich_ = ((step) & 1) * 64;                          \
        int ky_ = s_ / 3, kx_ = s_ % 3;                                          \
        int sy_ = y0 + (ra_row >> 6) + ky_ - 1;                                  \
        int sx_ = (ra_row & 63) + kx_ - 1;                                       \
        bool v_ = ((unsigned)sy_ < 64u) && ((unsigned)sx_ < 64u);                \
        const ushort* ap_ = hb + ((size_t)(sy_ * 64 + sx_)) * 128 + ich_ + ra_c; \
        uint4 zz_ = make_uint4(0u, 0u, 0u, 0u);                                  \
        ra0 = v_ ? *(const uint4*)(ap_ + 0)  : zz_;                              \
        ra1 = v_ ? *(const uint4*)(ap_ + 8)  : zz_;                              \
        ra2 = v_ ? *(const uint4*)(ap_ + 16) : zz_;                              \
        ra3 = v_ ? *(const uint4*)(ap_ + 24) : zz_;                              \
        const ushort* wp_ = w2b + (size_t)(n0 + rb_row) * 1152 + s_ * 128 + ich_ + rb_c; \
        rb0 = *(const uint4*)(wp_ + 0);                                          \
        rb1 = *(const uint4*)(wp_ + 8);                                          \
    }

__global__ __launch_bounds__(256, 2) void conv2_mfma(
    const ushort* __restrict__ h1b, const ushort* __restrict__ w2b,
    const float* __restrict__ cb, const float* __restrict__ g,
    const float* __restrict__ bb, ushort* __restrict__ Apb)
{
    constexpr int PAD = 72;
    __shared__ __align__(16) ushort As[128 * PAD];
    __shared__ __align__(16) ushort Bs[64 * PAD];
    int t = threadIdx.x;
    int m0 = blockIdx.x * 128, n0 = blockIdx.y * 64;
    int b = m0 >> 12;
    int y0 = (m0 & 4095) >> 6;
    int lane = t & 63, wid = t >> 6;
    int wm = (wid & 1) * 64, wn = (wid >> 1) * 32;
    int fr = lane & 15, fk = (lane >> 4) * 8;
    int ra_row = t >> 1, ra_c = (t & 1) * 32;
    int rb_row = t >> 2, rb_c = (t & 3) * 16;
    floatx4 acc[4][2];
    #pragma unroll
    for (int i = 0; i < 4; ++i)
        #pragma unroll
        for (int j = 0; j < 2; ++j) acc[i][j] = {0.f, 0.f, 0.f, 0.f};
    const ushort* hb = h1b + (size_t)b * 4096 * 128;

    uint4 ra0, ra1, ra2, ra3, rb0, rb1;
    C2_LOAD(0);
    for (int step = 0; step < 18; ++step) {
        __syncthreads();
        *(uint4*)&As[ra_row * PAD + ra_c + 0]  = ra0;
        *(uint4*)&As[ra_row * PAD + ra_c + 8]  = ra1;
        *(uint4*)&As[ra_row * PAD + ra_c + 16] = ra2;
        *(uint4*)&As[ra_row * PAD + ra_c + 24] = ra3;
        *(uint4*)&Bs[rb_row * PAD + rb_c + 0]  = rb0;
        *(uint4*)&Bs[rb_row * PAD + rb_c + 8]  = rb1;
        __syncthreads();
        if (step + 1 < 18) C2_LOAD(step + 1);
        #pragma unroll
        for (int ks = 0; ks < 64; ks += 32) {
            bf16x8 af[4], bw[2];
            #pragma unroll
            for (int i = 0; i < 4; ++i)
                af[i] = *(const bf16x8*)&As[(wm + i * 16 + fr) * PAD + ks + fk];
            #pragma unroll
            for (int j = 0; j < 2; ++j)
                bw[j] = *(const bf16x8*)&Bs[(wn + j * 16 + fr) * PAD + ks + fk];
            #pragma unroll
            for (int i = 0; i < 4; ++i)
                #pragma unroll
                for (int j = 0; j < 2; ++j)
                    acc[i][j] = __builtin_amdgcn_mfma_f32_16x16x32_bf16(af[i], bw[j], acc[i][j], 0, 0, 0);
        }
    }
    int rbase = (lane >> 4) * 4, cc = lane & 15;
    #pragma unroll
    for (int j = 0; j < 2; ++j) {
        int n = n0 + wn + j * 16 + cc;
        float scl = g[n] * BN_RSQ, shf = bb[n], bv2 = cb[n];
        #pragma unroll
        for (int i = 0; i < 4; ++i) {
            #pragma unroll
            for (int r = 0; r < 4; ++r) {
                int m = m0 + wm + i * 16 + rbase + r;   // b*4096 + y*64 + x
                float v = gelu_f((acc[i][j][r] + bv2) * scl + shf);
                int yy = (m >> 6) & 63, xx = m & 63;
                int arow = (m >> 12) * 1024 + (yy >> 1) * 32 + (xx >> 1);
                int acol = ((yy & 1) * 2 + (xx & 1)) * 256 + n;
                Apb[(size_t)arow * 1024 + acol] = f2bf(v);
            }
        }
    }
}

// ---------------------------------------------------------------------------
// fp32 tiled GEMM (reg dbuf): head FC only.
// ---------------------------------------------------------------------------
template<int BM, int BN, int BK, int TM, int TN>
__global__ __launch_bounds__(256) void gemm_kernel(
    const float* __restrict__ A, int lda,
    const float* __restrict__ W, int ldw,
    const float* __restrict__ bias,
    float* __restrict__ C, int ldc,
    int M, int N, int K, int act)
{
    static_assert(BM * BK / 4 == 256 && BN * BK / 4 == 256, "staging shape");
    __shared__ float As[BK][BM + 4];
    __shared__ float Bs[BK][BN + 4];
    int t = threadIdx.x;
    int m0 = blockIdx.x * BM, n0 = blockIdx.y * BN;
    float acc[TM][TN];
    #pragma unroll
    for (int i = 0; i < TM; i++)
        #pragma unroll
        for (int j = 0; j < TN; j++) acc[i][j] = 0.f;
    const int LPR = BK / 4;
    int lr = t / LPR, lc4 = (t % LPR) * 4;
    int ty = t >> 4, tx = t & 15;
    int ma = m0 + lr, nb = n0 + lr;
    float4 va = make_float4(0.f, 0.f, 0.f, 0.f);
    float4 vb = make_float4(0.f, 0.f, 0.f, 0.f);
    if (ma < M) va = *(const float4*)(A + (size_t)ma * lda + lc4);
    if (nb < N) vb = *(const float4*)(W + (size_t)nb * ldw + lc4);
    for (int k0 = 0; k0 < K; k0 += BK) {
        __syncthreads();
        As[lc4 + 0][lr] = va.x; As[lc4 + 1][lr] = va.y;
        As[lc4 + 2][lr] = va.z; As[lc4 + 3][lr] = va.w;
        Bs[lc4 + 0][lr] = vb.x; Bs[lc4 + 1][lr] = vb.y;
        Bs[lc4 + 2][lr] = vb.z; Bs[lc4 + 3][lr] = vb.w;
        __syncthreads();
        if (k0 + BK < K) {
            if (ma < M) va = *(const float4*)(A + (size_t)ma * lda + k0 + BK + lc4);
            if (nb < N) vb = *(const float4*)(W + (size_t)nb * ldw + k0 + BK + lc4);
        }
        #pragma unroll
        for (int kk = 0; kk < BK; ++kk) {
            float a[TM], bfr[TN];
            #pragma unroll
            for (int i = 0; i < TM; i += 4)
                *(float4*)&a[i] = *(const float4*)&As[kk][ty * TM + i];
            #pragma unroll
            for (int j = 0; j < TN; j += 4)
                *(float4*)&bfr[j] = *(const float4*)&Bs[kk][tx * TN + j];
            #pragma unroll
            for (int i = 0; i < TM; i++)
                #pragma unroll
                for (int j = 0; j < TN; j++) acc[i][j] = fmaf(a[i], bfr[j], acc[i][j]);
        }
    }
    #pragma unroll
    for (int i = 0; i < TM; i++) {
        int m = m0 + ty * TM + i;
        if (m >= M) continue;
        #pragma unroll
        for (int j = 0; j < TN; j++) {
            int n = n0 + tx * TN + j;
            if (n >= N) continue;
            float v = acc[i][j];
            if (bias) v += bias[n];
            if (act == 2) v = softplus_f(v);
            C[(size_t)m * ldc + n] = v;
        }
    }
}

// ---------------------------------------------------------------------------
// Depthwise conv1d (K=4, pad(1,2)) in [b,l,d], bf16 in -> bf16 out (xlb == u).
// ---------------------------------------------------------------------------
__global__ __launch_bounds__(256) void dwconv(
    const ushort* __restrict__ xib, const float* __restrict__ cw,
    const float* __restrict__ cb, ushort* __restrict__ xlb)
{
    int idx = blockIdx.x * 256 + threadIdx.x;   // 524288
    int d4 = (idx & 127) * 4;
    int bl = idx >> 7;
    int b = bl >> 10, l = bl & 1023;
    float4 w0 = *(const float4*)(cw + d4 * 4);
    float4 w1 = *(const float4*)(cw + d4 * 4 + 4);
    float4 w2 = *(const float4*)(cw + d4 * 4 + 8);
    float4 w3 = *(const float4*)(cw + d4 * 4 + 12);
    float4 acc = *(const float4*)(cb + d4);
    const ushort* rowb = xib + ((size_t)b << 19) + d4;
    #pragma unroll
    for (int k = 0; k < 4; ++k) {
        int ll = l + k - 1;
        if ((unsigned)ll < 1024u) {
            uint2 p = *(const uint2*)(rowb + (size_t)ll * 512);
            acc.x = fmaf(bf2f((ushort)(p.x & 0xffffu)), ((const float*)&w0)[k], acc.x);
            acc.y = fmaf(bf2f((ushort)(p.x >> 16)),     ((const float*)&w1)[k], acc.y);
            acc.z = fmaf(bf2f((ushort)(p.y & 0xffffu)), ((const float*)&w2)[k], acc.z);
            acc.w = fmaf(bf2f((ushort)(p.y >> 16)),     ((const float*)&w3)[k], acc.w);
        }
    }
    uint2 pk;
    pk.x = (uint)f2bf(acc.x) | ((uint)f2bf(acc.y) << 16);
    pk.y = (uint)f2bf(acc.z) | ((uint)f2bf(acc.w) << 16);
    *(uint2*)(xlb + (size_t)bl * 512 + d4) = pk;
}

// ---------------------------------------------------------------------------
// Chunked scan pass 1 (fused dt_proj, 4-step composition, fp32 LDS staging).
// 15 chunks of 64 timesteps (chunk 15's summary is never read): grid 960.
// dt_proj: xd as float4 broadcast, dpw_s stride 34 as float2 (2-way = free).
// ~34.5KB LDS -> 4 blocks/CU.
// ---------------------------------------------------------------------------
__global__ __launch_bounds__(512, 8) void scan_part1(
    const float* __restrict__ xdbl, const ushort* __restrict__ xlb,
    const float* __restrict__ dpw, const float* __restrict__ dpb,
    const float* __restrict__ alog,
    float* __restrict__ Psum, float* __restrict__ hFsum)
{
    __shared__ __align__(16) float Td[32][68];
    __shared__ __align__(16) float Tu[32][68];
    __shared__ __align__(16) float TB[16][68];
    __shared__ __align__(16) float xd[64][32];
    __shared__ __align__(16) float dpw_s[32][34];
    __shared__ float dpb_s[32];
    int t = threadIdx.x;
    int bid = blockIdx.x;                 // 960 = b(4) x dgG(16) x ch(15)
    int ch = bid % 15;
    int gq = bid / 15;
    int dgG = gq & 15, b = gq >> 4;
    int d0 = dgG * 32;
    int bl0 = b * 1024 + ch * 64;
    {   // xd: 64 l x 32 k, one float4/thread
        int l = t >> 3, k4 = (t & 7) * 4;
        float4 v = *(const float4*)(xdbl + (size_t)(bl0 + l) * 64 + k4);
        *(float4*)&xd[l][k4] = v;
    }
    if (t < 256) {   // Tu: 64 l x 32 d (bf16 -> fp32 at stage time)
        int l = t >> 2, d8 = (t & 3) * 8;
        uint4 p = *(const uint4*)(xlb + (size_t)(bl0 + l) * 512 + d0 + d8);
        Tu[d8 + 0][l] = bf2f((ushort)(p.x & 0xffffu));
        Tu[d8 + 1][l] = bf2f((ushort)(p.x >> 16));
        Tu[d8 + 2][l] = bf2f((ushort)(p.y & 0xffffu));
        Tu[d8 + 3][l] = bf2f((ushort)(p.y >> 16));
        Tu[d8 + 4][l] = bf2f((ushort)(p.z & 0xffffu));
        Tu[d8 + 5][l] = bf2f((ushort)(p.z >> 16));
        Tu[d8 + 6][l] = bf2f((ushort)(p.w & 0xffffu));
        Tu[d8 + 7][l] = bf2f((ushort)(p.w >> 16));
    } else {         // TB: 64 l x 16 n, fp32
        int tt = t - 256;
        int l = tt >> 2, n4 = (tt & 3) * 4;
        float4 bv = *(const float4*)(xdbl + (size_t)(bl0 + l) * 64 + 32 + n4);
        TB[n4 + 0][l] = bv.x; TB[n4 + 1][l] = bv.y;
        TB[n4 + 2][l] = bv.z; TB[n4 + 3][l] = bv.w;
    }
    #pragma unroll
    for (int r = 0; r < 2; ++r) {
        int idx = r * 512 + t;
        int dd = idx >> 5, kk = idx & 31;
        dpw_s[dd][kk] = dpw[(size_t)(d0 + dd) * 32 + kk];
    }
    if (t < 32) dpb_s[t] = dpb[d0 + t];
    __syncthreads();
    {   // fused dt_proj: 32 dd x 64 l, 4 entries/thread (vectorized reads)
        int dd = t & 31, lb = (t >> 5) * 4;
        #pragma unroll
        for (int j = 0; j < 4; ++j) {
            int l = lb + j;
            float s = dpb_s[dd];
            #pragma unroll
            for (int k4 = 0; k4 < 8; ++k4) {
                float4 xv = *(const float4*)&xd[l][k4 * 4];
                float2 wa = *(const float2*)&dpw_s[dd][k4 * 4];
                float2 wb = *(const float2*)&dpw_s[dd][k4 * 4 + 2];
                s = fmaf(xv.x, wa.x, s);
                s = fmaf(xv.y, wa.y, s);
                s = fmaf(xv.z, wb.x, s);
                s = fmaf(xv.w, wb.y, s);
            }
            Td[dd][l] = softplus_f(s);
        }
    }
    __syncthreads();
    int w = t >> 6, lane = t & 63;
    int dl = lane >> 4, n = lane & 15;
    int col = w * 4 + dl;
    int d = d0 + col;
    float Ac = -__expf(alog[d * 16 + n]);
    float h = 0.f, P = 1.f;
    for (int l4 = 0; l4 < 16; ++l4) {
        float4 de = *(const float4*)&Td[col][l4 * 4];
        float4 uu = *(const float4*)&Tu[col][l4 * 4];
        float4 Bv = *(const float4*)&TB[n][l4 * 4];
        float a1 = __expf(de.x * Ac), a2 = __expf(de.y * Ac);
        float a3 = __expf(de.z * Ac), a4 = __expf(de.w * Ac);
        float b1 = de.x * Bv.x * uu.x, b2 = de.y * Bv.y * uu.y;
        float b3 = de.z * Bv.z * uu.z, b4 = de.w * Bv.w * uu.w;
        float a21 = a2 * a1,     b21 = fmaf(a2, b1, b2);
        float a321 = a3 * a21,   b321 = fmaf(a3, b21, b3);
        float a4321 = a4 * a321, b4321 = fmaf(a4, b321, b4);
        h = fmaf(a4321, h, b4321);
        P *= a4321;
    }
    size_t si = ((size_t)(b * 128 + dgG * 8 + w) * 16 + ch) * 64 + lane;
    Psum[si] = P;
    hFsum[si] = h;
}

// ---------------------------------------------------------------------------
// Chunked scan pass 2 (fused dt_proj, 4-step composition, fp32 LDS staging,
// DPP row_shr n-reduction, packed yb2, xd overlaid on TB/TC/yb2 union,
// masked-unrolled chunk-prefix loads). ~34.5KB LDS -> 4 blocks/CU.
// ---------------------------------------------------------------------------
__global__ __launch_bounds__(512, 8) void scan_part2(
    const float* __restrict__ xdbl, const ushort* __restrict__ xlb,
    const float* __restrict__ dpw, const float* __restrict__ dpb,
    const float* __restrict__ alog, const float* __restrict__ dssm,
    const ushort* __restrict__ resb, ushort* __restrict__ ybb,
    const float* __restrict__ Psum, const float* __restrict__ hFsum)
{
    __shared__ __align__(16) float Td[32][68];
    __shared__ __align__(16) float Tu[32][68];
    // union: xd fp32[64][32] (8192B) overlays TB(4352)+TC(4352)+yb2(4224)=12928B
    __shared__ __align__(16) unsigned char uni[12928];
    __shared__ __align__(16) float dpw_s[32][34];
    __shared__ float dpb_s[32];
    float* xd = (float*)uni;                          // [64][32]
    float (*TB)[68] = (float(*)[68])uni;              // [16][68]
    float (*TC)[68] = (float(*)[68])(uni + 4352);     // [16][68]
    uint (*yb2)[33] = (uint(*)[33])(uni + 8704);      // [32][33]
    int t = threadIdx.x;
    int bid = blockIdx.x;                 // 1024 = b(4) x dgG(16) x ch(16)
    int ch = bid & 15, dgG = (bid >> 4) & 15, b = bid >> 8;
    int d0 = dgG * 32;
    int bl0 = b * 1024 + ch * 64;
    {   // xd into union
        int l = t >> 3, k4 = (t & 7) * 4;
        float4 v = *(const float4*)(xdbl + (size_t)(bl0 + l) * 64 + k4);
        *(float4*)&xd[l * 32 + k4] = v;
    }
    if (t < 256) {   // Tu (bf16 -> fp32 at stage time)
        int l = t >> 2, d8 = (t & 3) * 8;
        uint4 p = *(const uint4*)(xlb + (size_t)(bl0 + l) * 512 + d0 + d8);
        Tu[d8 + 0][l] = bf2f((ushort)(p.x & 0xffffu));
        Tu[d8 + 1][l] = bf2f((ushort)(p.x >> 16));
        Tu[d8 + 2][l] = bf2f((ushort)(p.y & 0xffffu));
        Tu[d8 + 3][l] = bf2f((ushort)(p.y >> 16));
        Tu[d8 + 4][l] = bf2f((ushort)(p.z & 0xffffu));
        Tu[d8 + 5][l] = bf2f((ushort)(p.z >> 16));
        Tu[d8 + 6][l] = bf2f((ushort)(p.w & 0xffffu));
        Tu[d8 + 7][l] = bf2f((ushort)(p.w >> 16));
    }
    #pragma unroll
    for (int r = 0; r < 2; ++r) {
        int idx = r * 512 + t;
        int dd = idx >> 5, kk = idx & 31;
        dpw_s[dd][kk] = dpw[(size_t)(d0 + dd) * 32 + kk];
    }
    if (t < 32) dpb_s[t] = dpb[d0 + t];
    __syncthreads();
    {   // fused dt_proj (reads xd, vectorized)
        int dd = t & 31, lb = (t >> 5) * 4;
        #pragma unroll
        for (int j = 0; j < 4; ++j) {
            int l = lb + j;
            float s = dpb_s[dd];
            #pragma unroll
            for (int k4 = 0; k4 < 8; ++k4) {
                float4 xv = *(const float4*)&xd[l * 32 + k4 * 4];
                float2 wa = *(const float2*)&dpw_s[dd][k4 * 4];
                float2 wb = *(const float2*)&dpw_s[dd][k4 * 4 + 2];
                s = fmaf(xv.x, wa.x, s);
                s = fmaf(xv.y, wa.y, s);
                s = fmaf(xv.z, wb.x, s);
                s = fmaf(xv.w, wb.y, s);
            }
            Td[dd][l] = softplus_f(s);
        }
    }
    __syncthreads();   // xd dead; Td visible
    if (t < 256) {     // TB/TC over dead xd, fp32
        int l = t >> 2, n4 = (t & 3) * 4;
        float4 bv = *(const float4*)(xdbl + (size_t)(bl0 + l) * 64 + 32 + n4);
        float4 cv = *(const float4*)(xdbl + (size_t)(bl0 + l) * 64 + 48 + n4);
        TB[n4 + 0][l] = bv.x; TB[n4 + 1][l] = bv.y;
        TB[n4 + 2][l] = bv.z; TB[n4 + 3][l] = bv.w;
        TC[n4 + 0][l] = cv.x; TC[n4 + 1][l] = cv.y;
        TC[n4 + 2][l] = cv.z; TC[n4 + 3][l] = cv.w;
    }
    int w = t >> 6, lane = t & 63;
    int dl = lane >> 4, n = lane & 15;
    int col = w * 4 + dl;
    int d = d0 + col;
    float Ac = -__expf(alog[d * 16 + n]);
    float Dd = dssm[d];
    float h = 0.f;
    {   // chunk-prefix: fully unrolled, masked -> all loads issue in parallel
        size_t sbase = (size_t)(b * 128 + dgG * 8 + w) * 1024 + lane;
        #pragma unroll
        for (int cc = 0; cc < 15; ++cc) {
            float Pv = Psum[sbase + (size_t)cc * 64];
            float hv = hFsum[sbase + (size_t)cc * 64];
            bool use = cc < ch;
            Pv = use ? Pv : 1.f;
            hv = use ? hv : 0.f;
            h = fmaf(Pv, h, hv);
        }
    }
    __syncthreads();   // TB/TC visible
    for (int l4 = 0; l4 < 16; ++l4) {
        float4 de = *(const float4*)&Td[col][l4 * 4];
        float4 uu = *(const float4*)&Tu[col][l4 * 4];
        float4 Bv = *(const float4*)&TB[n][l4 * 4];
        float4 Cv = *(const float4*)&TC[n][l4 * 4];
        float a1 = __expf(de.x * Ac), a2 = __expf(de.y * Ac);
        float a3 = __expf(de.z * Ac), a4 = __expf(de.w * Ac);
        float b1 = de.x * Bv.x * uu.x, b2 = de.y * Bv.y * uu.y;
        float b3 = de.z * Bv.z * uu.z, b4 = de.w * Bv.w * uu.w;
        float a21 = a2 * a1,     b21 = fmaf(a2, b1, b2);
        float a321 = a3 * a21,   b321 = fmaf(a3, b21, b3);
        float a4321 = a4 * a321, b4321 = fmaf(a4, b321, b4);
        float h1 = fmaf(a1, h, b1);
        float h2 = fmaf(a21, h, b21);
        float h3 = fmaf(a321, h, b321);
        float h4 = fmaf(a4321, h, b4321);
        h = h4;
        float p0 = h1 * Cv.x, p1 = h2 * Cv.y, p2 = h3 * Cv.z, p3 = h4 * Cv.w;
        // 16-lane n-reduction via DPP row_shr: sum lands in lane n==15.
        DPP_ROW_SHR_ADD(p0, 1); DPP_ROW_SHR_ADD(p0, 2);
        DPP_ROW_SHR_ADD(p0, 4); DPP_ROW_SHR_ADD(p0, 8);
        DPP_ROW_SHR_ADD(p1, 1); DPP_ROW_SHR_ADD(p1, 2);
        DPP_ROW_SHR_ADD(p1, 4); DPP_ROW_SHR_ADD(p1, 8);
        DPP_ROW_SHR_ADD(p2, 1); DPP_ROW_SHR_ADD(p2, 2);
        DPP_ROW_SHR_ADD(p2, 4); DPP_ROW_SHR_ADD(p2, 8);
        DPP_ROW_SHR_ADD(p3, 1); DPP_ROW_SHR_ADD(p3, 2);
        DPP_ROW_SHR_ADD(p3, 4); DPP_ROW_SHR_ADD(p3, 8);
        if (n == 15) {
            int l2 = l4 * 2;
            float y0 = fmaf(uu.x, Dd, p0), y1 = fmaf(uu.y, Dd, p1);
            float y2 = fmaf(uu.z, Dd, p2), y3 = fmaf(uu.w, Dd, p3);
            yb2[l2 + 0][col] = (uint)f2bf(y0) | ((uint)f2bf(y1) << 16);
            yb2[l2 + 1][col] = (uint)f2bf(y2) | ((uint)f2bf(y3) << 16);
        }
    }
    __syncthreads();
    // gated store: 32 l2 x 32 col = 1024 items over 512 threads x 2
    size_t base = ((size_t)(b * 1024 + ch * 64)) * 512 + d0;   // ushort offset
    #pragma unroll
    for (int j = 0; j < 2; ++j) {
        int idx = j * 512 + t;
        int l2 = idx >> 5, col2 = idx & 31;
        uint yv = yb2[l2][col2];
        int l0 = l2 * 2;
        float r0 = bf2f(resb[base + (size_t)l0 * 512 + col2]);
        float r1 = bf2f(resb[base + (size_t)(l0 + 1) * 512 + col2]);
        float y0 = bf2f((ushort)(yv & 0xffffu)) * r0;
        float y1 = bf2f((ushort)(yv >> 16)) * r1;
        ybb[base + (size_t)l0 * 512 + col2] = f2bf(y0);
        ybb[base + (size_t)(l0 + 1) * 512 + col2] = f2bf(y1);
    }
}

// s[row] = LN(o[row])*g + b + s[row]; also writes bf16 copy sb. One wave/row.
__global__ __launch_bounds__(256) void ln_res_kernel(
    const float* __restrict__ o, const float* __restrict__ g,
    const float* __restrict__ bb, float* __restrict__ s, ushort* __restrict__ sb)
{
    int row = blockIdx.x * 4 + (threadIdx.x >> 6);
    int lane = threadIdx.x & 63;
    const float4* orow = (const float4*)(o + (size_t)row * 256);
    float4 v = orow[lane];
    float sum = v.x + v.y + v.z + v.w;
    float sq = v.x * v.x + v.y * v.y + v.z * v.z + v.w * v.w;
    #pragma unroll
    for (int off = 1; off < 64; off <<= 1) {
        sum += __shfl_xor(sum, off);
        sq += __shfl_xor(sq, off);
    }
    float m = sum * (1.f / 256.f);
    float var = sq * (1.f / 256.f) - m * m;
    float rstd = rsqrtf(var + 1e-5f);
    float4 gg = ((const float4*)g)[lane];
    float4 bv = ((const float4*)bb)[lane];
    float4* srow = (float4*)(s + (size_t)row * 256);
    float4 sv = srow[lane];
    sv.x += (v.x - m) * rstd * gg.x + bv.x;
    sv.y += (v.y - m) * rstd * gg.y + bv.y;
    sv.z += (v.z - m) * rstd * gg.z + bv.z;
    sv.w += (v.w - m) * rstd * gg.w + bv.w;
    srow[lane] = sv;
    uint2 pk;
    pk.x = (uint)f2bf(sv.x) | ((uint)f2bf(sv.y) << 16);
    pk.y = (uint)f2bf(sv.z) | ((uint)f2bf(sv.w) << 16);
    *(uint2*)(sb + (size_t)row * 256 + lane * 4) = pk;
}

// mean over l then LN over 256 channels. grid 4 x 256.
__global__ __launch_bounds__(256) void pool_ln_kernel(
    const float* __restrict__ s, const float* __restrict__ nw,
    const float* __restrict__ nb, float* __restrict__ sln)
{
    int b = blockIdx.x, c = threadIdx.x;
    const float* p = s + (size_t)b * 262144 + c;
    float acc = 0.f;
    for (int l = 0; l < 1024; ++l) acc += p[(size_t)l * 256];
    float pooled = acc * (1.f / 1024.f);
    __shared__ float rs[4], rq[4];
    float sum = pooled, sq = pooled * pooled;
    #pragma unroll
    for (int off = 1; off < 64; off <<= 1) {
        sum += __shfl_xor(sum, off);
        sq += __shfl_xor(sq, off);
    }
    int w = threadIdx.x >> 6;
    if ((threadIdx.x & 63) == 0) { rs[w] = sum; rq[w] = sq; }
    __syncthreads();
    sum = rs[0] + rs[1] + rs[2] + rs[3];
    sq = rq[0] + rq[1] + rq[2] + rq[3];
    float m = sum * (1.f / 256.f);
    float var = sq * (1.f / 256.f) - m * m;
    float rstd = rsqrtf(var + 1e-5f);
    sln[b * 256 + c] = (pooled - m) * rstd * nw[c] + nb[c];
}

// softmax over 1000 logits per b
__global__ __launch_bounds__(256) void softmax_kernel(float* __restrict__ out)
{
    int b = threadIdx.x >> 6, lane = threadIdx.x & 63;
    const float* lg = out + b * 1000;
    float v[16];
    float mx = -1e30f;
    #pragma unroll
    for (int j = 0; j < 16; ++j) {
        int i = lane + j * 64;
        v[j] = (i < 1000) ? lg[i] : -1e30f;
        mx = fmaxf(mx, v[j]);
    }
    #pragma unroll
    for (int off = 1; off < 64; off <<= 1) mx = fmaxf(mx, __shfl_xor(mx, off));
    float sum = 0.f;
    #pragma unroll
    for (int j = 0; j < 16; ++j) {
        int i = lane + j * 64;
        if (i < 1000) { v[j] = __expf(v[j] - mx); sum += v[j]; }
    }
    #pragma unroll
    for (int off = 1; off < 64; off <<= 1) sum += __shfl_xor(sum, off);
    float inv = 1.f / sum;
    float* so = out + 4000 + b * 1000;
    #pragma unroll
    for (int j = 0; j < 16; ++j) {
        int i = lane + j * 64;
        if (i < 1000) so[i] = v[j] * inv;
    }
}

// ---------------------------------------------------------------------------
extern "C" void kernel_launch(void* const* d_in, const int* in_sizes, int n_in,
                              void* d_out, int out_size, void* d_ws, size_t ws_size,
                              hipStream_t stream)
{
    const float* x    = (const float*)d_in[0];
    const float* c1w  = (const float*)d_in[1];
    const float* c1b  = (const float*)d_in[2];
    const float* g1   = (const float*)d_in[3];
    const float* b1   = (const float*)d_in[4];
    const float* c2w  = (const float*)d_in[5];
    const float* c2b  = (const float*)d_in[6];
    const float* g2   = (const float*)d_in[7];
    const float* b2   = (const float*)d_in[8];
    const float* pw   = (const float*)d_in[9];
    const float* pb   = (const float*)d_in[10];
    const float* g3   = (const float*)d_in[11];
    const float* b3   = (const float*)d_in[12];
    const float* ipw  = (const float*)d_in[13];
    const float* ipb  = (const float*)d_in[14];
    const float* cw   = (const float*)d_in[15];
    const float* cb   = (const float*)d_in[16];
    const float* xpw  = (const float*)d_in[17];
    const float* dpw  = (const float*)d_in[18];
    const float* dpb  = (const float*)d_in[19];
    const float* alog = (const float*)d_in[20];
    const float* dssm = (const float*)d_in[21];
    const float* opw  = (const float*)d_in[22];
    const float* opb  = (const float*)d_in[23];
    const float* lnw  = (const float*)d_in[24];
    const float* lnb  = (const float*)d_in[25];
    const float* nw   = (const float*)d_in[26];
    const float* nb   = (const float*)d_in[27];
    const float* fcw  = (const float*)d_in[28];
    const float* fcb  = (const float*)d_in[29];
    float* out = (float*)d_out;
    float* wsf = (float*)d_ws;

    float*  s_   = wsf;
    ushort* sb   = (ushort*)(wsf + 1048576);
    ushort* xib  = (ushort*)(wsf + 1572864);
    float*  obuf = wsf + 1572864;
    ushort* resb = (ushort*)(wsf + 3670016);
    ushort* xlb  = (ushort*)(wsf + 4718592);   // == u == ybb (in-place gate)
    ushort* ybb  = (ushort*)(wsf + 4718592);
    ushort* h1b  = (ushort*)(wsf + 4718592);
    ushort* Apb  = (ushort*)(wsf + 6815744);
    float*  xdbl = wsf + 8912896;
    ushort* ipwb = (ushort*)(wsf + 9175040);
    ushort* opwb = (ushort*)(wsf + 9699328);
    ushort* w2b  = (ushort*)(wsf + 9961472);
    ushort* pwTb = (ushort*)(wsf + 10108928);
    float*  sln  = wsf + 10240000;
    float*  Psum = wsf + 10241024;             // [4][128][16][64] = 524288 fl
    float*  hFsum= wsf + 10765312;             // 524288 fl
    ushort* xpwb = (ushort*)(wsf + 11289600);  // 131072 ushorts; end 11355136 fl

    // --- fused weight prep (1 dispatch) ---
    hipLaunchKernelGGL(wprep, dim3(8832), dim3(256), 0, stream,
                       ipw, opw, c2w, pw, xpw, ipwb, opwb, w2b, pwTb, xpwb);

    // --- conv stem ---
    hipLaunchKernelGGL(conv1_nhwc, dim3(256), dim3(256), 0, stream, x, c1w, c1b, g1, b1, h1b);
    hipLaunchKernelGGL(conv2_mfma, dim3(128, 4), dim3(256), 0, stream, h1b, w2b, c2b, g2, b2, Apb);
    hipLaunchKernelGGL((mfma_gemm_bt<64, 64, 2>), dim3(64, 4), dim3(256), 0, stream,
                       Apb, 1024, pwTb, 1024, pb, g3, b3, s_, sb, nullptr, 256, 1024);

    // --- mamba blocks ---
    for (int i = 0; i < 4; ++i) {
        const ushort* ipwb_i = ipwb + (size_t)i * 1024 * 256;
        const float*  ipb_i  = ipb + i * 1024;
        const float*  cw_i   = cw + i * 512 * 4;
        const float*  cb_i   = cb + i * 512;
        const ushort* xpwb_i = xpwb + (size_t)i * 64 * 512;
        const float*  dpw_i  = dpw + (size_t)i * 512 * 32;
        const float*  dpb_i  = dpb + i * 512;
        const float*  alog_i = alog + (size_t)i * 512 * 16;
        const float*  dssm_i = dssm + i * 512;
        const ushort* opwb_i = opwb + (size_t)i * 256 * 512;
        const float*  opb_i  = opb + i * 256;
        const float*  lnw_i  = lnw + i * 256;
        const float*  lnb_i  = lnb + i * 256;

        hipLaunchKernelGGL((mfma_gemm_bt<64, 128, 3>), dim3(64, 8), dim3(256), 0, stream,
                           sb, 256, ipwb_i, 256, ipb_i, nullptr, nullptr,
                           nullptr, xib, resb, 0, 256);
        hipLaunchKernelGGL(dwconv, dim3(2048), dim3(256), 0, stream, xib, cw_i, cb_i, xlb);
        hipLaunchKernelGGL((mfma_gemm_bt<64, 64, 0>), dim3(64, 1), dim3(256), 0, stream,
                           xlb, 512, xpwb_i, 512, nullptr, nullptr, nullptr,
                           xdbl, nullptr, nullptr, 64, 512);
        hipLaunchKernelGGL(scan_part1, dim3(960), dim3(512), 0, stream,
                           xdbl, xlb, dpw_i, dpb_i, alog_i, Psum, hFsum);
        hipLaunchKernelGGL(scan_part2, dim3(1024), dim3(512), 0, stream,
                           xdbl, xlb, dpw_i, dpb_i, alog_i, dssm_i, resb, ybb, Psum, hFsum);
        hipLaunchKernelGGL((mfma_gemm_bt<64, 64, 0>), dim3(64, 4), dim3(256), 0, stream,
                           ybb, 512, opwb_i, 512, opb_i, nullptr, nullptr,
                           obuf, nullptr, nullptr, 256, 512);
        hipLaunchKernelGGL(ln_res_kernel, dim3(1024), dim3(256), 0, stream,
                           obuf, lnw_i, lnb_i, s_, sb);
    }

    // --- head ---
    hipLaunchKernelGGL(pool_ln_kernel, dim3(4), dim3(256), 0, stream, s_, nw, nb, sln);
    hipLaunchKernelGGL((gemm_kernel<64, 64, 16, 4, 4>), dim3(1, 16), dim3(256), 0, stream,
                       sln, 256, fcw, 256, fcb, out, 1000, 4, 1000, 256, 0);
    hipLaunchKernelGGL(softmax_kernel, dim3(1), dim3(256), 0, stream, out);
}

// Round 10
// 576.916 us; speedup vs baseline: 1.2282x; 1.0034x over previous
//
#include <hip/hip_runtime.h>
#include <math.h>

// ---------------------------------------------------------------------------
// FastImageMamba forward. R23: R22 (verified 578.9us) + pool_ln split into
// pool_partial (grid 128, coalesced 32-row sums -> partial[4][32][256]) and
// pool_ln_final (grid 4, 32 partial sums + LN). The old pool_ln was a
// 4-block kernel streaming 4MB serially (~35-40us exposed, occ 0.014%).
// B=4, DM=256, NL=4, NC=1000, DI=512, NS=16, DTR=32, K=4, L=1024, H=W=64
// ---------------------------------------------------------------------------

#define BN_RSQ 0.99999500003749969f   // 1/sqrt(1+1e-5)

typedef unsigned int uint;
typedef unsigned short ushort;
typedef __bf16 bf16x8 __attribute__((ext_vector_type(8)));
typedef float floatx4 __attribute__((ext_vector_type(4)));

__device__ __forceinline__ float gelu_f(float v) {
    return 0.5f * v * (1.0f + erff(v * 0.70710678118654752f));
}
__device__ __forceinline__ float softplus_f(float v) {
    return (v > 20.f) ? v : log1pf(expf(v));
}
__device__ __forceinline__ ushort f2bf(float f) {
    uint x = __float_as_uint(f);
    x += 0x7fffu + ((x >> 16) & 1u);
    return (ushort)(x >> 16);
}
__device__ __forceinline__ float bf2f(ushort u) {
    return __uint_as_float((uint)u << 16);
}

// DPP row_shr:N add step: after N=1,2,4,8 lane 15 of each 16-lane row holds
// the row sum (bound_ctrl=1 -> out-of-row sources read 0).
#define DPP_ROW_SHR_ADD(x, N)                                               \
    x += __int_as_float(__builtin_amdgcn_update_dpp(                        \
        0, __float_as_int(x), 0x110 + (N), 0xf, 0xf, true))

// ---------------------------------------------------------------------------
// Fused weight prep: all fp32->bf16 weight conversions in one dispatch.
// ---------------------------------------------------------------------------
__global__ void wprep(const float* __restrict__ ipw, const float* __restrict__ opw,
                      const float* __restrict__ c2w, const float* __restrict__ pw,
                      const float* __restrict__ xpw,
                      ushort* __restrict__ ipwb, ushort* __restrict__ opwb,
                      ushort* __restrict__ w2b, ushort* __restrict__ pwTb,
                      ushort* __restrict__ xpwb)
{
    int idx = blockIdx.x * 256 + threadIdx.x;
    if (idx < 1048576) {
        ipwb[idx] = f2bf(ipw[idx]);
    } else if (idx < 1572864) {
        int i = idx - 1048576;
        opwb[i] = f2bf(opw[i]);
    } else if (idx < 1867776) {
        int i = idx - 1572864;
        int oc = i / 1152, k = i % 1152;
        int s = k >> 7, ic = k & 127;
        w2b[i] = f2bf(c2w[(size_t)(oc * 128 + ic) * 9 + s]);
    } else if (idx < 2129920) {
        int i = idx - 1867776;
        int oc = i >> 10, k = i & 1023;
        int s = k >> 8, ic = k & 255;
        int ky = s >> 1, kx = s & 1;
        pwTb[i] = f2bf(pw[((size_t)(oc * 256 + ic) * 2 + ky) * 2 + kx]);
    } else if (idx < 2260992) {
        int i = idx - 2129920;
        xpwb[i] = f2bf(xpw[i]);
    }
}

// ---------------------------------------------------------------------------
// conv1: 3x3 s1p1, IC=3 -> OC=128, NCHW fp32 in, NHWC bf16 out (+bias+BN+GELU)
// ---------------------------------------------------------------------------
__global__ __launch_bounds__(256) void conv1_nhwc(
    const float* __restrict__ x, const float* __restrict__ w,
    const float* __restrict__ cb, const float* __restrict__ g,
    const float* __restrict__ bb, ushort* __restrict__ out)
{
    __shared__ float tin[3][3][64];
    __shared__ float ws[3456];
    int t = threadIdx.x;
    int b = blockIdx.x >> 6, y = blockIdx.x & 63;
    for (int i = t; i < 3456; i += 256) ws[i] = w[i];
    for (int i = t; i < 576; i += 256) {
        int ic = i / 192, r = (i >> 6) % 3, xx = i & 63;
        int gy = y + r - 1;
        tin[ic][r][xx] = ((unsigned)gy < 64u) ? x[((b * 3 + ic) * 64 + gy) * 64 + xx] : 0.f;
    }
    __syncthreads();
    int tx = t & 15, ty = t >> 4;
    int oc0 = tx * 8, px0 = ty * 4;
    float acc[4][8];
    #pragma unroll
    for (int p = 0; p < 4; ++p)
        #pragma unroll
        for (int o = 0; o < 8; ++o) acc[p][o] = 0.f;
    for (int ic = 0; ic < 3; ++ic)
        #pragma unroll
        for (int ky = 0; ky < 3; ++ky)
            #pragma unroll
            for (int kx = 0; kx < 3; ++kx) {
                float av[4];
                #pragma unroll
                for (int p = 0; p < 4; ++p) {
                    int xx = px0 + p + kx - 1;
                    av[p] = ((unsigned)xx < 64u) ? tin[ic][ky][xx] : 0.f;
                }
                #pragma unroll
                for (int o = 0; o < 8; ++o) {
                    float wv = ws[(oc0 + o) * 27 + ic * 9 + ky * 3 + kx];
                    #pragma unroll
                    for (int p = 0; p < 4; ++p) acc[p][o] = fmaf(av[p], wv, acc[p][o]);
                }
            }
    #pragma unroll
    for (int p = 0; p < 4; ++p) {
        uint pk[4];
        #pragma unroll
        for (int o2 = 0; o2 < 4; ++o2) {
            int oc = oc0 + o2 * 2;
            float v0 = gelu_f((acc[p][o2 * 2] + cb[oc]) * (g[oc] * BN_RSQ) + bb[oc]);
            float v1 = gelu_f((acc[p][o2 * 2 + 1] + cb[oc + 1]) * (g[oc + 1] * BN_RSQ) + bb[oc + 1]);
            pk[o2] = (uint)f2bf(v0) | ((uint)f2bf(v1) << 16);
        }
        uint4 vv = make_uint4(pk[0], pk[1], pk[2], pk[3]);
        *(uint4*)(out + ((size_t)((b * 64 + y) * 64 + px0 + p)) * 128 + oc0) = vv;
    }
}

// ---------------------------------------------------------------------------
// bf16 MFMA GEMM (A @ W^T), BMxBN tile, BK=32, 4 waves (2x2), reg dbuf.
// EPI: 0 = +bias -> fp32 Cf[ldc]
//      2 = +bias,BN,GELU -> fp32 Cf + bf16 Cb (same ldc)
//      3 = in_proj: n<512 -> bf16 Cb[m*512+n]; n>=512 -> bf16 silu -> Cb2
// ---------------------------------------------------------------------------
template<int BM, int BN, int EPI>
__global__ __launch_bounds__(256, 2) void mfma_gemm_bt(
    const ushort* __restrict__ A, int lda,
    const ushort* __restrict__ W, int ldw,
    const float* __restrict__ bias,
    const float* __restrict__ bnG, const float* __restrict__ bnB,
    float* __restrict__ Cf, ushort* __restrict__ Cb, ushort* __restrict__ Cb2,
    int ldc, int K)
{
    constexpr int PAD = 40;
    constexpr int AP = BM / 64;
    constexpr int BP = BN / 64;
    constexpr int FM = BM / 32;
    constexpr int FN = BN / 32;
    __shared__ __align__(16) ushort As[BM * PAD];
    __shared__ __align__(16) ushort Bs[BN * PAD];
    int t = threadIdx.x;
    int m0 = blockIdx.x * BM, n0 = blockIdx.y * BN;
    int lane = t & 63, wid = t >> 6;
    int wm = (wid & 1) * (BM / 2), wn = (wid >> 1) * (BN / 2);
    int fr = lane & 15, fk = (lane >> 4) * 8;
    int r0 = t >> 2, c0 = (t & 3) * 8;
    floatx4 acc[FM][FN];
    #pragma unroll
    for (int i = 0; i < FM; ++i)
        #pragma unroll
        for (int j = 0; j < FN; ++j) acc[i][j] = {0.f, 0.f, 0.f, 0.f};
    uint4 ra[AP], rb[BP];
    #pragma unroll
    for (int p = 0; p < AP; ++p)
        ra[p] = *(const uint4*)(A + (size_t)(m0 + r0 + p * 64) * lda + c0);
    #pragma unroll
    for (int p = 0; p < BP; ++p)
        rb[p] = *(const uint4*)(W + (size_t)(n0 + r0 + p * 64) * ldw + c0);
    for (int k0 = 0; k0 < K; k0 += 32) {
        __syncthreads();
        #pragma unroll
        for (int p = 0; p < AP; ++p) *(uint4*)&As[(r0 + p * 64) * PAD + c0] = ra[p];
        #pragma unroll
        for (int p = 0; p < BP; ++p) *(uint4*)&Bs[(r0 + p * 64) * PAD + c0] = rb[p];
        __syncthreads();
        if (k0 + 32 < K) {
            #pragma unroll
            for (int p = 0; p < AP; ++p)
                ra[p] = *(const uint4*)(A + (size_t)(m0 + r0 + p * 64) * lda + k0 + 32 + c0);
            #pragma unroll
            for (int p = 0; p < BP; ++p)
                rb[p] = *(const uint4*)(W + (size_t)(n0 + r0 + p * 64) * ldw + k0 + 32 + c0);
        }
        bf16x8 af[FM], bw[FN];
        #pragma unroll
        for (int i = 0; i < FM; ++i)
            af[i] = *(const bf16x8*)&As[(wm + i * 16 + fr) * PAD + fk];
        #pragma unroll
        for (int j = 0; j < FN; ++j)
            bw[j] = *(const bf16x8*)&Bs[(wn + j * 16 + fr) * PAD + fk];
        #pragma unroll
        for (int i = 0; i < FM; ++i)
            #pragma unroll
            for (int j = 0; j < FN; ++j)
                acc[i][j] = __builtin_amdgcn_mfma_f32_16x16x32_bf16(af[i], bw[j], acc[i][j], 0, 0, 0);
    }
    int rbase = (lane >> 4) * 4, cc = lane & 15;
    #pragma unroll
    for (int j = 0; j < FN; ++j) {
        int n = n0 + wn + j * 16 + cc;
        float bv = bias ? bias[n] : 0.f;
        float scl = 0.f, shf = 0.f;
        if (EPI == 2) { scl = bnG[n] * BN_RSQ; shf = bnB[n]; }
        #pragma unroll
        for (int i = 0; i < FM; ++i) {
            #pragma unroll
            for (int r = 0; r < 4; ++r) {
                int m = m0 + wm + i * 16 + rbase + r;
                float v = acc[i][j][r] + bv;
                if (EPI == 2) v = gelu_f(v * scl + shf);
                if (EPI == 0) {
                    Cf[(size_t)m * ldc + n] = v;
                } else if (EPI == 2) {
                    Cf[(size_t)m * ldc + n] = v;
                    Cb[(size_t)m * ldc + n] = f2bf(v);
                } else {
                    if (n < 512) Cb[(size_t)m * 512 + n] = f2bf(v);
                    else Cb2[(size_t)m * 512 + (n - 512)] = f2bf(v / (1.f + __expf(-v)));
                }
            }
        }
    }
}

// ---------------------------------------------------------------------------
// conv2: 9-shift implicit MFMA GEMM, 128px x 64oc tile, BK=64 (18 steps),
// reg dbuf with EXPLICIT SCALAR uint4s (array-by-ref spills to scratch).
// Writes DIRECTLY in im2col/Apb layout (im2col kernel deleted).
// ---------------------------------------------------------------------------
#define C2_LOAD(step)                                                            \
    {                                                                            \
        int s_ = (step) >> 1, ich_ = ((step) & 1) * 64;                          \
        int ky_ = s_ / 3, kx_ = s_ % 3;                                          \
        int sy_ = y0 + (ra_row >> 6) + ky_ - 1;                                  \
        int sx_ = (ra_row & 63) + kx_ - 1;                                       \
        bool v_ = ((unsigned)sy_ < 64u) && ((unsigned)sx_ < 64u);                \
        const ushort* ap_ = hb + ((size_t)(sy_ * 64 + sx_)) * 128 + ich_ + ra_c; \
        uint4 zz_ = make_uint4(0u, 0u, 0u, 0u);                                  \
        ra0 = v_ ? *(const uint4*)(ap_ + 0)  : zz_;                              \
        ra1 = v_ ? *(const uint4*)(ap_ + 8)  : zz_;                              \
        ra2 = v_ ? *(const uint4*)(ap_ + 16) : zz_;                              \
        ra3 = v_ ? *(const uint4*)(ap_ + 24) : zz_;                              \
        const ushort* wp_ = w2b + (size_t)(n0 + rb_row) * 1152 + s_ * 128 + ich_ + rb_c; \
        rb0 = *(const uint4*)(wp_ + 0);                                          \
        rb1 = *(const uint4*)(wp_ + 8);                                          \
    }

__global__ __launch_bounds__(256, 2) void conv2_mfma(
    const ushort* __restrict__ h1b, const ushort* __restrict__ w2b,
    const float* __restrict__ cb, const float* __restrict__ g,
    const float* __restrict__ bb, ushort* __restrict__ Apb)
{
    constexpr int PAD = 72;
    __shared__ __align__(16) ushort As[128 * PAD];
    __shared__ __align__(16) ushort Bs[64 * PAD];
    int t = threadIdx.x;
    int m0 = blockIdx.x * 128, n0 = blockIdx.y * 64;
    int b = m0 >> 12;
    int y0 = (m0 & 4095) >> 6;
    int lane = t & 63, wid = t >> 6;
    int wm = (wid & 1) * 64, wn = (wid >> 1) * 32;
    int fr = lane & 15, fk = (lane >> 4) * 8;
    int ra_row = t >> 1, ra_c = (t & 1) * 32;
    int rb_row = t >> 2, rb_c = (t & 3) * 16;
    floatx4 acc[4][2];
    #pragma unroll
    for (int i = 0; i < 4; ++i)
        #pragma unroll
        for (int j = 0; j < 2; ++j) acc[i][j] = {0.f, 0.f, 0.f, 0.f};
    const ushort* hb = h1b + (size_t)b * 4096 * 128;

    uint4 ra0, ra1, ra2, ra3, rb0, rb1;
    C2_LOAD(0);
    for (int step = 0; step < 18; ++step) {
        __syncthreads();
        *(uint4*)&As[ra_row * PAD + ra_c + 0]  = ra0;
        *(uint4*)&As[ra_row * PAD + ra_c + 8]  = ra1;
        *(uint4*)&As[ra_row * PAD + ra_c + 16] = ra2;
        *(uint4*)&As[ra_row * PAD + ra_c + 24] = ra3;
        *(uint4*)&Bs[rb_row * PAD + rb_c + 0]  = rb0;
        *(uint4*)&Bs[rb_row * PAD + rb_c + 8]  = rb1;
        __syncthreads();
        if (step + 1 < 18) C2_LOAD(step + 1);
        #pragma unroll
        for (int ks = 0; ks < 64; ks += 32) {
            bf16x8 af[4], bw[2];
            #pragma unroll
            for (int i = 0; i < 4; ++i)
                af[i] = *(const bf16x8*)&As[(wm + i * 16 + fr) * PAD + ks + fk];
            #pragma unroll
            for (int j = 0; j < 2; ++j)
                bw[j] = *(const bf16x8*)&Bs[(wn + j * 16 + fr) * PAD + ks + fk];
            #pragma unroll
            for (int i = 0; i < 4; ++i)
                #pragma unroll
                for (int j = 0; j < 2; ++j)
                    acc[i][j] = __builtin_amdgcn_mfma_f32_16x16x32_bf16(af[i], bw[j], acc[i][j], 0, 0, 0);
        }
    }
    int rbase = (lane >> 4) * 4, cc = lane & 15;
    #pragma unroll
    for (int j = 0; j < 2; ++j) {
        int n = n0 + wn + j * 16 + cc;
        float scl = g[n] * BN_RSQ, shf = bb[n], bv2 = cb[n];
        #pragma unroll
        for (int i = 0; i < 4; ++i) {
            #pragma unroll
            for (int r = 0; r < 4; ++r) {
                int m = m0 + wm + i * 16 + rbase + r;   // b*4096 + y*64 + x
                float v = gelu_f((acc[i][j][r] + bv2) * scl + shf);
                int yy = (m >> 6) & 63, xx = m & 63;
                int arow = (m >> 12) * 1024 + (yy >> 1) * 32 + (xx >> 1);
                int acol = ((yy & 1) * 2 + (xx & 1)) * 256 + n;
                Apb[(size_t)arow * 1024 + acol] = f2bf(v);
            }
        }
    }
}

// ---------------------------------------------------------------------------
// fp32 tiled GEMM (reg dbuf): head FC only.
// ---------------------------------------------------------------------------
template<int BM, int BN, int BK, int TM, int TN>
__global__ __launch_bounds__(256) void gemm_kernel(
    const float* __restrict__ A, int lda,
    const float* __restrict__ W, int ldw,
    const float* __restrict__ bias,
    float* __restrict__ C, int ldc,
    int M, int N, int K, int act)
{
    static_assert(BM * BK / 4 == 256 && BN * BK / 4 == 256, "staging shape");
    __shared__ float As[BK][BM + 4];
    __shared__ float Bs[BK][BN + 4];
    int t = threadIdx.x;
    int m0 = blockIdx.x * BM, n0 = blockIdx.y * BN;
    float acc[TM][TN];
    #pragma unroll
    for (int i = 0; i < TM; i++)
        #pragma unroll
        for (int j = 0; j < TN; j++) acc[i][j] = 0.f;
    const int LPR = BK / 4;
    int lr = t / LPR, lc4 = (t % LPR) * 4;
    int ty = t >> 4, tx = t & 15;
    int ma = m0 + lr, nb = n0 + lr;
    float4 va = make_float4(0.f, 0.f, 0.f, 0.f);
    float4 vb = make_float4(0.f, 0.f, 0.f, 0.f);
    if (ma < M) va = *(const float4*)(A + (size_t)ma * lda + lc4);
    if (nb < N) vb = *(const float4*)(W + (size_t)nb * ldw + lc4);
    for (int k0 = 0; k0 < K; k0 += BK) {
        __syncthreads();
        As[lc4 + 0][lr] = va.x; As[lc4 + 1][lr] = va.y;
        As[lc4 + 2][lr] = va.z; As[lc4 + 3][lr] = va.w;
        Bs[lc4 + 0][lr] = vb.x; Bs[lc4 + 1][lr] = vb.y;
        Bs[lc4 + 2][lr] = vb.z; Bs[lc4 + 3][lr] = vb.w;
        __syncthreads();
        if (k0 + BK < K) {
            if (ma < M) va = *(const float4*)(A + (size_t)ma * lda + k0 + BK + lc4);
            if (nb < N) vb = *(const float4*)(W + (size_t)nb * ldw + k0 + BK + lc4);
        }
        #pragma unroll
        for (int kk = 0; kk < BK; ++kk) {
            float a[TM], bfr[TN];
            #pragma unroll
            for (int i = 0; i < TM; i += 4)
                *(float4*)&a[i] = *(const float4*)&As[kk][ty * TM + i];
            #pragma unroll
            for (int j = 0; j < TN; j += 4)
                *(float4*)&bfr[j] = *(const float4*)&Bs[kk][tx * TN + j];
            #pragma unroll
            for (int i = 0; i < TM; i++)
                #pragma unroll
                for (int j = 0; j < TN; j++) acc[i][j] = fmaf(a[i], bfr[j], acc[i][j]);
        }
    }
    #pragma unroll
    for (int i = 0; i < TM; i++) {
        int m = m0 + ty * TM + i;
        if (m >= M) continue;
        #pragma unroll
        for (int j = 0; j < TN; j++) {
            int n = n0 + tx * TN + j;
            if (n >= N) continue;
            float v = acc[i][j];
            if (bias) v += bias[n];
            if (act == 2) v = softplus_f(v);
            C[(size_t)m * ldc + n] = v;
        }
    }
}

// ---------------------------------------------------------------------------
// Depthwise conv1d (K=4, pad(1,2)) in [b,l,d], bf16 in -> bf16 out (xlb == u).
// ---------------------------------------------------------------------------
__global__ __launch_bounds__(256) void dwconv(
    const ushort* __restrict__ xib, const float* __restrict__ cw,
    const float* __restrict__ cb, ushort* __restrict__ xlb)
{
    int idx = blockIdx.x * 256 + threadIdx.x;   // 524288
    int d4 = (idx & 127) * 4;
    int bl = idx >> 7;
    int b = bl >> 10, l = bl & 1023;
    float4 w0 = *(const float4*)(cw + d4 * 4);
    float4 w1 = *(const float4*)(cw + d4 * 4 + 4);
    float4 w2 = *(const float4*)(cw + d4 * 4 + 8);
    float4 w3 = *(const float4*)(cw + d4 * 4 + 12);
    float4 acc = *(const float4*)(cb + d4);
    const ushort* rowb = xib + ((size_t)b << 19) + d4;
    #pragma unroll
    for (int k = 0; k < 4; ++k) {
        int ll = l + k - 1;
        if ((unsigned)ll < 1024u) {
            uint2 p = *(const uint2*)(rowb + (size_t)ll * 512);
            acc.x = fmaf(bf2f((ushort)(p.x & 0xffffu)), ((const float*)&w0)[k], acc.x);
            acc.y = fmaf(bf2f((ushort)(p.x >> 16)),     ((const float*)&w1)[k], acc.y);
            acc.z = fmaf(bf2f((ushort)(p.y & 0xffffu)), ((const float*)&w2)[k], acc.z);
            acc.w = fmaf(bf2f((ushort)(p.y >> 16)),     ((const float*)&w3)[k], acc.w);
        }
    }
    uint2 pk;
    pk.x = (uint)f2bf(acc.x) | ((uint)f2bf(acc.y) << 16);
    pk.y = (uint)f2bf(acc.z) | ((uint)f2bf(acc.w) << 16);
    *(uint2*)(xlb + (size_t)bl * 512 + d4) = pk;
}

// ---------------------------------------------------------------------------
// Chunked scan pass 1 (fused dt_proj, 4-step composition, fp32 LDS staging).
// 15 chunks of 64 timesteps (chunk 15's summary is never read): grid 960.
// dt_proj: xd as float4 broadcast, dpw_s stride 34 as float2 (2-way = free).
// ~34.5KB LDS -> 4 blocks/CU.
// ---------------------------------------------------------------------------
__global__ __launch_bounds__(512, 8) void scan_part1(
    const float* __restrict__ xdbl, const ushort* __restrict__ xlb,
    const float* __restrict__ dpw, const float* __restrict__ dpb,
    const float* __restrict__ alog,
    float* __restrict__ Psum, float* __restrict__ hFsum)
{
    __shared__ __align__(16) float Td[32][68];
    __shared__ __align__(16) float Tu[32][68];
    __shared__ __align__(16) float TB[16][68];
    __shared__ __align__(16) float xd[64][32];
    __shared__ __align__(16) float dpw_s[32][34];
    __shared__ float dpb_s[32];
    int t = threadIdx.x;
    int bid = blockIdx.x;                 // 960 = b(4) x dgG(16) x ch(15)
    int ch = bid % 15;
    int gq = bid / 15;
    int dgG = gq & 15, b = gq >> 4;
    int d0 = dgG * 32;
    int bl0 = b * 1024 + ch * 64;
    {   // xd: 64 l x 32 k, one float4/thread
        int l = t >> 3, k4 = (t & 7) * 4;
        float4 v = *(const float4*)(xdbl + (size_t)(bl0 + l) * 64 + k4);
        *(float4*)&xd[l][k4] = v;
    }
    if (t < 256) {   // Tu: 64 l x 32 d (bf16 -> fp32 at stage time)
        int l = t >> 2, d8 = (t & 3) * 8;
        uint4 p = *(const uint4*)(xlb + (size_t)(bl0 + l) * 512 + d0 + d8);
        Tu[d8 + 0][l] = bf2f((ushort)(p.x & 0xffffu));
        Tu[d8 + 1][l] = bf2f((ushort)(p.x >> 16));
        Tu[d8 + 2][l] = bf2f((ushort)(p.y & 0xffffu));
        Tu[d8 + 3][l] = bf2f((ushort)(p.y >> 16));
        Tu[d8 + 4][l] = bf2f((ushort)(p.z & 0xffffu));
        Tu[d8 + 5][l] = bf2f((ushort)(p.z >> 16));
        Tu[d8 + 6][l] = bf2f((ushort)(p.w & 0xffffu));
        Tu[d8 + 7][l] = bf2f((ushort)(p.w >> 16));
    } else {         // TB: 64 l x 16 n, fp32
        int tt = t - 256;
        int l = tt >> 2, n4 = (tt & 3) * 4;
        float4 bv = *(const float4*)(xdbl + (size_t)(bl0 + l) * 64 + 32 + n4);
        TB[n4 + 0][l] = bv.x; TB[n4 + 1][l] = bv.y;
        TB[n4 + 2][l] = bv.z; TB[n4 + 3][l] = bv.w;
    }
    #pragma unroll
    for (int r = 0; r < 2; ++r) {
        int idx = r * 512 + t;
        int dd = idx >> 5, kk = idx & 31;
        dpw_s[dd][kk] = dpw[(size_t)(d0 + dd) * 32 + kk];
    }
    if (t < 32) dpb_s[t] = dpb[d0 + t];
    __syncthreads();
    {   // fused dt_proj: 32 dd x 64 l, 4 entries/thread (vectorized reads)
        int dd = t & 31, lb = (t >> 5) * 4;
        #pragma unroll
        for (int j = 0; j < 4; ++j) {
            int l = lb + j;
            float s = dpb_s[dd];
            #pragma unroll
            for (int k4 = 0; k4 < 8; ++k4) {
                float4 xv = *(const float4*)&xd[l][k4 * 4];
                float2 wa = *(const float2*)&dpw_s[dd][k4 * 4];
                float2 wb = *(const float2*)&dpw_s[dd][k4 * 4 + 2];
                s = fmaf(xv.x, wa.x, s);
                s = fmaf(xv.y, wa.y, s);
                s = fmaf(xv.z, wb.x, s);
                s = fmaf(xv.w, wb.y, s);
            }
            Td[dd][l] = softplus_f(s);
        }
    }
    __syncthreads();
    int w = t >> 6, lane = t & 63;
    int dl = lane >> 4, n = lane & 15;
    int col = w * 4 + dl;
    int d = d0 + col;
    float Ac = -__expf(alog[d * 16 + n]);
    float h = 0.f, P = 1.f;
    for (int l4 = 0; l4 < 16; ++l4) {
        float4 de = *(const float4*)&Td[col][l4 * 4];
        float4 uu = *(const float4*)&Tu[col][l4 * 4];
        float4 Bv = *(const float4*)&TB[n][l4 * 4];
        float a1 = __expf(de.x * Ac), a2 = __expf(de.y * Ac);
        float a3 = __expf(de.z * Ac), a4 = __expf(de.w * Ac);
        float b1 = de.x * Bv.x * uu.x, b2 = de.y * Bv.y * uu.y;
        float b3 = de.z * Bv.z * uu.z, b4 = de.w * Bv.w * uu.w;
        float a21 = a2 * a1,     b21 = fmaf(a2, b1, b2);
        float a321 = a3 * a21,   b321 = fmaf(a3, b21, b3);
        float a4321 = a4 * a321, b4321 = fmaf(a4, b321, b4);
        h = fmaf(a4321, h, b4321);
        P *= a4321;
    }
    size_t si = ((size_t)(b * 128 + dgG * 8 + w) * 16 + ch) * 64 + lane;
    Psum[si] = P;
    hFsum[si] = h;
}

// ---------------------------------------------------------------------------
// Chunked scan pass 2 (fused dt_proj, 4-step composition, fp32 LDS staging,
// DPP row_shr n-reduction, packed yb2, xd overlaid on TB/TC/yb2 union,
// masked-unrolled chunk-prefix loads). ~34.5KB LDS -> 4 blocks/CU.
// ---------------------------------------------------------------------------
__global__ __launch_bounds__(512, 8) void scan_part2(
    const float* __restrict__ xdbl, const ushort* __restrict__ xlb,
    const float* __restrict__ dpw, const float* __restrict__ dpb,
    const float* __restrict__ alog, const float* __restrict__ dssm,
    const ushort* __restrict__ resb, ushort* __restrict__ ybb,
    const float* __restrict__ Psum, const float* __restrict__ hFsum)
{
    __shared__ __align__(16) float Td[32][68];
    __shared__ __align__(16) float Tu[32][68];
    // union: xd fp32[64][32] (8192B) overlays TB(4352)+TC(4352)+yb2(4224)=12928B
    __shared__ __align__(16) unsigned char uni[12928];
    __shared__ __align__(16) float dpw_s[32][34];
    __shared__ float dpb_s[32];
    float* xd = (float*)uni;                          // [64][32]
    float (*TB)[68] = (float(*)[68])uni;              // [16][68]
    float (*TC)[68] = (float(*)[68])(uni + 4352);     // [16][68]
    uint (*yb2)[33] = (uint(*)[33])(uni + 8704);      // [32][33]
    int t = threadIdx.x;
    int bid = blockIdx.x;                 // 1024 = b(4) x dgG(16) x ch(16)
    int ch = bid & 15, dgG = (bid >> 4) & 15, b = bid >> 8;
    int d0 = dgG * 32;
    int bl0 = b * 1024 + ch * 64;
    {   // xd into union
        int l = t >> 3, k4 = (t & 7) * 4;
        float4 v = *(const float4*)(xdbl + (size_t)(bl0 + l) * 64 + k4);
        *(float4*)&xd[l * 32 + k4] = v;
    }
    if (t < 256) {   // Tu (bf16 -> fp32 at stage time)
        int l = t >> 2, d8 = (t & 3) * 8;
        uint4 p = *(const uint4*)(xlb + (size_t)(bl0 + l) * 512 + d0 + d8);
        Tu[d8 + 0][l] = bf2f((ushort)(p.x & 0xffffu));
        Tu[d8 + 1][l] = bf2f((ushort)(p.x >> 16));
        Tu[d8 + 2][l] = bf2f((ushort)(p.y & 0xffffu));
        Tu[d8 + 3][l] = bf2f((ushort)(p.y >> 16));
        Tu[d8 + 4][l] = bf2f((ushort)(p.z & 0xffffu));
        Tu[d8 + 5][l] = bf2f((ushort)(p.z >> 16));
        Tu[d8 + 6][l] = bf2f((ushort)(p.w & 0xffffu));
        Tu[d8 + 7][l] = bf2f((ushort)(p.w >> 16));
    }
    #pragma unroll
    for (int r = 0; r < 2; ++r) {
        int idx = r * 512 + t;
        int dd = idx >> 5, kk = idx & 31;
        dpw_s[dd][kk] = dpw[(size_t)(d0 + dd) * 32 + kk];
    }
    if (t < 32) dpb_s[t] = dpb[d0 + t];
    __syncthreads();
    {   // fused dt_proj (reads xd, vectorized)
        int dd = t & 31, lb = (t >> 5) * 4;
        #pragma unroll
        for (int j = 0; j < 4; ++j) {
            int l = lb + j;
            float s = dpb_s[dd];
            #pragma unroll
            for (int k4 = 0; k4 < 8; ++k4) {
                float4 xv = *(const float4*)&xd[l * 32 + k4 * 4];
                float2 wa = *(const float2*)&dpw_s[dd][k4 * 4];
                float2 wb = *(const float2*)&dpw_s[dd][k4 * 4 + 2];
                s = fmaf(xv.x, wa.x, s);
                s = fmaf(xv.y, wa.y, s);
                s = fmaf(xv.z, wb.x, s);
                s = fmaf(xv.w, wb.y, s);
            }
            Td[dd][l] = softplus_f(s);
        }
    }
    __syncthreads();   // xd dead; Td visible
    if (t < 256) {     // TB/TC over dead xd, fp32
        int l = t >> 2, n4 = (t & 3) * 4;
        float4 bv = *(const float4*)(xdbl + (size_t)(bl0 + l) * 64 + 32 + n4);
        float4 cv = *(const float4*)(xdbl + (size_t)(bl0 + l) * 64 + 48 + n4);
        TB[n4 + 0][l] = bv.x; TB[n4 + 1][l] = bv.y;
        TB[n4 + 2][l] = bv.z; TB[n4 + 3][l] = bv.w;
        TC[n4 + 0][l] = cv.x; TC[n4 + 1][l] = cv.y;
        TC[n4 + 2][l] = cv.z; TC[n4 + 3][l] = cv.w;
    }
    int w = t >> 6, lane = t & 63;
    int dl = lane >> 4, n = lane & 15;
    int col = w * 4 + dl;
    int d = d0 + col;
    float Ac = -__expf(alog[d * 16 + n]);
    float Dd = dssm[d];
    float h = 0.f;
    {   // chunk-prefix: fully unrolled, masked -> all loads issue in parallel
        size_t sbase = (size_t)(b * 128 + dgG * 8 + w) * 1024 + lane;
        #pragma unroll
        for (int cc = 0; cc < 15; ++cc) {
            float Pv = Psum[sbase + (size_t)cc * 64];
            float hv = hFsum[sbase + (size_t)cc * 64];
            bool use = cc < ch;
            Pv = use ? Pv : 1.f;
            hv = use ? hv : 0.f;
            h = fmaf(Pv, h, hv);
        }
    }
    __syncthreads();   // TB/TC visible
    for (int l4 = 0; l4 < 16; ++l4) {
        float4 de = *(const float4*)&Td[col][l4 * 4];
        float4 uu = *(const float4*)&Tu[col][l4 * 4];
        float4 Bv = *(const float4*)&TB[n][l4 * 4];
        float4 Cv = *(const float4*)&TC[n][l4 * 4];
        float a1 = __expf(de.x * Ac), a2 = __expf(de.y * Ac);
        float a3 = __expf(de.z * Ac), a4 = __expf(de.w * Ac);
        float b1 = de.x * Bv.x * uu.x, b2 = de.y * Bv.y * uu.y;
        float b3 = de.z * Bv.z * uu.z, b4 = de.w * Bv.w * uu.w;
        float a21 = a2 * a1,     b21 = fmaf(a2, b1, b2);
        float a321 = a3 * a21,   b321 = fmaf(a3, b21, b3);
        float a4321 = a4 * a321, b4321 = fmaf(a4, b321, b4);
        float h1 = fmaf(a1, h, b1);
        float h2 = fmaf(a21, h, b21);
        float h3 = fmaf(a321, h, b321);
        float h4 = fmaf(a4321, h, b4321);
        h = h4;
        float p0 = h1 * Cv.x, p1 = h2 * Cv.y, p2 = h3 * Cv.z, p3 = h4 * Cv.w;
        // 16-lane n-reduction via DPP row_shr: sum lands in lane n==15.
        DPP_ROW_SHR_ADD(p0, 1); DPP_ROW_SHR_ADD(p0, 2);
        DPP_ROW_SHR_ADD(p0, 4); DPP_ROW_SHR_ADD(p0, 8);
        DPP_ROW_SHR_ADD(p1, 1); DPP_ROW_SHR_ADD(p1, 2);
        DPP_ROW_SHR_ADD(p1, 4); DPP_ROW_SHR_ADD(p1, 8);
        DPP_ROW_SHR_ADD(p2, 1); DPP_ROW_SHR_ADD(p2, 2);
        DPP_ROW_SHR_ADD(p2, 4); DPP_ROW_SHR_ADD(p2, 8);
        DPP_ROW_SHR_ADD(p3, 1); DPP_ROW_SHR_ADD(p3, 2);
        DPP_ROW_SHR_ADD(p3, 4); DPP_ROW_SHR_ADD(p3, 8);
        if (n == 15) {
            int l2 = l4 * 2;
            float y0 = fmaf(uu.x, Dd, p0), y1 = fmaf(uu.y, Dd, p1);
            float y2 = fmaf(uu.z, Dd, p2), y3 = fmaf(uu.w, Dd, p3);
            yb2[l2 + 0][col] = (uint)f2bf(y0) | ((uint)f2bf(y1) << 16);
            yb2[l2 + 1][col] = (uint)f2bf(y2) | ((uint)f2bf(y3) << 16);
        }
    }
    __syncthreads();
    // gated store: 32 l2 x 32 col = 1024 items over 512 threads x 2
    size_t base = ((size_t)(b * 1024 + ch * 64)) * 512 + d0;   // ushort offset
    #pragma unroll
    for (int j = 0; j < 2; ++j) {
        int idx = j * 512 + t;
        int l2 = idx >> 5, col2 = idx & 31;
        uint yv = yb2[l2][col2];
        int l0 = l2 * 2;
        float r0 = bf2f(resb[base + (size_t)l0 * 512 + col2]);
        float r1 = bf2f(resb[base + (size_t)(l0 + 1) * 512 + col2]);
        float y0 = bf2f((ushort)(yv & 0xffffu)) * r0;
        float y1 = bf2f((ushort)(yv >> 16)) * r1;
        ybb[base + (size_t)l0 * 512 + col2] = f2bf(y0);
        ybb[base + (size_t)(l0 + 1) * 512 + col2] = f2bf(y1);
    }
}

// s[row] = LN(o[row])*g + b + s[row]; also writes bf16 copy sb. One wave/row.
__global__ __launch_bounds__(256) void ln_res_kernel(
    const float* __restrict__ o, const float* __restrict__ g,
    const float* __restrict__ bb, float* __restrict__ s, ushort* __restrict__ sb)
{
    int row = blockIdx.x * 4 + (threadIdx.x >> 6);
    int lane = threadIdx.x & 63;
    const float4* orow = (const float4*)(o + (size_t)row * 256);
    float4 v = orow[lane];
    float sum = v.x + v.y + v.z + v.w;
    float sq = v.x * v.x + v.y * v.y + v.z * v.z + v.w * v.w;
    #pragma unroll
    for (int off = 1; off < 64; off <<= 1) {
        sum += __shfl_xor(sum, off);
        sq += __shfl_xor(sq, off);
    }
    float m = sum * (1.f / 256.f);
    float var = sq * (1.f / 256.f) - m * m;
    float rstd = rsqrtf(var + 1e-5f);
    float4 gg = ((const float4*)g)[lane];
    float4 bv = ((const float4*)bb)[lane];
    float4* srow = (float4*)(s + (size_t)row * 256);
    float4 sv = srow[lane];
    sv.x += (v.x - m) * rstd * gg.x + bv.x;
    sv.y += (v.y - m) * rstd * gg.y + bv.y;
    sv.z += (v.z - m) * rstd * gg.z + bv.z;
    sv.w += (v.w - m) * rstd * gg.w + bv.w;
    srow[lane] = sv;
    uint2 pk;
    pk.x = (uint)f2bf(sv.x) | ((uint)f2bf(sv.y) << 16);
    pk.y = (uint)f2bf(sv.z) | ((uint)f2bf(sv.w) << 16);
    *(uint2*)(sb + (size_t)row * 256 + lane * 4) = pk;
}

// Stage 1 of mean-pool: 128 blocks (b x 32 chunks), each sums 32 l-rows
// coalesced -> partial[b][chunk][256].
__global__ __launch_bounds__(256) void pool_partial(
    const float* __restrict__ s, float* __restrict__ partial)
{
    int b = blockIdx.x >> 5, chunk = blockIdx.x & 31;
    int c = threadIdx.x;
    const float* p = s + (size_t)b * 262144 + (size_t)(chunk * 32) * 256 + c;
    float acc = 0.f;
    #pragma unroll
    for (int l = 0; l < 32; ++l) acc += p[(size_t)l * 256];
    partial[(size_t)blockIdx.x * 256 + c] = acc;
}

// Stage 2: sum 32 partials, then LN over 256 channels. grid 4 x 256.
__global__ __launch_bounds__(256) void pool_ln_final(
    const float* __restrict__ partial, const float* __restrict__ nw,
    const float* __restrict__ nb, float* __restrict__ sln)
{
    int b = blockIdx.x, c = threadIdx.x;
    const float* p = partial + (size_t)b * 32 * 256 + c;
    float acc = 0.f;
    #pragma unroll
    for (int k = 0; k < 32; ++k) acc += p[(size_t)k * 256];
    float pooled = acc * (1.f / 1024.f);
    __shared__ float rs[4], rq[4];
    float sum = pooled, sq = pooled * pooled;
    #pragma unroll
    for (int off = 1; off < 64; off <<= 1) {
        sum += __shfl_xor(sum, off);
        sq += __shfl_xor(sq, off);
    }
    int w = threadIdx.x >> 6;
    if ((threadIdx.x & 63) == 0) { rs[w] = sum; rq[w] = sq; }
    __syncthreads();
    sum = rs[0] + rs[1] + rs[2] + rs[3];
    sq = rq[0] + rq[1] + rq[2] + rq[3];
    float m = sum * (1.f / 256.f);
    float var = sq * (1.f / 256.f) - m * m;
    float rstd = rsqrtf(var + 1e-5f);
    sln[b * 256 + c] = (pooled - m) * rstd * nw[c] + nb[c];
}

// softmax over 1000 logits per b
__global__ __launch_bounds__(256) void softmax_kernel(float* __restrict__ out)
{
    int b = threadIdx.x >> 6, lane = threadIdx.x & 63;
    const float* lg = out + b * 1000;
    float v[16];
    float mx = -1e30f;
    #pragma unroll
    for (int j = 0; j < 16; ++j) {
        int i = lane + j * 64;
        v[j] = (i < 1000) ? lg[i] : -1e30f;
        mx = fmaxf(mx, v[j]);
    }
    #pragma unroll
    for (int off = 1; off < 64; off <<= 1) mx = fmaxf(mx, __shfl_xor(mx, off));
    float sum = 0.f;
    #pragma unroll
    for (int j = 0; j < 16; ++j) {
        int i = lane + j * 64;
        if (i < 1000) { v[j] = __expf(v[j] - mx); sum += v[j]; }
    }
    #pragma unroll
    for (int off = 1; off < 64; off <<= 1) sum += __shfl_xor(sum, off);
    float inv = 1.f / sum;
    float* so = out + 4000 + b * 1000;
    #pragma unroll
    for (int j = 0; j < 16; ++j) {
        int i = lane + j * 64;
        if (i < 1000) so[i] = v[j] * inv;
    }
}

// ---------------------------------------------------------------------------
extern "C" void kernel_launch(void* const* d_in, const int* in_sizes, int n_in,
                              void* d_out, int out_size, void* d_ws, size_t ws_size,
                              hipStream_t stream)
{
    const float* x    = (const float*)d_in[0];
    const float* c1w  = (const float*)d_in[1];
    const float* c1b  = (const float*)d_in[2];
    const float* g1   = (const float*)d_in[3];
    const float* b1   = (const float*)d_in[4];
    const float* c2w  = (const float*)d_in[5];
    const float* c2b  = (const float*)d_in[6];
    const float* g2   = (const float*)d_in[7];
    const float* b2   = (const float*)d_in[8];
    const float* pw   = (const float*)d_in[9];
    const float* pb   = (const float*)d_in[10];
    const float* g3   = (const float*)d_in[11];
    const float* b3   = (const float*)d_in[12];
    const float* ipw  = (const float*)d_in[13];
    const float* ipb  = (const float*)d_in[14];
    const float* cw   = (const float*)d_in[15];
    const float* cb   = (const float*)d_in[16];
    const float* xpw  = (const float*)d_in[17];
    const float* dpw  = (const float*)d_in[18];
    const float* dpb  = (const float*)d_in[19];
    const float* alog = (const float*)d_in[20];
    const float* dssm = (const float*)d_in[21];
    const float* opw  = (const float*)d_in[22];
    const float* opb  = (const float*)d_in[23];
    const float* lnw  = (const float*)d_in[24];
    const float* lnb  = (const float*)d_in[25];
    const float* nw   = (const float*)d_in[26];
    const float* nb   = (const float*)d_in[27];
    const float* fcw  = (const float*)d_in[28];
    const float* fcb  = (const float*)d_in[29];
    float* out = (float*)d_out;
    float* wsf = (float*)d_ws;

    float*  s_   = wsf;
    ushort* sb   = (ushort*)(wsf + 1048576);
    ushort* xib  = (ushort*)(wsf + 1572864);
    float*  obuf = wsf + 1572864;
    ushort* resb = (ushort*)(wsf + 3670016);
    ushort* xlb  = (ushort*)(wsf + 4718592);   // == u == ybb (in-place gate)
    ushort* ybb  = (ushort*)(wsf + 4718592);
    ushort* h1b  = (ushort*)(wsf + 4718592);
    ushort* Apb  = (ushort*)(wsf + 6815744);
    float*  xdbl = wsf + 8912896;
    ushort* ipwb = (ushort*)(wsf + 9175040);
    ushort* opwb = (ushort*)(wsf + 9699328);
    ushort* w2b  = (ushort*)(wsf + 9961472);
    ushort* pwTb = (ushort*)(wsf + 10108928);
    float*  sln  = wsf + 10240000;
    float*  Psum = wsf + 10241024;             // [4][128][16][64] = 524288 fl
    float*  hFsum= wsf + 10765312;             // 524288 fl
    ushort* xpwb = (ushort*)(wsf + 11289600);  // 131072 ushorts; end 11355136 fl
    float*  pprt = wsf + 11355136;             // [4][32][256] = 32768 fl

    // --- fused weight prep (1 dispatch) ---
    hipLaunchKernelGGL(wprep, dim3(8832), dim3(256), 0, stream,
                       ipw, opw, c2w, pw, xpw, ipwb, opwb, w2b, pwTb, xpwb);

    // --- conv stem ---
    hipLaunchKernelGGL(conv1_nhwc, dim3(256), dim3(256), 0, stream, x, c1w, c1b, g1, b1, h1b);
    hipLaunchKernelGGL(conv2_mfma, dim3(128, 4), dim3(256), 0, stream, h1b, w2b, c2b, g2, b2, Apb);
    hipLaunchKernelGGL((mfma_gemm_bt<64, 64, 2>), dim3(64, 4), dim3(256), 0, stream,
                       Apb, 1024, pwTb, 1024, pb, g3, b3, s_, sb, nullptr, 256, 1024);

    // --- mamba blocks ---
    for (int i = 0; i < 4; ++i) {
        const ushort* ipwb_i = ipwb + (size_t)i * 1024 * 256;
        const float*  ipb_i  = ipb + i * 1024;
        const float*  cw_i   = cw + i * 512 * 4;
        const float*  cb_i   = cb + i * 512;
        const ushort* xpwb_i = xpwb + (size_t)i * 64 * 512;
        const float*  dpw_i  = dpw + (size_t)i * 512 * 32;
        const float*  dpb_i  = dpb + i * 512;
        const float*  alog_i = alog + (size_t)i * 512 * 16;
        const float*  dssm_i = dssm + i * 512;
        const ushort* opwb_i = opwb + (size_t)i * 256 * 512;
        const float*  opb_i  = opb + i * 256;
        const float*  lnw_i  = lnw + i * 256;
        const float*  lnb_i  = lnb + i * 256;

        hipLaunchKernelGGL((mfma_gemm_bt<64, 128, 3>), dim3(64, 8), dim3(256), 0, stream,
                           sb, 256, ipwb_i, 256, ipb_i, nullptr, nullptr,
                           nullptr, xib, resb, 0, 256);
        hipLaunchKernelGGL(dwconv, dim3(2048), dim3(256), 0, stream, xib, cw_i, cb_i, xlb);
        hipLaunchKernelGGL((mfma_gemm_bt<64, 64, 0>), dim3(64, 1), dim3(256), 0, stream,
                           xlb, 512, xpwb_i, 512, nullptr, nullptr, nullptr,
                           xdbl, nullptr, nullptr, 64, 512);
        hipLaunchKernelGGL(scan_part1, dim3(960), dim3(512), 0, stream,
                           xdbl, xlb, dpw_i, dpb_i, alog_i, Psum, hFsum);
        hipLaunchKernelGGL(scan_part2, dim3(1024), dim3(512), 0, stream,
                           xdbl, xlb, dpw_i, dpb_i, alog_i, dssm_i, resb, ybb, Psum, hFsum);
        hipLaunchKernelGGL((mfma_gemm_bt<64, 64, 0>), dim3(64, 4), dim3(256), 0, stream,
                           ybb, 512, opwb_i, 512, opb_i, nullptr, nullptr,
                           obuf, nullptr, nullptr, 256, 512);
        hipLaunchKernelGGL(ln_res_kernel, dim3(1024), dim3(256), 0, stream,
                           obuf, lnw_i, lnb_i, s_, sb);
    }

    // --- head ---
    hipLaunchKernelGGL(pool_partial, dim3(128), dim3(256), 0, stream, s_, pprt);
    hipLaunchKernelGGL(pool_ln_final, dim3(4), dim3(256), 0, stream, pprt, nw, nb, sln);
    hipLaunchKernelGGL((gemm_kernel<64, 64, 16, 4, 4>), dim3(1, 16), dim3(256), 0, stream,
                       sln, 256, fcw, 256, fcb, out, 1000, 4, 1000, 256, 0);
    hipLaunchKernelGGL(softmax_kernel, dim3(1), dim3(256), 0, stream, out);
}

// Round 11
// 575.975 us; speedup vs baseline: 1.2302x; 1.0016x over previous
//
#include <hip/hip_runtime.h>
#include <math.h>

// ---------------------------------------------------------------------------
// FastImageMamba forward. R24: R23 (verified 576.9us) + xproj GEMM split-K=2
// (grid (64,2), 2x occupancy on the worst latency-bound GEMM) writing
// xdp[2][4096][64]; both scan kernels sum the two partials during their
// existing xd/TB/TC staging (no reduce dispatch). ~1ulp reassociation only.
// B=4, DM=256, NL=4, NC=1000, DI=512, NS=16, DTR=32, K=4, L=1024, H=W=64
// ---------------------------------------------------------------------------

#define BN_RSQ 0.99999500003749969f   // 1/sqrt(1+1e-5)

typedef unsigned int uint;
typedef unsigned short ushort;
typedef __bf16 bf16x8 __attribute__((ext_vector_type(8)));
typedef float floatx4 __attribute__((ext_vector_type(4)));

__device__ __forceinline__ float gelu_f(float v) {
    return 0.5f * v * (1.0f + erff(v * 0.70710678118654752f));
}
__device__ __forceinline__ float softplus_f(float v) {
    return (v > 20.f) ? v : log1pf(expf(v));
}
__device__ __forceinline__ ushort f2bf(float f) {
    uint x = __float_as_uint(f);
    x += 0x7fffu + ((x >> 16) & 1u);
    return (ushort)(x >> 16);
}
__device__ __forceinline__ float bf2f(ushort u) {
    return __uint_as_float((uint)u << 16);
}

// DPP row_shr:N add step: after N=1,2,4,8 lane 15 of each 16-lane row holds
// the row sum (bound_ctrl=1 -> out-of-row sources read 0).
#define DPP_ROW_SHR_ADD(x, N)                                               \
    x += __int_as_float(__builtin_amdgcn_update_dpp(                        \
        0, __float_as_int(x), 0x110 + (N), 0xf, 0xf, true))

// ---------------------------------------------------------------------------
// Fused weight prep: all fp32->bf16 weight conversions in one dispatch.
// ---------------------------------------------------------------------------
__global__ void wprep(const float* __restrict__ ipw, const float* __restrict__ opw,
                      const float* __restrict__ c2w, const float* __restrict__ pw,
                      const float* __restrict__ xpw,
                      ushort* __restrict__ ipwb, ushort* __restrict__ opwb,
                      ushort* __restrict__ w2b, ushort* __restrict__ pwTb,
                      ushort* __restrict__ xpwb)
{
    int idx = blockIdx.x * 256 + threadIdx.x;
    if (idx < 1048576) {
        ipwb[idx] = f2bf(ipw[idx]);
    } else if (idx < 1572864) {
        int i = idx - 1048576;
        opwb[i] = f2bf(opw[i]);
    } else if (idx < 1867776) {
        int i = idx - 1572864;
        int oc = i / 1152, k = i % 1152;
        int s = k >> 7, ic = k & 127;
        w2b[i] = f2bf(c2w[(size_t)(oc * 128 + ic) * 9 + s]);
    } else if (idx < 2129920) {
        int i = idx - 1867776;
        int oc = i >> 10, k = i & 1023;
        int s = k >> 8, ic = k & 255;
        int ky = s >> 1, kx = s & 1;
        pwTb[i] = f2bf(pw[((size_t)(oc * 256 + ic) * 2 + ky) * 2 + kx]);
    } else if (idx < 2260992) {
        int i = idx - 2129920;
        xpwb[i] = f2bf(xpw[i]);
    }
}

// ---------------------------------------------------------------------------
// conv1: 3x3 s1p1, IC=3 -> OC=128, NCHW fp32 in, NHWC bf16 out (+bias+BN+GELU)
// ---------------------------------------------------------------------------
__global__ __launch_bounds__(256) void conv1_nhwc(
    const float* __restrict__ x, const float* __restrict__ w,
    const float* __restrict__ cb, const float* __restrict__ g,
    const float* __restrict__ bb, ushort* __restrict__ out)
{
    __shared__ float tin[3][3][64];
    __shared__ float ws[3456];
    int t = threadIdx.x;
    int b = blockIdx.x >> 6, y = blockIdx.x & 63;
    for (int i = t; i < 3456; i += 256) ws[i] = w[i];
    for (int i = t; i < 576; i += 256) {
        int ic = i / 192, r = (i >> 6) % 3, xx = i & 63;
        int gy = y + r - 1;
        tin[ic][r][xx] = ((unsigned)gy < 64u) ? x[((b * 3 + ic) * 64 + gy) * 64 + xx] : 0.f;
    }
    __syncthreads();
    int tx = t & 15, ty = t >> 4;
    int oc0 = tx * 8, px0 = ty * 4;
    float acc[4][8];
    #pragma unroll
    for (int p = 0; p < 4; ++p)
        #pragma unroll
        for (int o = 0; o < 8; ++o) acc[p][o] = 0.f;
    for (int ic = 0; ic < 3; ++ic)
        #pragma unroll
        for (int ky = 0; ky < 3; ++ky)
            #pragma unroll
            for (int kx = 0; kx < 3; ++kx) {
                float av[4];
                #pragma unroll
                for (int p = 0; p < 4; ++p) {
                    int xx = px0 + p + kx - 1;
                    av[p] = ((unsigned)xx < 64u) ? tin[ic][ky][xx] : 0.f;
                }
                #pragma unroll
                for (int o = 0; o < 8; ++o) {
                    float wv = ws[(oc0 + o) * 27 + ic * 9 + ky * 3 + kx];
                    #pragma unroll
                    for (int p = 0; p < 4; ++p) acc[p][o] = fmaf(av[p], wv, acc[p][o]);
                }
            }
    #pragma unroll
    for (int p = 0; p < 4; ++p) {
        uint pk[4];
        #pragma unroll
        for (int o2 = 0; o2 < 4; ++o2) {
            int oc = oc0 + o2 * 2;
            float v0 = gelu_f((acc[p][o2 * 2] + cb[oc]) * (g[oc] * BN_RSQ) + bb[oc]);
            float v1 = gelu_f((acc[p][o2 * 2 + 1] + cb[oc + 1]) * (g[oc + 1] * BN_RSQ) + bb[oc + 1]);
            pk[o2] = (uint)f2bf(v0) | ((uint)f2bf(v1) << 16);
        }
        uint4 vv = make_uint4(pk[0], pk[1], pk[2], pk[3]);
        *(uint4*)(out + ((size_t)((b * 64 + y) * 64 + px0 + p)) * 128 + oc0) = vv;
    }
}

// ---------------------------------------------------------------------------
// bf16 MFMA GEMM (A @ W^T), BMxBN tile, BK=32, 4 waves (2x2), reg dbuf.
// EPI: 0 = +bias -> fp32 Cf[ldc]
//      2 = +bias,BN,GELU -> fp32 Cf + bf16 Cb (same ldc)
//      3 = in_proj: n<512 -> bf16 Cb[m*512+n]; n>=512 -> bf16 silu -> Cb2
// ---------------------------------------------------------------------------
template<int BM, int BN, int EPI>
__global__ __launch_bounds__(256, 2) void mfma_gemm_bt(
    const ushort* __restrict__ A, int lda,
    const ushort* __restrict__ W, int ldw,
    const float* __restrict__ bias,
    const float* __restrict__ bnG, const float* __restrict__ bnB,
    float* __restrict__ Cf, ushort* __restrict__ Cb, ushort* __restrict__ Cb2,
    int ldc, int K)
{
    constexpr int PAD = 40;
    constexpr int AP = BM / 64;
    constexpr int BP = BN / 64;
    constexpr int FM = BM / 32;
    constexpr int FN = BN / 32;
    __shared__ __align__(16) ushort As[BM * PAD];
    __shared__ __align__(16) ushort Bs[BN * PAD];
    int t = threadIdx.x;
    int m0 = blockIdx.x * BM, n0 = blockIdx.y * BN;
    int lane = t & 63, wid = t >> 6;
    int wm = (wid & 1) * (BM / 2), wn = (wid >> 1) * (BN / 2);
    int fr = lane & 15, fk = (lane >> 4) * 8;
    int r0 = t >> 2, c0 = (t & 3) * 8;
    floatx4 acc[FM][FN];
    #pragma unroll
    for (int i = 0; i < FM; ++i)
        #pragma unroll
        for (int j = 0; j < FN; ++j) acc[i][j] = {0.f, 0.f, 0.f, 0.f};
    uint4 ra[AP], rb[BP];
    #pragma unroll
    for (int p = 0; p < AP; ++p)
        ra[p] = *(const uint4*)(A + (size_t)(m0 + r0 + p * 64) * lda + c0);
    #pragma unroll
    for (int p = 0; p < BP; ++p)
        rb[p] = *(const uint4*)(W + (size_t)(n0 + r0 + p * 64) * ldw + c0);
    for (int k0 = 0; k0 < K; k0 += 32) {
        __syncthreads();
        #pragma unroll
        for (int p = 0; p < AP; ++p) *(uint4*)&As[(r0 + p * 64) * PAD + c0] = ra[p];
        #pragma unroll
        for (int p = 0; p < BP; ++p) *(uint4*)&Bs[(r0 + p * 64) * PAD + c0] = rb[p];
        __syncthreads();
        if (k0 + 32 < K) {
            #pragma unroll
            for (int p = 0; p < AP; ++p)
                ra[p] = *(const uint4*)(A + (size_t)(m0 + r0 + p * 64) * lda + k0 + 32 + c0);
            #pragma unroll
            for (int p = 0; p < BP; ++p)
                rb[p] = *(const uint4*)(W + (size_t)(n0 + r0 + p * 64) * ldw + k0 + 32 + c0);
        }
        bf16x8 af[FM], bw[FN];
        #pragma unroll
        for (int i = 0; i < FM; ++i)
            af[i] = *(const bf16x8*)&As[(wm + i * 16 + fr) * PAD + fk];
        #pragma unroll
        for (int j = 0; j < FN; ++j)
            bw[j] = *(const bf16x8*)&Bs[(wn + j * 16 + fr) * PAD + fk];
        #pragma unroll
        for (int i = 0; i < FM; ++i)
            #pragma unroll
            for (int j = 0; j < FN; ++j)
                acc[i][j] = __builtin_amdgcn_mfma_f32_16x16x32_bf16(af[i], bw[j], acc[i][j], 0, 0, 0);
    }
    int rbase = (lane >> 4) * 4, cc = lane & 15;
    #pragma unroll
    for (int j = 0; j < FN; ++j) {
        int n = n0 + wn + j * 16 + cc;
        float bv = bias ? bias[n] : 0.f;
        float scl = 0.f, shf = 0.f;
        if (EPI == 2) { scl = bnG[n] * BN_RSQ; shf = bnB[n]; }
        #pragma unroll
        for (int i = 0; i < FM; ++i) {
            #pragma unroll
            for (int r = 0; r < 4; ++r) {
                int m = m0 + wm + i * 16 + rbase + r;
                float v = acc[i][j][r] + bv;
                if (EPI == 2) v = gelu_f(v * scl + shf);
                if (EPI == 0) {
                    Cf[(size_t)m * ldc + n] = v;
                } else if (EPI == 2) {
                    Cf[(size_t)m * ldc + n] = v;
                    Cb[(size_t)m * ldc + n] = f2bf(v);
                } else {
                    if (n < 512) Cb[(size_t)m * 512 + n] = f2bf(v);
                    else Cb2[(size_t)m * 512 + (n - 512)] = f2bf(v / (1.f + __expf(-v)));
                }
            }
        }
    }
}

// ---------------------------------------------------------------------------
// xproj GEMM, split-K=2: grid (64,2). Slice y covers K in [y*256,(y+1)*256),
// writes fp32 partial to Cf + y*4096*64. Scans sum the two partials.
// BM=BN=64, BK=32, 4 waves. A=xlb [4096][512], W=xpwb [64][512].
// ---------------------------------------------------------------------------
__global__ __launch_bounds__(256, 2) void xproj_gemm_sk(
    const ushort* __restrict__ A, const ushort* __restrict__ W,
    float* __restrict__ Cf)
{
    constexpr int PAD = 40;
    __shared__ __align__(16) ushort As[64 * PAD];
    __shared__ __align__(16) ushort Bs[64 * PAD];
    int t = threadIdx.x;
    int m0 = blockIdx.x * 64;
    int koff = blockIdx.y * 256;
    float* Cfp = Cf + (size_t)blockIdx.y * 262144;
    int lane = t & 63, wid = t >> 6;
    int wm = (wid & 1) * 32, wn = (wid >> 1) * 32;
    int fr = lane & 15, fk = (lane >> 4) * 8;
    int r0 = t >> 2, c0 = (t & 3) * 8;
    floatx4 acc[2][2];
    #pragma unroll
    for (int i = 0; i < 2; ++i)
        #pragma unroll
        for (int j = 0; j < 2; ++j) acc[i][j] = {0.f, 0.f, 0.f, 0.f};
    uint4 ra, rb;
    ra = *(const uint4*)(A + (size_t)(m0 + r0) * 512 + koff + c0);
    rb = *(const uint4*)(W + (size_t)r0 * 512 + koff + c0);
    for (int k0 = 0; k0 < 256; k0 += 32) {
        __syncthreads();
        *(uint4*)&As[r0 * PAD + c0] = ra;
        *(uint4*)&Bs[r0 * PAD + c0] = rb;
        __syncthreads();
        if (k0 + 32 < 256) {
            ra = *(const uint4*)(A + (size_t)(m0 + r0) * 512 + koff + k0 + 32 + c0);
            rb = *(const uint4*)(W + (size_t)r0 * 512 + koff + k0 + 32 + c0);
        }
        bf16x8 af[2], bw[2];
        #pragma unroll
        for (int i = 0; i < 2; ++i)
            af[i] = *(const bf16x8*)&As[(wm + i * 16 + fr) * PAD + fk];
        #pragma unroll
        for (int j = 0; j < 2; ++j)
            bw[j] = *(const bf16x8*)&Bs[(wn + j * 16 + fr) * PAD + fk];
        #pragma unroll
        for (int i = 0; i < 2; ++i)
            #pragma unroll
            for (int j = 0; j < 2; ++j)
                acc[i][j] = __builtin_amdgcn_mfma_f32_16x16x32_bf16(af[i], bw[j], acc[i][j], 0, 0, 0);
    }
    int rbase = (lane >> 4) * 4, cc = lane & 15;
    #pragma unroll
    for (int j = 0; j < 2; ++j) {
        int n = wn + j * 16 + cc;
        #pragma unroll
        for (int i = 0; i < 2; ++i) {
            #pragma unroll
            for (int r = 0; r < 4; ++r) {
                int m = m0 + wm + i * 16 + rbase + r;
                Cfp[(size_t)m * 64 + n] = acc[i][j][r];
            }
        }
    }
}

// ---------------------------------------------------------------------------
// conv2: 9-shift implicit MFMA GEMM, 128px x 64oc tile, BK=64 (18 steps),
// reg dbuf with EXPLICIT SCALAR uint4s (array-by-ref spills to scratch).
// Writes DIRECTLY in im2col/Apb layout (im2col kernel deleted).
// ---------------------------------------------------------------------------
#define C2_LOAD(step)                                                            \
    {                                                                            \
        int s_ = (step) >> 1, ich_ = ((step) & 1) * 64;                          \
        int ky_ = s_ / 3, kx_ = s_ % 3;                                          \
        int sy_ = y0 + (ra_row >> 6) + ky_ - 1;                                  \
        int sx_ = (ra_row & 63) + kx_ - 1;                                       \
        bool v_ = ((unsigned)sy_ < 64u) && ((unsigned)sx_ < 64u);                \
        const ushort* ap_ = hb + ((size_t)(sy_ * 64 + sx_)) * 128 + ich_ + ra_c; \
        uint4 zz_ = make_uint4(0u, 0u, 0u, 0u);                                  \
        ra0 = v_ ? *(const uint4*)(ap_ + 0)  : zz_;                              \
        ra1 = v_ ? *(const uint4*)(ap_ + 8)  : zz_;                              \
        ra2 = v_ ? *(const uint4*)(ap_ + 16) : zz_;                              \
        ra3 = v_ ? *(const uint4*)(ap_ + 24) : zz_;                              \
        const ushort* wp_ = w2b + (size_t)(n0 + rb_row) * 1152 + s_ * 128 + ich_ + rb_c; \
        rb0 = *(const uint4*)(wp_ + 0);                                          \
        rb1 = *(const uint4*)(wp_ + 8);                                          \
    }

__global__ __launch_bounds__(256, 2) void conv2_mfma(
    const ushort* __restrict__ h1b, const ushort* __restrict__ w2b,
    const float* __restrict__ cb, const float* __restrict__ g,
    const float* __restrict__ bb, ushort* __restrict__ Apb)
{
    constexpr int PAD = 72;
    __shared__ __align__(16) ushort As[128 * PAD];
    __shared__ __align__(16) ushort Bs[64 * PAD];
    int t = threadIdx.x;
    int m0 = blockIdx.x * 128, n0 = blockIdx.y * 64;
    int b = m0 >> 12;
    int y0 = (m0 & 4095) >> 6;
    int lane = t & 63, wid = t >> 6;
    int wm = (wid & 1) * 64, wn = (wid >> 1) * 32;
    int fr = lane & 15, fk = (lane >> 4) * 8;
    int ra_row = t >> 1, ra_c = (t & 1) * 32;
    int rb_row = t >> 2, rb_c = (t & 3) * 16;
    floatx4 acc[4][2];
    #pragma unroll
    for (int i = 0; i < 4; ++i)
        #pragma unroll
        for (int j = 0; j < 2; ++j) acc[i][j] = {0.f, 0.f, 0.f, 0.f};
    const ushort* hb = h1b + (size_t)b * 4096 * 128;

    uint4 ra0, ra1, ra2, ra3, rb0, rb1;
    C2_LOAD(0);
    for (int step = 0; step < 18; ++step) {
        __syncthreads();
        *(uint4*)&As[ra_row * PAD + ra_c + 0]  = ra0;
        *(uint4*)&As[ra_row * PAD + ra_c + 8]  = ra1;
        *(uint4*)&As[ra_row * PAD + ra_c + 16] = ra2;
        *(uint4*)&As[ra_row * PAD + ra_c + 24] = ra3;
        *(uint4*)&Bs[rb_row * PAD + rb_c + 0]  = rb0;
        *(uint4*)&Bs[rb_row * PAD + rb_c + 8]  = rb1;
        __syncthreads();
        if (step + 1 < 18) C2_LOAD(step + 1);
        #pragma unroll
        for (int ks = 0; ks < 64; ks += 32) {
            bf16x8 af[4], bw[2];
            #pragma unroll
            for (int i = 0; i < 4; ++i)
                af[i] = *(const bf16x8*)&As[(wm + i * 16 + fr) * PAD + ks + fk];
            #pragma unroll
            for (int j = 0; j < 2; ++j)
                bw[j] = *(const bf16x8*)&Bs[(wn + j * 16 + fr) * PAD + ks + fk];
            #pragma unroll
            for (int i = 0; i < 4; ++i)
                #pragma unroll
                for (int j = 0; j < 2; ++j)
                    acc[i][j] = __builtin_amdgcn_mfma_f32_16x16x32_bf16(af[i], bw[j], acc[i][j], 0, 0, 0);
        }
    }
    int rbase = (lane >> 4) * 4, cc = lane & 15;
    #pragma unroll
    for (int j = 0; j < 2; ++j) {
        int n = n0 + wn + j * 16 + cc;
        float scl = g[n] * BN_RSQ, shf = bb[n], bv2 = cb[n];
        #pragma unroll
        for (int i = 0; i < 4; ++i) {
            #pragma unroll
            for (int r = 0; r < 4; ++r) {
                int m = m0 + wm + i * 16 + rbase + r;   // b*4096 + y*64 + x
                float v = gelu_f((acc[i][j][r] + bv2) * scl + shf);
                int yy = (m >> 6) & 63, xx = m & 63;
                int arow = (m >> 12) * 1024 + (yy >> 1) * 32 + (xx >> 1);
                int acol = ((yy & 1) * 2 + (xx & 1)) * 256 + n;
                Apb[(size_t)arow * 1024 + acol] = f2bf(v);
            }
        }
    }
}

// ---------------------------------------------------------------------------
// fp32 tiled GEMM (reg dbuf): head FC only.
// ---------------------------------------------------------------------------
template<int BM, int BN, int BK, int TM, int TN>
__global__ __launch_bounds__(256) void gemm_kernel(
    const float* __restrict__ A, int lda,
    const float* __restrict__ W, int ldw,
    const float* __restrict__ bias,
    float* __restrict__ C, int ldc,
    int M, int N, int K, int act)
{
    static_assert(BM * BK / 4 == 256 && BN * BK / 4 == 256, "staging shape");
    __shared__ float As[BK][BM + 4];
    __shared__ float Bs[BK][BN + 4];
    int t = threadIdx.x;
    int m0 = blockIdx.x * BM, n0 = blockIdx.y * BN;
    float acc[TM][TN];
    #pragma unroll
    for (int i = 0; i < TM; i++)
        #pragma unroll
        for (int j = 0; j < TN; j++) acc[i][j] = 0.f;
    const int LPR = BK / 4;
    int lr = t / LPR, lc4 = (t % LPR) * 4;
    int ty = t >> 4, tx = t & 15;
    int ma = m0 + lr, nb = n0 + lr;
    float4 va = make_float4(0.f, 0.f, 0.f, 0.f);
    float4 vb = make_float4(0.f, 0.f, 0.f, 0.f);
    if (ma < M) va = *(const float4*)(A + (size_t)ma * lda + lc4);
    if (nb < N) vb = *(const float4*)(W + (size_t)nb * ldw + lc4);
    for (int k0 = 0; k0 < K; k0 += BK) {
        __syncthreads();
        As[lc4 + 0][lr] = va.x; As[lc4 + 1][lr] = va.y;
        As[lc4 + 2][lr] = va.z; As[lc4 + 3][lr] = va.w;
        Bs[lc4 + 0][lr] = vb.x; Bs[lc4 + 1][lr] = vb.y;
        Bs[lc4 + 2][lr] = vb.z; Bs[lc4 + 3][lr] = vb.w;
        __syncthreads();
        if (k0 + BK < K) {
            if (ma < M) va = *(const float4*)(A + (size_t)ma * lda + k0 + BK + lc4);
            if (nb < N) vb = *(const float4*)(W + (size_t)nb * ldw + k0 + BK + lc4);
        }
        #pragma unroll
        for (int kk = 0; kk < BK; ++kk) {
            float a[TM], bfr[TN];
            #pragma unroll
            for (int i = 0; i < TM; i += 4)
                *(float4*)&a[i] = *(const float4*)&As[kk][ty * TM + i];
            #pragma unroll
            for (int j = 0; j < TN; j += 4)
                *(float4*)&bfr[j] = *(const float4*)&Bs[kk][tx * TN + j];
            #pragma unroll
            for (int i = 0; i < TM; i++)
                #pragma unroll
                for (int j = 0; j < TN; j++) acc[i][j] = fmaf(a[i], bfr[j], acc[i][j]);
        }
    }
    #pragma unroll
    for (int i = 0; i < TM; i++) {
        int m = m0 + ty * TM + i;
        if (m >= M) continue;
        #pragma unroll
        for (int j = 0; j < TN; j++) {
            int n = n0 + tx * TN + j;
            if (n >= N) continue;
            float v = acc[i][j];
            if (bias) v += bias[n];
            if (act == 2) v = softplus_f(v);
            C[(size_t)m * ldc + n] = v;
        }
    }
}

// ---------------------------------------------------------------------------
// Depthwise conv1d (K=4, pad(1,2)) in [b,l,d], bf16 in -> bf16 out (xlb == u).
// ---------------------------------------------------------------------------
__global__ __launch_bounds__(256) void dwconv(
    const ushort* __restrict__ xib, const float* __restrict__ cw,
    const float* __restrict__ cb, ushort* __restrict__ xlb)
{
    int idx = blockIdx.x * 256 + threadIdx.x;   // 524288
    int d4 = (idx & 127) * 4;
    int bl = idx >> 7;
    int b = bl >> 10, l = bl & 1023;
    float4 w0 = *(const float4*)(cw + d4 * 4);
    float4 w1 = *(const float4*)(cw + d4 * 4 + 4);
    float4 w2 = *(const float4*)(cw + d4 * 4 + 8);
    float4 w3 = *(const float4*)(cw + d4 * 4 + 12);
    float4 acc = *(const float4*)(cb + d4);
    const ushort* rowb = xib + ((size_t)b << 19) + d4;
    #pragma unroll
    for (int k = 0; k < 4; ++k) {
        int ll = l + k - 1;
        if ((unsigned)ll < 1024u) {
            uint2 p = *(const uint2*)(rowb + (size_t)ll * 512);
            acc.x = fmaf(bf2f((ushort)(p.x & 0xffffu)), ((const float*)&w0)[k], acc.x);
            acc.y = fmaf(bf2f((ushort)(p.x >> 16)),     ((const float*)&w1)[k], acc.y);
            acc.z = fmaf(bf2f((ushort)(p.y & 0xffffu)), ((const float*)&w2)[k], acc.z);
            acc.w = fmaf(bf2f((ushort)(p.y >> 16)),     ((const float*)&w3)[k], acc.w);
        }
    }
    uint2 pk;
    pk.x = (uint)f2bf(acc.x) | ((uint)f2bf(acc.y) << 16);
    pk.y = (uint)f2bf(acc.z) | ((uint)f2bf(acc.w) << 16);
    *(uint2*)(xlb + (size_t)bl * 512 + d4) = pk;
}

// ---------------------------------------------------------------------------
// Chunked scan pass 1 (fused dt_proj, 4-step composition, fp32 LDS staging).
// 15 chunks of 64 timesteps (chunk 15's summary is never read): grid 960.
// xdp = [2][4096][64] split-K partials; staging sums them. ~34.5KB LDS.
// ---------------------------------------------------------------------------
__global__ __launch_bounds__(512, 8) void scan_part1(
    const float* __restrict__ xdp, const ushort* __restrict__ xlb,
    const float* __restrict__ dpw, const float* __restrict__ dpb,
    const float* __restrict__ alog,
    float* __restrict__ Psum, float* __restrict__ hFsum)
{
    __shared__ __align__(16) float Td[32][68];
    __shared__ __align__(16) float Tu[32][68];
    __shared__ __align__(16) float TB[16][68];
    __shared__ __align__(16) float xd[64][32];
    __shared__ __align__(16) float dpw_s[32][34];
    __shared__ float dpb_s[32];
    int t = threadIdx.x;
    int bid = blockIdx.x;                 // 960 = b(4) x dgG(16) x ch(15)
    int ch = bid % 15;
    int gq = bid / 15;
    int dgG = gq & 15, b = gq >> 4;
    int d0 = dgG * 32;
    int bl0 = b * 1024 + ch * 64;
    {   // xd: 64 l x 32 k, sum of two split-K partials
        int l = t >> 3, k4 = (t & 7) * 4;
        size_t off = (size_t)(bl0 + l) * 64 + k4;
        float4 v0 = *(const float4*)(xdp + off);
        float4 v1 = *(const float4*)(xdp + 262144 + off);
        float4 v = make_float4(v0.x + v1.x, v0.y + v1.y, v0.z + v1.z, v0.w + v1.w);
        *(float4*)&xd[l][k4] = v;
    }
    if (t < 256) {   // Tu: 64 l x 32 d (bf16 -> fp32 at stage time)
        int l = t >> 2, d8 = (t & 3) * 8;
        uint4 p = *(const uint4*)(xlb + (size_t)(bl0 + l) * 512 + d0 + d8);
        Tu[d8 + 0][l] = bf2f((ushort)(p.x & 0xffffu));
        Tu[d8 + 1][l] = bf2f((ushort)(p.x >> 16));
        Tu[d8 + 2][l] = bf2f((ushort)(p.y & 0xffffu));
        Tu[d8 + 3][l] = bf2f((ushort)(p.y >> 16));
        Tu[d8 + 4][l] = bf2f((ushort)(p.z & 0xffffu));
        Tu[d8 + 5][l] = bf2f((ushort)(p.z >> 16));
        Tu[d8 + 6][l] = bf2f((ushort)(p.w & 0xffffu));
        Tu[d8 + 7][l] = bf2f((ushort)(p.w >> 16));
    } else {         // TB: 64 l x 16 n, sum of partials
        int tt = t - 256;
        int l = tt >> 2, n4 = (tt & 3) * 4;
        size_t off = (size_t)(bl0 + l) * 64 + 32 + n4;
        float4 b0 = *(const float4*)(xdp + off);
        float4 b1 = *(const float4*)(xdp + 262144 + off);
        TB[n4 + 0][l] = b0.x + b1.x; TB[n4 + 1][l] = b0.y + b1.y;
        TB[n4 + 2][l] = b0.z + b1.z; TB[n4 + 3][l] = b0.w + b1.w;
    }
    #pragma unroll
    for (int r = 0; r < 2; ++r) {
        int idx = r * 512 + t;
        int dd = idx >> 5, kk = idx & 31;
        dpw_s[dd][kk] = dpw[(size_t)(d0 + dd) * 32 + kk];
    }
    if (t < 32) dpb_s[t] = dpb[d0 + t];
    __syncthreads();
    {   // fused dt_proj: 32 dd x 64 l, 4 entries/thread (vectorized reads)
        int dd = t & 31, lb = (t >> 5) * 4;
        #pragma unroll
        for (int j = 0; j < 4; ++j) {
            int l = lb + j;
            float s = dpb_s[dd];
            #pragma unroll
            for (int k4 = 0; k4 < 8; ++k4) {
                float4 xv = *(const float4*)&xd[l][k4 * 4];
                float2 wa = *(const float2*)&dpw_s[dd][k4 * 4];
                float2 wb = *(const float2*)&dpw_s[dd][k4 * 4 + 2];
                s = fmaf(xv.x, wa.x, s);
                s = fmaf(xv.y, wa.y, s);
                s = fmaf(xv.z, wb.x, s);
                s = fmaf(xv.w, wb.y, s);
            }
            Td[dd][l] = softplus_f(s);
        }
    }
    __syncthreads();
    int w = t >> 6, lane = t & 63;
    int dl = lane >> 4, n = lane & 15;
    int col = w * 4 + dl;
    int d = d0 + col;
    float Ac = -__expf(alog[d * 16 + n]);
    float h = 0.f, P = 1.f;
    for (int l4 = 0; l4 < 16; ++l4) {
        float4 de = *(const float4*)&Td[col][l4 * 4];
        float4 uu = *(const float4*)&Tu[col][l4 * 4];
        float4 Bv = *(const float4*)&TB[n][l4 * 4];
        float a1 = __expf(de.x * Ac), a2 = __expf(de.y * Ac);
        float a3 = __expf(de.z * Ac), a4 = __expf(de.w * Ac);
        float b1 = de.x * Bv.x * uu.x, b2 = de.y * Bv.y * uu.y;
        float b3 = de.z * Bv.z * uu.z, b4 = de.w * Bv.w * uu.w;
        float a21 = a2 * a1,     b21 = fmaf(a2, b1, b2);
        float a321 = a3 * a21,   b321 = fmaf(a3, b21, b3);
        float a4321 = a4 * a321, b4321 = fmaf(a4, b321, b4);
        h = fmaf(a4321, h, b4321);
        P *= a4321;
    }
    size_t si = ((size_t)(b * 128 + dgG * 8 + w) * 16 + ch) * 64 + lane;
    Psum[si] = P;
    hFsum[si] = h;
}

// ---------------------------------------------------------------------------
// Chunked scan pass 2 (fused dt_proj, 4-step composition, fp32 LDS staging,
// DPP row_shr n-reduction, packed yb2, xd overlaid on TB/TC/yb2 union,
// masked-unrolled chunk-prefix loads). xdp split-K partials summed in staging.
// ---------------------------------------------------------------------------
__global__ __launch_bounds__(512, 8) void scan_part2(
    const float* __restrict__ xdp, const ushort* __restrict__ xlb,
    const float* __restrict__ dpw, const float* __restrict__ dpb,
    const float* __restrict__ alog, const float* __restrict__ dssm,
    const ushort* __restrict__ resb, ushort* __restrict__ ybb,
    const float* __restrict__ Psum, const float* __restrict__ hFsum)
{
    __shared__ __align__(16) float Td[32][68];
    __shared__ __align__(16) float Tu[32][68];
    // union: xd fp32[64][32] (8192B) overlays TB(4352)+TC(4352)+yb2(4224)=12928B
    __shared__ __align__(16) unsigned char uni[12928];
    __shared__ __align__(16) float dpw_s[32][34];
    __shared__ float dpb_s[32];
    float* xd = (float*)uni;                          // [64][32]
    float (*TB)[68] = (float(*)[68])uni;              // [16][68]
    float (*TC)[68] = (float(*)[68])(uni + 4352);     // [16][68]
    uint (*yb2)[33] = (uint(*)[33])(uni + 8704);      // [32][33]
    int t = threadIdx.x;
    int bid = blockIdx.x;                 // 1024 = b(4) x dgG(16) x ch(16)
    int ch = bid & 15, dgG = (bid >> 4) & 15, b = bid >> 8;
    int d0 = dgG * 32;
    int bl0 = b * 1024 + ch * 64;
    {   // xd into union (sum of split-K partials)
        int l = t >> 3, k4 = (t & 7) * 4;
        size_t off = (size_t)(bl0 + l) * 64 + k4;
        float4 v0 = *(const float4*)(xdp + off);
        float4 v1 = *(const float4*)(xdp + 262144 + off);
        float4 v = make_float4(v0.x + v1.x, v0.y + v1.y, v0.z + v1.z, v0.w + v1.w);
        *(float4*)&xd[l * 32 + k4] = v;
    }
    if (t < 256) {   // Tu (bf16 -> fp32 at stage time)
        int l = t >> 2, d8 = (t & 3) * 8;
        uint4 p = *(const uint4*)(xlb + (size_t)(bl0 + l) * 512 + d0 + d8);
        Tu[d8 + 0][l] = bf2f((ushort)(p.x & 0xffffu));
        Tu[d8 + 1][l] = bf2f((ushort)(p.x >> 16));
        Tu[d8 + 2][l] = bf2f((ushort)(p.y & 0xffffu));
        Tu[d8 + 3][l] = bf2f((ushort)(p.y >> 16));
        Tu[d8 + 4][l] = bf2f((ushort)(p.z & 0xffffu));
        Tu[d8 + 5][l] = bf2f((ushort)(p.z >> 16));
        Tu[d8 + 6][l] = bf2f((ushort)(p.w & 0xffffu));
        Tu[d8 + 7][l] = bf2f((ushort)(p.w >> 16));
    }
    #pragma unroll
    for (int r = 0; r < 2; ++r) {
        int idx = r * 512 + t;
        int dd = idx >> 5, kk = idx & 31;
        dpw_s[dd][kk] = dpw[(size_t)(d0 + dd) * 32 + kk];
    }
    if (t < 32) dpb_s[t] = dpb[d0 + t];
    __syncthreads();
    {   // fused dt_proj (reads xd, vectorized)
        int dd = t & 31, lb = (t >> 5) * 4;
        #pragma unroll
        for (int j = 0; j < 4; ++j) {
            int l = lb + j;
            float s = dpb_s[dd];
            #pragma unroll
            for (int k4 = 0; k4 < 8; ++k4) {
                float4 xv = *(const float4*)&xd[l * 32 + k4 * 4];
                float2 wa = *(const float2*)&dpw_s[dd][k4 * 4];
                float2 wb = *(const float2*)&dpw_s[dd][k4 * 4 + 2];
                s = fmaf(xv.x, wa.x, s);
                s = fmaf(xv.y, wa.y, s);
                s = fmaf(xv.z, wb.x, s);
                s = fmaf(xv.w, wb.y, s);
            }
            Td[dd][l] = softplus_f(s);
        }
    }
    __syncthreads();   // xd dead; Td visible
    if (t < 256) {     // TB/TC over dead xd (sum of split-K partials)
        int l = t >> 2, n4 = (t & 3) * 4;
        size_t offb = (size_t)(bl0 + l) * 64 + 32 + n4;
        size_t offc = (size_t)(bl0 + l) * 64 + 48 + n4;
        float4 b0 = *(const float4*)(xdp + offb);
        float4 b1 = *(const float4*)(xdp + 262144 + offb);
        float4 c0 = *(const float4*)(xdp + offc);
        float4 c1 = *(const float4*)(xdp + 262144 + offc);
        TB[n4 + 0][l] = b0.x + b1.x; TB[n4 + 1][l] = b0.y + b1.y;
        TB[n4 + 2][l] = b0.z + b1.z; TB[n4 + 3][l] = b0.w + b1.w;
        TC[n4 + 0][l] = c0.x + c1.x; TC[n4 + 1][l] = c0.y + c1.y;
        TC[n4 + 2][l] = c0.z + c1.z; TC[n4 + 3][l] = c0.w + c1.w;
    }
    int w = t >> 6, lane = t & 63;
    int dl = lane >> 4, n = lane & 15;
    int col = w * 4 + dl;
    int d = d0 + col;
    float Ac = -__expf(alog[d * 16 + n]);
    float Dd = dssm[d];
    float h = 0.f;
    {   // chunk-prefix: fully unrolled, masked -> all loads issue in parallel
        size_t sbase = (size_t)(b * 128 + dgG * 8 + w) * 1024 + lane;
        #pragma unroll
        for (int cc = 0; cc < 15; ++cc) {
            float Pv = Psum[sbase + (size_t)cc * 64];
            float hv = hFsum[sbase + (size_t)cc * 64];
            bool use = cc < ch;
            Pv = use ? Pv : 1.f;
            hv = use ? hv : 0.f;
            h = fmaf(Pv, h, hv);
        }
    }
    __syncthreads();   // TB/TC visible
    for (int l4 = 0; l4 < 16; ++l4) {
        float4 de = *(const float4*)&Td[col][l4 * 4];
        float4 uu = *(const float4*)&Tu[col][l4 * 4];
        float4 Bv = *(const float4*)&TB[n][l4 * 4];
        float4 Cv = *(const float4*)&TC[n][l4 * 4];
        float a1 = __expf(de.x * Ac), a2 = __expf(de.y * Ac);
        float a3 = __expf(de.z * Ac), a4 = __expf(de.w * Ac);
        float b1 = de.x * Bv.x * uu.x, b2 = de.y * Bv.y * uu.y;
        float b3 = de.z * Bv.z * uu.z, b4 = de.w * Bv.w * uu.w;
        float a21 = a2 * a1,     b21 = fmaf(a2, b1, b2);
        float a321 = a3 * a21,   b321 = fmaf(a3, b21, b3);
        float a4321 = a4 * a321, b4321 = fmaf(a4, b321, b4);
        float h1 = fmaf(a1, h, b1);
        float h2 = fmaf(a21, h, b21);
        float h3 = fmaf(a321, h, b321);
        float h4 = fmaf(a4321, h, b4321);
        h = h4;
        float p0 = h1 * Cv.x, p1 = h2 * Cv.y, p2 = h3 * Cv.z, p3 = h4 * Cv.w;
        // 16-lane n-reduction via DPP row_shr: sum lands in lane n==15.
        DPP_ROW_SHR_ADD(p0, 1); DPP_ROW_SHR_ADD(p0, 2);
        DPP_ROW_SHR_ADD(p0, 4); DPP_ROW_SHR_ADD(p0, 8);
        DPP_ROW_SHR_ADD(p1, 1); DPP_ROW_SHR_ADD(p1, 2);
        DPP_ROW_SHR_ADD(p1, 4); DPP_ROW_SHR_ADD(p1, 8);
        DPP_ROW_SHR_ADD(p2, 1); DPP_ROW_SHR_ADD(p2, 2);
        DPP_ROW_SHR_ADD(p2, 4); DPP_ROW_SHR_ADD(p2, 8);
        DPP_ROW_SHR_ADD(p3, 1); DPP_ROW_SHR_ADD(p3, 2);
        DPP_ROW_SHR_ADD(p3, 4); DPP_ROW_SHR_ADD(p3, 8);
        if (n == 15) {
            int l2 = l4 * 2;
            float y0 = fmaf(uu.x, Dd, p0), y1 = fmaf(uu.y, Dd, p1);
            float y2 = fmaf(uu.z, Dd, p2), y3 = fmaf(uu.w, Dd, p3);
            yb2[l2 + 0][col] = (uint)f2bf(y0) | ((uint)f2bf(y1) << 16);
            yb2[l2 + 1][col] = (uint)f2bf(y2) | ((uint)f2bf(y3) << 16);
        }
    }
    __syncthreads();
    // gated store: 32 l2 x 32 col = 1024 items over 512 threads x 2
    size_t base = ((size_t)(b * 1024 + ch * 64)) * 512 + d0;   // ushort offset
    #pragma unroll
    for (int j = 0; j < 2; ++j) {
        int idx = j * 512 + t;
        int l2 = idx >> 5, col2 = idx & 31;
        uint yv = yb2[l2][col2];
        int l0 = l2 * 2;
        float r0 = bf2f(resb[base + (size_t)l0 * 512 + col2]);
        float r1 = bf2f(resb[base + (size_t)(l0 + 1) * 512 + col2]);
        float y0 = bf2f((ushort)(yv & 0xffffu)) * r0;
        float y1 = bf2f((ushort)(yv >> 16)) * r1;
        ybb[base + (size_t)l0 * 512 + col2] = f2bf(y0);
        ybb[base + (size_t)(l0 + 1) * 512 + col2] = f2bf(y1);
    }
}

// s[row] = LN(o[row])*g + b + s[row]; also writes bf16 copy sb. One wave/row.
__global__ __launch_bounds__(256) void ln_res_kernel(
    const float* __restrict__ o, const float* __restrict__ g,
    const float* __restrict__ bb, float* __restrict__ s, ushort* __restrict__ sb)
{
    int row = blockIdx.x * 4 + (threadIdx.x >> 6);
    int lane = threadIdx.x & 63;
    const float4* orow = (const float4*)(o + (size_t)row * 256);
    float4 v = orow[lane];
    float sum = v.x + v.y + v.z + v.w;
    float sq = v.x * v.x + v.y * v.y + v.z * v.z + v.w * v.w;
    #pragma unroll
    for (int off = 1; off < 64; off <<= 1) {
        sum += __shfl_xor(sum, off);
        sq += __shfl_xor(sq, off);
    }
    float m = sum * (1.f / 256.f);
    float var = sq * (1.f / 256.f) - m * m;
    float rstd = rsqrtf(var + 1e-5f);
    float4 gg = ((const float4*)g)[lane];
    float4 bv = ((const float4*)bb)[lane];
    float4* srow = (float4*)(s + (size_t)row * 256);
    float4 sv = srow[lane];
    sv.x += (v.x - m) * rstd * gg.x + bv.x;
    sv.y += (v.y - m) * rstd * gg.y + bv.y;
    sv.z += (v.z - m) * rstd * gg.z + bv.z;
    sv.w += (v.w - m) * rstd * gg.w + bv.w;
    srow[lane] = sv;
    uint2 pk;
    pk.x = (uint)f2bf(sv.x) | ((uint)f2bf(sv.y) << 16);
    pk.y = (uint)f2bf(sv.z) | ((uint)f2bf(sv.w) << 16);
    *(uint2*)(sb + (size_t)row * 256 + lane * 4) = pk;
}

// Stage 1 of mean-pool: 128 blocks (b x 32 chunks), each sums 32 l-rows
// coalesced -> partial[b][chunk][256].
__global__ __launch_bounds__(256) void pool_partial(
    const float* __restrict__ s, float* __restrict__ partial)
{
    int b = blockIdx.x >> 5, chunk = blockIdx.x & 31;
    int c = threadIdx.x;
    const float* p = s + (size_t)b * 262144 + (size_t)(chunk * 32) * 256 + c;
    float acc = 0.f;
    #pragma unroll
    for (int l = 0; l < 32; ++l) acc += p[(size_t)l * 256];
    partial[(size_t)blockIdx.x * 256 + c] = acc;
}

// Stage 2: sum 32 partials, then LN over 256 channels. grid 4 x 256.
__global__ __launch_bounds__(256) void pool_ln_final(
    const float* __restrict__ partial, const float* __restrict__ nw,
    const float* __restrict__ nb, float* __restrict__ sln)
{
    int b = blockIdx.x, c = threadIdx.x;
    const float* p = partial + (size_t)b * 32 * 256 + c;
    float acc = 0.f;
    #pragma unroll
    for (int k = 0; k < 32; ++k) acc += p[(size_t)k * 256];
    float pooled = acc * (1.f / 1024.f);
    __shared__ float rs[4], rq[4];
    float sum = pooled, sq = pooled * pooled;
    #pragma unroll
    for (int off = 1; off < 64; off <<= 1) {
        sum += __shfl_xor(sum, off);
        sq += __shfl_xor(sq, off);
    }
    int w = threadIdx.x >> 6;
    if ((threadIdx.x & 63) == 0) { rs[w] = sum; rq[w] = sq; }
    __syncthreads();
    sum = rs[0] + rs[1] + rs[2] + rs[3];
    sq = rq[0] + rq[1] + rq[2] + rq[3];
    float m = sum * (1.f / 256.f);
    float var = sq * (1.f / 256.f) - m * m;
    float rstd = rsqrtf(var + 1e-5f);
    sln[b * 256 + c] = (pooled - m) * rstd * nw[c] + nb[c];
}

// softmax over 1000 logits per b
__global__ __launch_bounds__(256) void softmax_kernel(float* __restrict__ out)
{
    int b = threadIdx.x >> 6, lane = threadIdx.x & 63;
    const float* lg = out + b * 1000;
    float v[16];
    float mx = -1e30f;
    #pragma unroll
    for (int j = 0; j < 16; ++j) {
        int i = lane + j * 64;
        v[j] = (i < 1000) ? lg[i] : -1e30f;
        mx = fmaxf(mx, v[j]);
    }
    #pragma unroll
    for (int off = 1; off < 64; off <<= 1) mx = fmaxf(mx, __shfl_xor(mx, off));
    float sum = 0.f;
    #pragma unroll
    for (int j = 0; j < 16; ++j) {
        int i = lane + j * 64;
        if (i < 1000) { v[j] = __expf(v[j] - mx); sum += v[j]; }
    }
    #pragma unroll
    for (int off = 1; off < 64; off <<= 1) sum += __shfl_xor(sum, off);
    float inv = 1.f / sum;
    float* so = out + 4000 + b * 1000;
    #pragma unroll
    for (int j = 0; j < 16; ++j) {
        int i = lane + j * 64;
        if (i < 1000) so[i] = v[j] * inv;
    }
}

// ---------------------------------------------------------------------------
extern "C" void kernel_launch(void* const* d_in, const int* in_sizes, int n_in,
                              void* d_out, int out_size, void* d_ws, size_t ws_size,
                              hipStream_t stream)
{
    const float* x    = (const float*)d_in[0];
    const float* c1w  = (const float*)d_in[1];
    const float* c1b  = (const float*)d_in[2];
    const float* g1   = (const float*)d_in[3];
    const float* b1   = (const float*)d_in[4];
    const float* c2w  = (const float*)d_in[5];
    const float* c2b  = (const float*)d_in[6];
    const float* g2   = (const float*)d_in[7];
    const float* b2   = (const float*)d_in[8];
    const float* pw   = (const float*)d_in[9];
    const float* pb   = (const float*)d_in[10];
    const float* g3   = (const float*)d_in[11];
    const float* b3   = (const float*)d_in[12];
    const float* ipw  = (const float*)d_in[13];
    const float* ipb  = (const float*)d_in[14];
    const float* cw   = (const float*)d_in[15];
    const float* cb   = (const float*)d_in[16];
    const float* xpw  = (const float*)d_in[17];
    const float* dpw  = (const float*)d_in[18];
    const float* dpb  = (const float*)d_in[19];
    const float* alog = (const float*)d_in[20];
    const float* dssm = (const float*)d_in[21];
    const float* opw  = (const float*)d_in[22];
    const float* opb  = (const float*)d_in[23];
    const float* lnw  = (const float*)d_in[24];
    const float* lnb  = (const float*)d_in[25];
    const float* nw   = (const float*)d_in[26];
    const float* nb   = (const float*)d_in[27];
    const float* fcw  = (const float*)d_in[28];
    const float* fcb  = (const float*)d_in[29];
    float* out = (float*)d_out;
    float* wsf = (float*)d_ws;

    float*  s_   = wsf;
    ushort* sb   = (ushort*)(wsf + 1048576);
    ushort* xib  = (ushort*)(wsf + 1572864);
    float*  obuf = wsf + 1572864;
    ushort* resb = (ushort*)(wsf + 3670016);
    ushort* xlb  = (ushort*)(wsf + 4718592);   // == u == ybb (in-place gate)
    ushort* ybb  = (ushort*)(wsf + 4718592);
    ushort* h1b  = (ushort*)(wsf + 4718592);
    ushort* Apb  = (ushort*)(wsf + 6815744);
    ushort* ipwb = (ushort*)(wsf + 9175040);
    ushort* opwb = (ushort*)(wsf + 9699328);
    ushort* w2b  = (ushort*)(wsf + 9961472);
    ushort* pwTb = (ushort*)(wsf + 10108928);
    float*  sln  = wsf + 10240000;
    float*  Psum = wsf + 10241024;             // [4][128][16][64] = 524288 fl
    float*  hFsum= wsf + 10765312;             // 524288 fl
    ushort* xpwb = (ushort*)(wsf + 11289600);  // 131072 ushorts; end 11355136 fl
    float*  pprt = wsf + 11355136;             // [4][32][256] = 32768 fl
    float*  xdp  = wsf + 11387904;             // [2][4096][64] = 524288 fl

    // --- fused weight prep (1 dispatch) ---
    hipLaunchKernelGGL(wprep, dim3(8832), dim3(256), 0, stream,
                       ipw, opw, c2w, pw, xpw, ipwb, opwb, w2b, pwTb, xpwb);

    // --- conv stem ---
    hipLaunchKernelGGL(conv1_nhwc, dim3(256), dim3(256), 0, stream, x, c1w, c1b, g1, b1, h1b);
    hipLaunchKernelGGL(conv2_mfma, dim3(128, 4), dim3(256), 0, stream, h1b, w2b, c2b, g2, b2, Apb);
    hipLaunchKernelGGL((mfma_gemm_bt<64, 64, 2>), dim3(64, 4), dim3(256), 0, stream,
                       Apb, 1024, pwTb, 1024, pb, g3, b3, s_, sb, nullptr, 256, 1024);

    // --- mamba blocks ---
    for (int i = 0; i < 4; ++i) {
        const ushort* ipwb_i = ipwb + (size_t)i * 1024 * 256;
        const float*  ipb_i  = ipb + i * 1024;
        const float*  cw_i   = cw + i * 512 * 4;
        const float*  cb_i   = cb + i * 512;
        const ushort* xpwb_i = xpwb + (size_t)i * 64 * 512;
        const float*  dpw_i  = dpw + (size_t)i * 512 * 32;
        const float*  dpb_i  = dpb + i * 512;
        const float*  alog_i = alog + (size_t)i * 512 * 16;
        const float*  dssm_i = dssm + i * 512;
        const ushort* opwb_i = opwb + (size_t)i * 256 * 512;
        const float*  opb_i  = opb + i * 256;
        const float*  lnw_i  = lnw + i * 256;
        const float*  lnb_i  = lnb + i * 256;

        hipLaunchKernelGGL((mfma_gemm_bt<64, 128, 3>), dim3(64, 8), dim3(256), 0, stream,
                           sb, 256, ipwb_i, 256, ipb_i, nullptr, nullptr,
                           nullptr, xib, resb, 0, 256);
        hipLaunchKernelGGL(dwconv, dim3(2048), dim3(256), 0, stream, xib, cw_i, cb_i, xlb);
        hipLaunchKernelGGL(xproj_gemm_sk, dim3(64, 2), dim3(256), 0, stream,
                           xlb, xpwb_i, xdp);
        hipLaunchKernelGGL(scan_part1, dim3(960), dim3(512), 0, stream,
                           xdp, xlb, dpw_i, dpb_i, alog_i, Psum, hFsum);
        hipLaunchKernelGGL(scan_part2, dim3(1024), dim3(512), 0, stream,
                           xdp, xlb, dpw_i, dpb_i, alog_i, dssm_i, resb, ybb, Psum, hFsum);
        hipLaunchKernelGGL((mfma_gemm_bt<64, 64, 0>), dim3(64, 4), dim3(256), 0, stream,
                           ybb, 512, opwb_i, 512, opb_i, nullptr, nullptr,
                           obuf, nullptr, nullptr, 256, 512);
        hipLaunchKernelGGL(ln_res_kernel, dim3(1024), dim3(256), 0, stream,
                           obuf, lnw_i, lnb_i, s_, sb);
    }

    // --- head ---
    hipLaunchKernelGGL(pool_partial, dim3(128), dim3(256), 0, stream, s_, pprt);
    hipLaunchKernelGGL(pool_ln_final, dim3(4), dim3(256), 0, stream, pprt, nw, nb, sln);
    hipLaunchKernelGGL((gemm_kernel<64, 64, 16, 4, 4>), dim3(1, 16), dim3(256), 0, stream,
                       sln, 256, fcw, 256, fcb, out, 1000, 4, 1000, 256, 0);
    hipLaunchKernelGGL(softmax_kernel, dim3(1), dim3(256), 0, stream, out);
}

// Round 13
// 575.750 us; speedup vs baseline: 1.2307x; 1.0004x over previous
//
#include <hip/hip_runtime.h>
#include <math.h>

// ---------------------------------------------------------------------------
// FastImageMamba forward. R25b: R24 (verified 576.0us) + exp2 pre-scaling in
// both scan hot loops: Ac2 = Ac*log2(e) once per thread, then exp2f(de*Ac2)
// (drops the implicit v_mul in every __expf; 64 VALU ops/thread/pass).
// (R25 failed to compile: __exp2f is not a HIP builtin -> use exp2f.)
// B=4, DM=256, NL=4, NC=1000, DI=512, NS=16, DTR=32, K=4, L=1024, H=W=64
// ---------------------------------------------------------------------------

#define BN_RSQ 0.99999500003749969f   // 1/sqrt(1+1e-5)
#define LOG2E  1.4426950408889634f

typedef unsigned int uint;
typedef unsigned short ushort;
typedef __bf16 bf16x8 __attribute__((ext_vector_type(8)));
typedef float floatx4 __attribute__((ext_vector_type(4)));

__device__ __forceinline__ float gelu_f(float v) {
    return 0.5f * v * (1.0f + erff(v * 0.70710678118654752f));
}
__device__ __forceinline__ float softplus_f(float v) {
    return (v > 20.f) ? v : log1pf(expf(v));
}
__device__ __forceinline__ ushort f2bf(float f) {
    uint x = __float_as_uint(f);
    x += 0x7fffu + ((x >> 16) & 1u);
    return (ushort)(x >> 16);
}
__device__ __forceinline__ float bf2f(ushort u) {
    return __uint_as_float((uint)u << 16);
}

// DPP row_shr:N add step: after N=1,2,4,8 lane 15 of each 16-lane row holds
// the row sum (bound_ctrl=1 -> out-of-row sources read 0).
#define DPP_ROW_SHR_ADD(x, N)                                               \
    x += __int_as_float(__builtin_amdgcn_update_dpp(                        \
        0, __float_as_int(x), 0x110 + (N), 0xf, 0xf, true))

// ---------------------------------------------------------------------------
// Fused weight prep: all fp32->bf16 weight conversions in one dispatch.
// ---------------------------------------------------------------------------
__global__ void wprep(const float* __restrict__ ipw, const float* __restrict__ opw,
                      const float* __restrict__ c2w, const float* __restrict__ pw,
                      const float* __restrict__ xpw,
                      ushort* __restrict__ ipwb, ushort* __restrict__ opwb,
                      ushort* __restrict__ w2b, ushort* __restrict__ pwTb,
                      ushort* __restrict__ xpwb)
{
    int idx = blockIdx.x * 256 + threadIdx.x;
    if (idx < 1048576) {
        ipwb[idx] = f2bf(ipw[idx]);
    } else if (idx < 1572864) {
        int i = idx - 1048576;
        opwb[i] = f2bf(opw[i]);
    } else if (idx < 1867776) {
        int i = idx - 1572864;
        int oc = i / 1152, k = i % 1152;
        int s = k >> 7, ic = k & 127;
        w2b[i] = f2bf(c2w[(size_t)(oc * 128 + ic) * 9 + s]);
    } else if (idx < 2129920) {
        int i = idx - 1867776;
        int oc = i >> 10, k = i & 1023;
        int s = k >> 8, ic = k & 255;
        int ky = s >> 1, kx = s & 1;
        pwTb[i] = f2bf(pw[((size_t)(oc * 256 + ic) * 2 + ky) * 2 + kx]);
    } else if (idx < 2260992) {
        int i = idx - 2129920;
        xpwb[i] = f2bf(xpw[i]);
    }
}

// ---------------------------------------------------------------------------
// conv1: 3x3 s1p1, IC=3 -> OC=128, NCHW fp32 in, NHWC bf16 out (+bias+BN+GELU)
// ---------------------------------------------------------------------------
__global__ __launch_bounds__(256) void conv1_nhwc(
    const float* __restrict__ x, const float* __restrict__ w,
    const float* __restrict__ cb, const float* __restrict__ g,
    const float* __restrict__ bb, ushort* __restrict__ out)
{
    __shared__ float tin[3][3][64];
    __shared__ float ws[3456];
    int t = threadIdx.x;
    int b = blockIdx.x >> 6, y = blockIdx.x & 63;
    for (int i = t; i < 3456; i += 256) ws[i] = w[i];
    for (int i = t; i < 576; i += 256) {
        int ic = i / 192, r = (i >> 6) % 3, xx = i & 63;
        int gy = y + r - 1;
        tin[ic][r][xx] = ((unsigned)gy < 64u) ? x[((b * 3 + ic) * 64 + gy) * 64 + xx] : 0.f;
    }
    __syncthreads();
    int tx = t & 15, ty = t >> 4;
    int oc0 = tx * 8, px0 = ty * 4;
    float acc[4][8];
    #pragma unroll
    for (int p = 0; p < 4; ++p)
        #pragma unroll
        for (int o = 0; o < 8; ++o) acc[p][o] = 0.f;
    for (int ic = 0; ic < 3; ++ic)
        #pragma unroll
        for (int ky = 0; ky < 3; ++ky)
            #pragma unroll
            for (int kx = 0; kx < 3; ++kx) {
                float av[4];
                #pragma unroll
                for (int p = 0; p < 4; ++p) {
                    int xx = px0 + p + kx - 1;
                    av[p] = ((unsigned)xx < 64u) ? tin[ic][ky][xx] : 0.f;
                }
                #pragma unroll
                for (int o = 0; o < 8; ++o) {
                    float wv = ws[(oc0 + o) * 27 + ic * 9 + ky * 3 + kx];
                    #pragma unroll
                    for (int p = 0; p < 4; ++p) acc[p][o] = fmaf(av[p], wv, acc[p][o]);
                }
            }
    #pragma unroll
    for (int p = 0; p < 4; ++p) {
        uint pk[4];
        #pragma unroll
        for (int o2 = 0; o2 < 4; ++o2) {
            int oc = oc0 + o2 * 2;
            float v0 = gelu_f((acc[p][o2 * 2] + cb[oc]) * (g[oc] * BN_RSQ) + bb[oc]);
            float v1 = gelu_f((acc[p][o2 * 2 + 1] + cb[oc + 1]) * (g[oc + 1] * BN_RSQ) + bb[oc + 1]);
            pk[o2] = (uint)f2bf(v0) | ((uint)f2bf(v1) << 16);
        }
        uint4 vv = make_uint4(pk[0], pk[1], pk[2], pk[3]);
        *(uint4*)(out + ((size_t)((b * 64 + y) * 64 + px0 + p)) * 128 + oc0) = vv;
    }
}

// ---------------------------------------------------------------------------
// bf16 MFMA GEMM (A @ W^T), BMxBN tile, BK=32, 4 waves (2x2), reg dbuf.
// EPI: 0 = +bias -> fp32 Cf[ldc]
//      2 = +bias,BN,GELU -> fp32 Cf + bf16 Cb (same ldc)
//      3 = in_proj: n<512 -> bf16 Cb[m*512+n]; n>=512 -> bf16 silu -> Cb2
// ---------------------------------------------------------------------------
template<int BM, int BN, int EPI>
__global__ __launch_bounds__(256, 2) void mfma_gemm_bt(
    const ushort* __restrict__ A, int lda,
    const ushort* __restrict__ W, int ldw,
    const float* __restrict__ bias,
    const float* __restrict__ bnG, const float* __restrict__ bnB,
    float* __restrict__ Cf, ushort* __restrict__ Cb, ushort* __restrict__ Cb2,
    int ldc, int K)
{
    constexpr int PAD = 40;
    constexpr int AP = BM / 64;
    constexpr int BP = BN / 64;
    constexpr int FM = BM / 32;
    constexpr int FN = BN / 32;
    __shared__ __align__(16) ushort As[BM * PAD];
    __shared__ __align__(16) ushort Bs[BN * PAD];
    int t = threadIdx.x;
    int m0 = blockIdx.x * BM, n0 = blockIdx.y * BN;
    int lane = t & 63, wid = t >> 6;
    int wm = (wid & 1) * (BM / 2), wn = (wid >> 1) * (BN / 2);
    int fr = lane & 15, fk = (lane >> 4) * 8;
    int r0 = t >> 2, c0 = (t & 3) * 8;
    floatx4 acc[FM][FN];
    #pragma unroll
    for (int i = 0; i < FM; ++i)
        #pragma unroll
        for (int j = 0; j < FN; ++j) acc[i][j] = {0.f, 0.f, 0.f, 0.f};
    uint4 ra[AP], rb[BP];
    #pragma unroll
    for (int p = 0; p < AP; ++p)
        ra[p] = *(const uint4*)(A + (size_t)(m0 + r0 + p * 64) * lda + c0);
    #pragma unroll
    for (int p = 0; p < BP; ++p)
        rb[p] = *(const uint4*)(W + (size_t)(n0 + r0 + p * 64) * ldw + c0);
    for (int k0 = 0; k0 < K; k0 += 32) {
        __syncthreads();
        #pragma unroll
        for (int p = 0; p < AP; ++p) *(uint4*)&As[(r0 + p * 64) * PAD + c0] = ra[p];
        #pragma unroll
        for (int p = 0; p < BP; ++p) *(uint4*)&Bs[(r0 + p * 64) * PAD + c0] = rb[p];
        __syncthreads();
        if (k0 + 32 < K) {
            #pragma unroll
            for (int p = 0; p < AP; ++p)
                ra[p] = *(const uint4*)(A + (size_t)(m0 + r0 + p * 64) * lda + k0 + 32 + c0);
            #pragma unroll
            for (int p = 0; p < BP; ++p)
                rb[p] = *(const uint4*)(W + (size_t)(n0 + r0 + p * 64) * ldw + k0 + 32 + c0);
        }
        bf16x8 af[FM], bw[FN];
        #pragma unroll
        for (int i = 0; i < FM; ++i)
            af[i] = *(const bf16x8*)&As[(wm + i * 16 + fr) * PAD + fk];
        #pragma unroll
        for (int j = 0; j < FN; ++j)
            bw[j] = *(const bf16x8*)&Bs[(wn + j * 16 + fr) * PAD + fk];
        #pragma unroll
        for (int i = 0; i < FM; ++i)
            #pragma unroll
            for (int j = 0; j < FN; ++j)
                acc[i][j] = __builtin_amdgcn_mfma_f32_16x16x32_bf16(af[i], bw[j], acc[i][j], 0, 0, 0);
    }
    int rbase = (lane >> 4) * 4, cc = lane & 15;
    #pragma unroll
    for (int j = 0; j < FN; ++j) {
        int n = n0 + wn + j * 16 + cc;
        float bv = bias ? bias[n] : 0.f;
        float scl = 0.f, shf = 0.f;
        if (EPI == 2) { scl = bnG[n] * BN_RSQ; shf = bnB[n]; }
        #pragma unroll
        for (int i = 0; i < FM; ++i) {
            #pragma unroll
            for (int r = 0; r < 4; ++r) {
                int m = m0 + wm + i * 16 + rbase + r;
                float v = acc[i][j][r] + bv;
                if (EPI == 2) v = gelu_f(v * scl + shf);
                if (EPI == 0) {
                    Cf[(size_t)m * ldc + n] = v;
                } else if (EPI == 2) {
                    Cf[(size_t)m * ldc + n] = v;
                    Cb[(size_t)m * ldc + n] = f2bf(v);
                } else {
                    if (n < 512) Cb[(size_t)m * 512 + n] = f2bf(v);
                    else Cb2[(size_t)m * 512 + (n - 512)] = f2bf(v / (1.f + __expf(-v)));
                }
            }
        }
    }
}

// ---------------------------------------------------------------------------
// xproj GEMM, split-K=2: grid (64,2). Slice y covers K in [y*256,(y+1)*256),
// writes fp32 partial to Cf + y*4096*64. Scans sum the two partials.
// BM=BN=64, BK=32, 4 waves. A=xlb [4096][512], W=xpwb [64][512].
// ---------------------------------------------------------------------------
__global__ __launch_bounds__(256, 2) void xproj_gemm_sk(
    const ushort* __restrict__ A, const ushort* __restrict__ W,
    float* __restrict__ Cf)
{
    constexpr int PAD = 40;
    __shared__ __align__(16) ushort As[64 * PAD];
    __shared__ __align__(16) ushort Bs[64 * PAD];
    int t = threadIdx.x;
    int m0 = blockIdx.x * 64;
    int koff = blockIdx.y * 256;
    float* Cfp = Cf + (size_t)blockIdx.y * 262144;
    int lane = t & 63, wid = t >> 6;
    int wm = (wid & 1) * 32, wn = (wid >> 1) * 32;
    int fr = lane & 15, fk = (lane >> 4) * 8;
    int r0 = t >> 2, c0 = (t & 3) * 8;
    floatx4 acc[2][2];
    #pragma unroll
    for (int i = 0; i < 2; ++i)
        #pragma unroll
        for (int j = 0; j < 2; ++j) acc[i][j] = {0.f, 0.f, 0.f, 0.f};
    uint4 ra, rb;
    ra = *(const uint4*)(A + (size_t)(m0 + r0) * 512 + koff + c0);
    rb = *(const uint4*)(W + (size_t)r0 * 512 + koff + c0);
    for (int k0 = 0; k0 < 256; k0 += 32) {
        __syncthreads();
        *(uint4*)&As[r0 * PAD + c0] = ra;
        *(uint4*)&Bs[r0 * PAD + c0] = rb;
        __syncthreads();
        if (k0 + 32 < 256) {
            ra = *(const uint4*)(A + (size_t)(m0 + r0) * 512 + koff + k0 + 32 + c0);
            rb = *(const uint4*)(W + (size_t)r0 * 512 + koff + k0 + 32 + c0);
        }
        bf16x8 af[2], bw[2];
        #pragma unroll
        for (int i = 0; i < 2; ++i)
            af[i] = *(const bf16x8*)&As[(wm + i * 16 + fr) * PAD + fk];
        #pragma unroll
        for (int j = 0; j < 2; ++j)
            bw[j] = *(const bf16x8*)&Bs[(wn + j * 16 + fr) * PAD + fk];
        #pragma unroll
        for (int i = 0; i < 2; ++i)
            #pragma unroll
            for (int j = 0; j < 2; ++j)
                acc[i][j] = __builtin_amdgcn_mfma_f32_16x16x32_bf16(af[i], bw[j], acc[i][j], 0, 0, 0);
    }
    int rbase = (lane >> 4) * 4, cc = lane & 15;
    #pragma unroll
    for (int j = 0; j < 2; ++j) {
        int n = wn + j * 16 + cc;
        #pragma unroll
        for (int i = 0; i < 2; ++i) {
            #pragma unroll
            for (int r = 0; r < 4; ++r) {
                int m = m0 + wm + i * 16 + rbase + r;
                Cfp[(size_t)m * 64 + n] = acc[i][j][r];
            }
        }
    }
}

// ---------------------------------------------------------------------------
// conv2: 9-shift implicit MFMA GEMM, 128px x 64oc tile, BK=64 (18 steps),
// reg dbuf with EXPLICIT SCALAR uint4s (array-by-ref spills to scratch).
// Writes DIRECTLY in im2col/Apb layout (im2col kernel deleted).
// ---------------------------------------------------------------------------
#define C2_LOAD(step)                                                            \
    {                                                                            \
        int s_ = (step) >> 1, ich_ = ((step) & 1) * 64;                          \
        int ky_ = s_ / 3, kx_ = s_ % 3;                                          \
        int sy_ = y0 + (ra_row >> 6) + ky_ - 1;                                  \
        int sx_ = (ra_row & 63) + kx_ - 1;                                       \
        bool v_ = ((unsigned)sy_ < 64u) && ((unsigned)sx_ < 64u);                \
        const ushort* ap_ = hb + ((size_t)(sy_ * 64 + sx_)) * 128 + ich_ + ra_c; \
        uint4 zz_ = make_uint4(0u, 0u, 0u, 0u);                                  \
        ra0 = v_ ? *(const uint4*)(ap_ + 0)  : zz_;                              \
        ra1 = v_ ? *(const uint4*)(ap_ + 8)  : zz_;                              \
        ra2 = v_ ? *(const uint4*)(ap_ + 16) : zz_;                              \
        ra3 = v_ ? *(const uint4*)(ap_ + 24) : zz_;                              \
        const ushort* wp_ = w2b + (size_t)(n0 + rb_row) * 1152 + s_ * 128 + ich_ + rb_c; \
        rb0 = *(const uint4*)(wp_ + 0);                                          \
        rb1 = *(const uint4*)(wp_ + 8);                                          \
    }

__global__ __launch_bounds__(256, 2) void conv2_mfma(
    const ushort* __restrict__ h1b, const ushort* __restrict__ w2b,
    const float* __restrict__ cb, const float* __restrict__ g,
    const float* __restrict__ bb, ushort* __restrict__ Apb)
{
    constexpr int PAD = 72;
    __shared__ __align__(16) ushort As[128 * PAD];
    __shared__ __align__(16) ushort Bs[64 * PAD];
    int t = threadIdx.x;
    int m0 = blockIdx.x * 128, n0 = blockIdx.y * 64;
    int b = m0 >> 12;
    int y0 = (m0 & 4095) >> 6;
    int lane = t & 63, wid = t >> 6;
    int wm = (wid & 1) * 64, wn = (wid >> 1) * 32;
    int fr = lane & 15, fk = (lane >> 4) * 8;
    int ra_row = t >> 1, ra_c = (t & 1) * 32;
    int rb_row = t >> 2, rb_c = (t & 3) * 16;
    floatx4 acc[4][2];
    #pragma unroll
    for (int i = 0; i < 4; ++i)
        #pragma unroll
        for (int j = 0; j < 2; ++j) acc[i][j] = {0.f, 0.f, 0.f, 0.f};
    const ushort* hb = h1b + (size_t)b * 4096 * 128;

    uint4 ra0, ra1, ra2, ra3, rb0, rb1;
    C2_LOAD(0);
    for (int step = 0; step < 18; ++step) {
        __syncthreads();
        *(uint4*)&As[ra_row * PAD + ra_c + 0]  = ra0;
        *(uint4*)&As[ra_row * PAD + ra_c + 8]  = ra1;
        *(uint4*)&As[ra_row * PAD + ra_c + 16] = ra2;
        *(uint4*)&As[ra_row * PAD + ra_c + 24] = ra3;
        *(uint4*)&Bs[rb_row * PAD + rb_c + 0]  = rb0;
        *(uint4*)&Bs[rb_row * PAD + rb_c + 8]  = rb1;
        __syncthreads();
        if (step + 1 < 18) C2_LOAD(step + 1);
        #pragma unroll
        for (int ks = 0; ks < 64; ks += 32) {
            bf16x8 af[4], bw[2];
            #pragma unroll
            for (int i = 0; i < 4; ++i)
                af[i] = *(const bf16x8*)&As[(wm + i * 16 + fr) * PAD + ks + fk];
            #pragma unroll
            for (int j = 0; j < 2; ++j)
                bw[j] = *(const bf16x8*)&Bs[(wn + j * 16 + fr) * PAD + ks + fk];
            #pragma unroll
            for (int i = 0; i < 4; ++i)
                #pragma unroll
                for (int j = 0; j < 2; ++j)
                    acc[i][j] = __builtin_amdgcn_mfma_f32_16x16x32_bf16(af[i], bw[j], acc[i][j], 0, 0, 0);
        }
    }
    int rbase = (lane >> 4) * 4, cc = lane & 15;
    #pragma unroll
    for (int j = 0; j < 2; ++j) {
        int n = n0 + wn + j * 16 + cc;
        float scl = g[n] * BN_RSQ, shf = bb[n], bv2 = cb[n];
        #pragma unroll
        for (int i = 0; i < 4; ++i) {
            #pragma unroll
            for (int r = 0; r < 4; ++r) {
                int m = m0 + wm + i * 16 + rbase + r;   // b*4096 + y*64 + x
                float v = gelu_f((acc[i][j][r] + bv2) * scl + shf);
                int yy = (m >> 6) & 63, xx = m & 63;
                int arow = (m >> 12) * 1024 + (yy >> 1) * 32 + (xx >> 1);
                int acol = ((yy & 1) * 2 + (xx & 1)) * 256 + n;
                Apb[(size_t)arow * 1024 + acol] = f2bf(v);
            }
        }
    }
}

// ---------------------------------------------------------------------------
// fp32 tiled GEMM (reg dbuf): head FC only.
// ---------------------------------------------------------------------------
template<int BM, int BN, int BK, int TM, int TN>
__global__ __launch_bounds__(256) void gemm_kernel(
    const float* __restrict__ A, int lda,
    const float* __restrict__ W, int ldw,
    const float* __restrict__ bias,
    float* __restrict__ C, int ldc,
    int M, int N, int K, int act)
{
    static_assert(BM * BK / 4 == 256 && BN * BK / 4 == 256, "staging shape");
    __shared__ float As[BK][BM + 4];
    __shared__ float Bs[BK][BN + 4];
    int t = threadIdx.x;
    int m0 = blockIdx.x * BM, n0 = blockIdx.y * BN;
    float acc[TM][TN];
    #pragma unroll
    for (int i = 0; i < TM; i++)
        #pragma unroll
        for (int j = 0; j < TN; j++) acc[i][j] = 0.f;
    const int LPR = BK / 4;
    int lr = t / LPR, lc4 = (t % LPR) * 4;
    int ty = t >> 4, tx = t & 15;
    int ma = m0 + lr, nb = n0 + lr;
    float4 va = make_float4(0.f, 0.f, 0.f, 0.f);
    float4 vb = make_float4(0.f, 0.f, 0.f, 0.f);
    if (ma < M) va = *(const float4*)(A + (size_t)ma * lda + lc4);
    if (nb < N) vb = *(const float4*)(W + (size_t)nb * ldw + lc4);
    for (int k0 = 0; k0 < K; k0 += BK) {
        __syncthreads();
        As[lc4 + 0][lr] = va.x; As[lc4 + 1][lr] = va.y;
        As[lc4 + 2][lr] = va.z; As[lc4 + 3][lr] = va.w;
        Bs[lc4 + 0][lr] = vb.x; Bs[lc4 + 1][lr] = vb.y;
        Bs[lc4 + 2][lr] = vb.z; Bs[lc4 + 3][lr] = vb.w;
        __syncthreads();
        if (k0 + BK < K) {
            if (ma < M) va = *(const float4*)(A + (size_t)ma * lda + k0 + BK + lc4);
            if (nb < N) vb = *(const float4*)(W + (size_t)nb * ldw + k0 + BK + lc4);
        }
        #pragma unroll
        for (int kk = 0; kk < BK; ++kk) {
            float a[TM], bfr[TN];
            #pragma unroll
            for (int i = 0; i < TM; i += 4)
                *(float4*)&a[i] = *(const float4*)&As[kk][ty * TM + i];
            #pragma unroll
            for (int j = 0; j < TN; j += 4)
                *(float4*)&bfr[j] = *(const float4*)&Bs[kk][tx * TN + j];
            #pragma unroll
            for (int i = 0; i < TM; i++)
                #pragma unroll
                for (int j = 0; j < TN; j++) acc[i][j] = fmaf(a[i], bfr[j], acc[i][j]);
        }
    }
    #pragma unroll
    for (int i = 0; i < TM; i++) {
        int m = m0 + ty * TM + i;
        if (m >= M) continue;
        #pragma unroll
        for (int j = 0; j < TN; j++) {
            int n = n0 + tx * TN + j;
            if (n >= N) continue;
            float v = acc[i][j];
            if (bias) v += bias[n];
            if (act == 2) v = softplus_f(v);
            C[(size_t)m * ldc + n] = v;
        }
    }
}

// ---------------------------------------------------------------------------
// Depthwise conv1d (K=4, pad(1,2)) in [b,l,d], bf16 in -> bf16 out (xlb == u).
// ---------------------------------------------------------------------------
__global__ __launch_bounds__(256) void dwconv(
    const ushort* __restrict__ xib, const float* __restrict__ cw,
    const float* __restrict__ cb, ushort* __restrict__ xlb)
{
    int idx = blockIdx.x * 256 + threadIdx.x;   // 524288
    int d4 = (idx & 127) * 4;
    int bl = idx >> 7;
    int b = bl >> 10, l = bl & 1023;
    float4 w0 = *(const float4*)(cw + d4 * 4);
    float4 w1 = *(const float4*)(cw + d4 * 4 + 4);
    float4 w2 = *(const float4*)(cw + d4 * 4 + 8);
    float4 w3 = *(const float4*)(cw + d4 * 4 + 12);
    float4 acc = *(const float4*)(cb + d4);
    const ushort* rowb = xib + ((size_t)b << 19) + d4;
    #pragma unroll
    for (int k = 0; k < 4; ++k) {
        int ll = l + k - 1;
        if ((unsigned)ll < 1024u) {
            uint2 p = *(const uint2*)(rowb + (size_t)ll * 512);
            acc.x = fmaf(bf2f((ushort)(p.x & 0xffffu)), ((const float*)&w0)[k], acc.x);
            acc.y = fmaf(bf2f((ushort)(p.x >> 16)),     ((const float*)&w1)[k], acc.y);
            acc.z = fmaf(bf2f((ushort)(p.y & 0xffffu)), ((const float*)&w2)[k], acc.z);
            acc.w = fmaf(bf2f((ushort)(p.y >> 16)),     ((const float*)&w3)[k], acc.w);
        }
    }
    uint2 pk;
    pk.x = (uint)f2bf(acc.x) | ((uint)f2bf(acc.y) << 16);
    pk.y = (uint)f2bf(acc.z) | ((uint)f2bf(acc.w) << 16);
    *(uint2*)(xlb + (size_t)bl * 512 + d4) = pk;
}

// ---------------------------------------------------------------------------
// Chunked scan pass 1 (fused dt_proj, 4-step composition, fp32 LDS staging).
// 15 chunks of 64 timesteps (chunk 15's summary is never read): grid 960.
// xdp = [2][4096][64] split-K partials; staging sums them. exp2 pre-scale.
// ---------------------------------------------------------------------------
__global__ __launch_bounds__(512, 8) void scan_part1(
    const float* __restrict__ xdp, const ushort* __restrict__ xlb,
    const float* __restrict__ dpw, const float* __restrict__ dpb,
    const float* __restrict__ alog,
    float* __restrict__ Psum, float* __restrict__ hFsum)
{
    __shared__ __align__(16) float Td[32][68];
    __shared__ __align__(16) float Tu[32][68];
    __shared__ __align__(16) float TB[16][68];
    __shared__ __align__(16) float xd[64][32];
    __shared__ __align__(16) float dpw_s[32][34];
    __shared__ float dpb_s[32];
    int t = threadIdx.x;
    int bid = blockIdx.x;                 // 960 = b(4) x dgG(16) x ch(15)
    int ch = bid % 15;
    int gq = bid / 15;
    int dgG = gq & 15, b = gq >> 4;
    int d0 = dgG * 32;
    int bl0 = b * 1024 + ch * 64;
    {   // xd: 64 l x 32 k, sum of two split-K partials
        int l = t >> 3, k4 = (t & 7) * 4;
        size_t off = (size_t)(bl0 + l) * 64 + k4;
        float4 v0 = *(const float4*)(xdp + off);
        float4 v1 = *(const float4*)(xdp + 262144 + off);
        float4 v = make_float4(v0.x + v1.x, v0.y + v1.y, v0.z + v1.z, v0.w + v1.w);
        *(float4*)&xd[l][k4] = v;
    }
    if (t < 256) {   // Tu: 64 l x 32 d (bf16 -> fp32 at stage time)
        int l = t >> 2, d8 = (t & 3) * 8;
        uint4 p = *(const uint4*)(xlb + (size_t)(bl0 + l) * 512 + d0 + d8);
        Tu[d8 + 0][l] = bf2f((ushort)(p.x & 0xffffu));
        Tu[d8 + 1][l] = bf2f((ushort)(p.x >> 16));
        Tu[d8 + 2][l] = bf2f((ushort)(p.y & 0xffffu));
        Tu[d8 + 3][l] = bf2f((ushort)(p.y >> 16));
        Tu[d8 + 4][l] = bf2f((ushort)(p.z & 0xffffu));
        Tu[d8 + 5][l] = bf2f((ushort)(p.z >> 16));
        Tu[d8 + 6][l] = bf2f((ushort)(p.w & 0xffffu));
        Tu[d8 + 7][l] = bf2f((ushort)(p.w >> 16));
    } else {         // TB: 64 l x 16 n, sum of partials
        int tt = t - 256;
        int l = tt >> 2, n4 = (tt & 3) * 4;
        size_t off = (size_t)(bl0 + l) * 64 + 32 + n4;
        float4 b0 = *(const float4*)(xdp + off);
        float4 b1 = *(const float4*)(xdp + 262144 + off);
        TB[n4 + 0][l] = b0.x + b1.x; TB[n4 + 1][l] = b0.y + b1.y;
        TB[n4 + 2][l] = b0.z + b1.z; TB[n4 + 3][l] = b0.w + b1.w;
    }
    #pragma unroll
    for (int r = 0; r < 2; ++r) {
        int idx = r * 512 + t;
        int dd = idx >> 5, kk = idx & 31;
        dpw_s[dd][kk] = dpw[(size_t)(d0 + dd) * 32 + kk];
    }
    if (t < 32) dpb_s[t] = dpb[d0 + t];
    __syncthreads();
    {   // fused dt_proj: 32 dd x 64 l, 4 entries/thread (vectorized reads)
        int dd = t & 31, lb = (t >> 5) * 4;
        #pragma unroll
        for (int j = 0; j < 4; ++j) {
            int l = lb + j;
            float s = dpb_s[dd];
            #pragma unroll
            for (int k4 = 0; k4 < 8; ++k4) {
                float4 xv = *(const float4*)&xd[l][k4 * 4];
                float2 wa = *(const float2*)&dpw_s[dd][k4 * 4];
                float2 wb = *(const float2*)&dpw_s[dd][k4 * 4 + 2];
                s = fmaf(xv.x, wa.x, s);
                s = fmaf(xv.y, wa.y, s);
                s = fmaf(xv.z, wb.x, s);
                s = fmaf(xv.w, wb.y, s);
            }
            Td[dd][l] = softplus_f(s);
        }
    }
    __syncthreads();
    int w = t >> 6, lane = t & 63;
    int dl = lane >> 4, n = lane & 15;
    int col = w * 4 + dl;
    int d = d0 + col;
    float Ac2 = -__expf(alog[d * 16 + n]) * LOG2E;   // pre-scaled for exp2
    float h = 0.f, P = 1.f;
    for (int l4 = 0; l4 < 16; ++l4) {
        float4 de = *(const float4*)&Td[col][l4 * 4];
        float4 uu = *(const float4*)&Tu[col][l4 * 4];
        float4 Bv = *(const float4*)&TB[n][l4 * 4];
        float a1 = exp2f(de.x * Ac2), a2 = exp2f(de.y * Ac2);
        float a3 = exp2f(de.z * Ac2), a4 = exp2f(de.w * Ac2);
        float b1 = de.x * Bv.x * uu.x, b2 = de.y * Bv.y * uu.y;
        float b3 = de.z * Bv.z * uu.z, b4 = de.w * Bv.w * uu.w;
        float a21 = a2 * a1,     b21 = fmaf(a2, b1, b2);
        float a321 = a3 * a21,   b321 = fmaf(a3, b21, b3);
        float a4321 = a4 * a321, b4321 = fmaf(a4, b321, b4);
        h = fmaf(a4321, h, b4321);
        P *= a4321;
    }
    size_t si = ((size_t)(b * 128 + dgG * 8 + w) * 16 + ch) * 64 + lane;
    Psum[si] = P;
    hFsum[si] = h;
}

// ---------------------------------------------------------------------------
// Chunked scan pass 2 (fused dt_proj, 4-step composition, fp32 LDS staging,
// DPP row_shr n-reduction, packed yb2, xd overlaid on TB/TC/yb2 union,
// masked-unrolled chunk-prefix loads, exp2 pre-scale). ~34.5KB LDS.
// ---------------------------------------------------------------------------
__global__ __launch_bounds__(512, 8) void scan_part2(
    const float* __restrict__ xdp, const ushort* __restrict__ xlb,
    const float* __restrict__ dpw, const float* __restrict__ dpb,
    const float* __restrict__ alog, const float* __restrict__ dssm,
    const ushort* __restrict__ resb, ushort* __restrict__ ybb,
    const float* __restrict__ Psum, const float* __restrict__ hFsum)
{
    __shared__ __align__(16) float Td[32][68];
    __shared__ __align__(16) float Tu[32][68];
    // union: xd fp32[64][32] (8192B) overlays TB(4352)+TC(4352)+yb2(4224)=12928B
    __shared__ __align__(16) unsigned char uni[12928];
    __shared__ __align__(16) float dpw_s[32][34];
    __shared__ float dpb_s[32];
    float* xd = (float*)uni;                          // [64][32]
    float (*TB)[68] = (float(*)[68])uni;              // [16][68]
    float (*TC)[68] = (float(*)[68])(uni + 4352);     // [16][68]
    uint (*yb2)[33] = (uint(*)[33])(uni + 8704);      // [32][33]
    int t = threadIdx.x;
    int bid = blockIdx.x;                 // 1024 = b(4) x dgG(16) x ch(16)
    int ch = bid & 15, dgG = (bid >> 4) & 15, b = bid >> 8;
    int d0 = dgG * 32;
    int bl0 = b * 1024 + ch * 64;
    {   // xd into union (sum of split-K partials)
        int l = t >> 3, k4 = (t & 7) * 4;
        size_t off = (size_t)(bl0 + l) * 64 + k4;
        float4 v0 = *(const float4*)(xdp + off);
        float4 v1 = *(const float4*)(xdp + 262144 + off);
        float4 v = make_float4(v0.x + v1.x, v0.y + v1.y, v0.z + v1.z, v0.w + v1.w);
        *(float4*)&xd[l * 32 + k4] = v;
    }
    if (t < 256) {   // Tu (bf16 -> fp32 at stage time)
        int l = t >> 2, d8 = (t & 3) * 8;
        uint4 p = *(const uint4*)(xlb + (size_t)(bl0 + l) * 512 + d0 + d8);
        Tu[d8 + 0][l] = bf2f((ushort)(p.x & 0xffffu));
        Tu[d8 + 1][l] = bf2f((ushort)(p.x >> 16));
        Tu[d8 + 2][l] = bf2f((ushort)(p.y & 0xffffu));
        Tu[d8 + 3][l] = bf2f((ushort)(p.y >> 16));
        Tu[d8 + 4][l] = bf2f((ushort)(p.z & 0xffffu));
        Tu[d8 + 5][l] = bf2f((ushort)(p.z >> 16));
        Tu[d8 + 6][l] = bf2f((ushort)(p.w & 0xffffu));
        Tu[d8 + 7][l] = bf2f((ushort)(p.w >> 16));
    }
    #pragma unroll
    for (int r = 0; r < 2; ++r) {
        int idx = r * 512 + t;
        int dd = idx >> 5, kk = idx & 31;
        dpw_s[dd][kk] = dpw[(size_t)(d0 + dd) * 32 + kk];
    }
    if (t < 32) dpb_s[t] = dpb[d0 + t];
    __syncthreads();
    {   // fused dt_proj (reads xd, vectorized)
        int dd = t & 31, lb = (t >> 5) * 4;
        #pragma unroll
        for (int j = 0; j < 4; ++j) {
            int l = lb + j;
            float s = dpb_s[dd];
            #pragma unroll
            for (int k4 = 0; k4 < 8; ++k4) {
                float4 xv = *(const float4*)&xd[l * 32 + k4 * 4];
                float2 wa = *(const float2*)&dpw_s[dd][k4 * 4];
                float2 wb = *(const float2*)&dpw_s[dd][k4 * 4 + 2];
                s = fmaf(xv.x, wa.x, s);
                s = fmaf(xv.y, wa.y, s);
                s = fmaf(xv.z, wb.x, s);
                s = fmaf(xv.w, wb.y, s);
            }
            Td[dd][l] = softplus_f(s);
        }
    }
    __syncthreads();   // xd dead; Td visible
    if (t < 256) {     // TB/TC over dead xd (sum of split-K partials)
        int l = t >> 2, n4 = (t & 3) * 4;
        size_t offb = (size_t)(bl0 + l) * 64 + 32 + n4;
        size_t offc = (size_t)(bl0 + l) * 64 + 48 + n4;
        float4 b0 = *(const float4*)(xdp + offb);
        float4 b1 = *(const float4*)(xdp + 262144 + offb);
        float4 c0 = *(const float4*)(xdp + offc);
        float4 c1 = *(const float4*)(xdp + 262144 + offc);
        TB[n4 + 0][l] = b0.x + b1.x; TB[n4 + 1][l] = b0.y + b1.y;
        TB[n4 + 2][l] = b0.z + b1.z; TB[n4 + 3][l] = b0.w + b1.w;
        TC[n4 + 0][l] = c0.x + c1.x; TC[n4 + 1][l] = c0.y + c1.y;
        TC[n4 + 2][l] = c0.z + c1.z; TC[n4 + 3][l] = c0.w + c1.w;
    }
    int w = t >> 6, lane = t & 63;
    int dl = lane >> 4, n = lane & 15;
    int col = w * 4 + dl;
    int d = d0 + col;
    float Ac2 = -__expf(alog[d * 16 + n]) * LOG2E;   // pre-scaled for exp2
    float Dd = dssm[d];
    float h = 0.f;
    {   // chunk-prefix: fully unrolled, masked -> all loads issue in parallel
        size_t sbase = (size_t)(b * 128 + dgG * 8 + w) * 1024 + lane;
        #pragma unroll
        for (int cc = 0; cc < 15; ++cc) {
            float Pv = Psum[sbase + (size_t)cc * 64];
            float hv = hFsum[sbase + (size_t)cc * 64];
            bool use = cc < ch;
            Pv = use ? Pv : 1.f;
            hv = use ? hv : 0.f;
            h = fmaf(Pv, h, hv);
        }
    }
    __syncthreads();   // TB/TC visible
    for (int l4 = 0; l4 < 16; ++l4) {
        float4 de = *(const float4*)&Td[col][l4 * 4];
        float4 uu = *(const float4*)&Tu[col][l4 * 4];
        float4 Bv = *(const float4*)&TB[n][l4 * 4];
        float4 Cv = *(const float4*)&TC[n][l4 * 4];
        float a1 = exp2f(de.x * Ac2), a2 = exp2f(de.y * Ac2);
        float a3 = exp2f(de.z * Ac2), a4 = exp2f(de.w * Ac2);
        float b1 = de.x * Bv.x * uu.x, b2 = de.y * Bv.y * uu.y;
        float b3 = de.z * Bv.z * uu.z, b4 = de.w * Bv.w * uu.w;
        float a21 = a2 * a1,     b21 = fmaf(a2, b1, b2);
        float a321 = a3 * a21,   b321 = fmaf(a3, b21, b3);
        float a4321 = a4 * a321, b4321 = fmaf(a4, b321, b4);
        float h1 = fmaf(a1, h, b1);
        float h2 = fmaf(a21, h, b21);
        float h3 = fmaf(a321, h, b321);
        float h4 = fmaf(a4321, h, b4321);
        h = h4;
        float p0 = h1 * Cv.x, p1 = h2 * Cv.y, p2 = h3 * Cv.z, p3 = h4 * Cv.w;
        // 16-lane n-reduction via DPP row_shr: sum lands in lane n==15.
        DPP_ROW_SHR_ADD(p0, 1); DPP_ROW_SHR_ADD(p0, 2);
        DPP_ROW_SHR_ADD(p0, 4); DPP_ROW_SHR_ADD(p0, 8);
        DPP_ROW_SHR_ADD(p1, 1); DPP_ROW_SHR_ADD(p1, 2);
        DPP_ROW_SHR_ADD(p1, 4); DPP_ROW_SHR_ADD(p1, 8);
        DPP_ROW_SHR_ADD(p2, 1); DPP_ROW_SHR_ADD(p2, 2);
        DPP_ROW_SHR_ADD(p2, 4); DPP_ROW_SHR_ADD(p2, 8);
        DPP_ROW_SHR_ADD(p3, 1); DPP_ROW_SHR_ADD(p3, 2);
        DPP_ROW_SHR_ADD(p3, 4); DPP_ROW_SHR_ADD(p3, 8);
        if (n == 15) {
            int l2 = l4 * 2;
            float y0 = fmaf(uu.x, Dd, p0), y1 = fmaf(uu.y, Dd, p1);
            float y2 = fmaf(uu.z, Dd, p2), y3 = fmaf(uu.w, Dd, p3);
            yb2[l2 + 0][col] = (uint)f2bf(y0) | ((uint)f2bf(y1) << 16);
            yb2[l2 + 1][col] = (uint)f2bf(y2) | ((uint)f2bf(y3) << 16);
        }
    }
    __syncthreads();
    // gated store: 32 l2 x 32 col = 1024 items over 512 threads x 2
    size_t base = ((size_t)(b * 1024 + ch * 64)) * 512 + d0;   // ushort offset
    #pragma unroll
    for (int j = 0; j < 2; ++j) {
        int idx = j * 512 + t;
        int l2 = idx >> 5, col2 = idx & 31;
        uint yv = yb2[l2][col2];
        int l0 = l2 * 2;
        float r0 = bf2f(resb[base + (size_t)l0 * 512 + col2]);
        float r1 = bf2f(resb[base + (size_t)(l0 + 1) * 512 + col2]);
        float y0 = bf2f((ushort)(yv & 0xffffu)) * r0;
        float y1 = bf2f((ushort)(yv >> 16)) * r1;
        ybb[base + (size_t)l0 * 512 + col2] = f2bf(y0);
        ybb[base + (size_t)(l0 + 1) * 512 + col2] = f2bf(y1);
    }
}

// s[row] = LN(o[row])*g + b + s[row]; also writes bf16 copy sb. One wave/row.
__global__ __launch_bounds__(256) void ln_res_kernel(
    const float* __restrict__ o, const float* __restrict__ g,
    const float* __restrict__ bb, float* __restrict__ s, ushort* __restrict__ sb)
{
    int row = blockIdx.x * 4 + (threadIdx.x >> 6);
    int lane = threadIdx.x & 63;
    const float4* orow = (const float4*)(o + (size_t)row * 256);
    float4 v = orow[lane];
    float sum = v.x + v.y + v.z + v.w;
    float sq = v.x * v.x + v.y * v.y + v.z * v.z + v.w * v.w;
    #pragma unroll
    for (int off = 1; off < 64; off <<= 1) {
        sum += __shfl_xor(sum, off);
        sq += __shfl_xor(sq, off);
    }
    float m = sum * (1.f / 256.f);
    float var = sq * (1.f / 256.f) - m * m;
    float rstd = rsqrtf(var + 1e-5f);
    float4 gg = ((const float4*)g)[lane];
    float4 bv = ((const float4*)bb)[lane];
    float4* srow = (float4*)(s + (size_t)row * 256);
    float4 sv = srow[lane];
    sv.x += (v.x - m) * rstd * gg.x + bv.x;
    sv.y += (v.y - m) * rstd * gg.y + bv.y;
    sv.z += (v.z - m) * rstd * gg.z + bv.z;
    sv.w += (v.w - m) * rstd * gg.w + bv.w;
    srow[lane] = sv;
    uint2 pk;
    pk.x = (uint)f2bf(sv.x) | ((uint)f2bf(sv.y) << 16);
    pk.y = (uint)f2bf(sv.z) | ((uint)f2bf(sv.w) << 16);
    *(uint2*)(sb + (size_t)row * 256 + lane * 4) = pk;
}

// Stage 1 of mean-pool: 128 blocks (b x 32 chunks), each sums 32 l-rows
// coalesced -> partial[b][chunk][256].
__global__ __launch_bounds__(256) void pool_partial(
    const float* __restrict__ s, float* __restrict__ partial)
{
    int b = blockIdx.x >> 5, chunk = blockIdx.x & 31;
    int c = threadIdx.x;
    const float* p = s + (size_t)b * 262144 + (size_t)(chunk * 32) * 256 + c;
    float acc = 0.f;
    #pragma unroll
    for (int l = 0; l < 32; ++l) acc += p[(size_t)l * 256];
    partial[(size_t)blockIdx.x * 256 + c] = acc;
}

// Stage 2: sum 32 partials, then LN over 256 channels. grid 4 x 256.
__global__ __launch_bounds__(256) void pool_ln_final(
    const float* __restrict__ partial, const float* __restrict__ nw,
    const float* __restrict__ nb, float* __restrict__ sln)
{
    int b = blockIdx.x, c = threadIdx.x;
    const float* p = partial + (size_t)b * 32 * 256 + c;
    float acc = 0.f;
    #pragma unroll
    for (int k = 0; k < 32; ++k) acc += p[(size_t)k * 256];
    float pooled = acc * (1.f / 1024.f);
    __shared__ float rs[4], rq[4];
    float sum = pooled, sq = pooled * pooled;
    #pragma unroll
    for (int off = 1; off < 64; off <<= 1) {
        sum += __shfl_xor(sum, off);
        sq += __shfl_xor(sq, off);
    }
    int w = threadIdx.x >> 6;
    if ((threadIdx.x & 63) == 0) { rs[w] = sum; rq[w] = sq; }
    __syncthreads();
    sum = rs[0] + rs[1] + rs[2] + rs[3];
    sq = rq[0] + rq[1] + rq[2] + rq[3];
    float m = sum * (1.f / 256.f);
    float var = sq * (1.f / 256.f) - m * m;
    float rstd = rsqrtf(var + 1e-5f);
    sln[b * 256 + c] = (pooled - m) * rstd * nw[c] + nb[c];
}

// softmax over 1000 logits per b
__global__ __launch_bounds__(256) void softmax_kernel(float* __restrict__ out)
{
    int b = threadIdx.x >> 6, lane = threadIdx.x & 63;
    const float* lg = out + b * 1000;
    float v[16];
    float mx = -1e30f;
    #pragma unroll
    for (int j = 0; j < 16; ++j) {
        int i = lane + j * 64;
        v[j] = (i < 1000) ? lg[i] : -1e30f;
        mx = fmaxf(mx, v[j]);
    }
    #pragma unroll
    for (int off = 1; off < 64; off <<= 1) mx = fmaxf(mx, __shfl_xor(mx, off));
    float sum = 0.f;
    #pragma unroll
    for (int j = 0; j < 16; ++j) {
        int i = lane + j * 64;
        if (i < 1000) { v[j] = __expf(v[j] - mx); sum += v[j]; }
    }
    #pragma unroll
    for (int off = 1; off < 64; off <<= 1) sum += __shfl_xor(sum, off);
    float inv = 1.f / sum;
    float* so = out + 4000 + b * 1000;
    #pragma unroll
    for (int j = 0; j < 16; ++j) {
        int i = lane + j * 64;
        if (i < 1000) so[i] = v[j] * inv;
    }
}

// ---------------------------------------------------------------------------
extern "C" void kernel_launch(void* const* d_in, const int* in_sizes, int n_in,
                              void* d_out, int out_size, void* d_ws, size_t ws_size,
                              hipStream_t stream)
{
    const float* x    = (const float*)d_in[0];
    const float* c1w  = (const float*)d_in[1];
    const float* c1b  = (const float*)d_in[2];
    const float* g1   = (const float*)d_in[3];
    const float* b1   = (const float*)d_in[4];
    const float* c2w  = (const float*)d_in[5];
    const float* c2b  = (const float*)d_in[6];
    const float* g2   = (const float*)d_in[7];
    const float* b2   = (const float*)d_in[8];
    const float* pw   = (const float*)d_in[9];
    const float* pb   = (const float*)d_in[10];
    const float* g3   = (const float*)d_in[11];
    const float* b3   = (const float*)d_in[12];
    const float* ipw  = (const float*)d_in[13];
    const float* ipb  = (const float*)d_in[14];
    const float* cw   = (const float*)d_in[15];
    const float* cb   = (const float*)d_in[16];
    const float* xpw  = (const float*)d_in[17];
    const float* dpw  = (const float*)d_in[18];
    const float* dpb  = (const float*)d_in[19];
    const float* alog = (const float*)d_in[20];
    const float* dssm = (const float*)d_in[21];
    const float* opw  = (const float*)d_in[22];
    const float* opb  = (const float*)d_in[23];
    const float* lnw  = (const float*)d_in[24];
    const float* lnb  = (const float*)d_in[25];
    const float* nw   = (const float*)d_in[26];
    const float* nb   = (const float*)d_in[27];
    const float* fcw  = (const float*)d_in[28];
    const float* fcb  = (const float*)d_in[29];
    float* out = (float*)d_out;
    float* wsf = (float*)d_ws;

    float*  s_   = wsf;
    ushort* sb   = (ushort*)(wsf + 1048576);
    ushort* xib  = (ushort*)(wsf + 1572864);
    float*  obuf = wsf + 1572864;
    ushort* resb = (ushort*)(wsf + 3670016);
    ushort* xlb  = (ushort*)(wsf + 4718592);   // == u == ybb (in-place gate)
    ushort* ybb  = (ushort*)(wsf + 4718592);
    ushort* h1b  = (ushort*)(wsf + 4718592);
    ushort* Apb  = (ushort*)(wsf + 6815744);
    ushort* ipwb = (ushort*)(wsf + 9175040);
    ushort* opwb = (ushort*)(wsf + 9699328);
    ushort* w2b  = (ushort*)(wsf + 9961472);
    ushort* pwTb = (ushort*)(wsf + 10108928);
    float*  sln  = wsf + 10240000;
    float*  Psum = wsf + 10241024;             // [4][128][16][64] = 524288 fl
    float*  hFsum= wsf + 10765312;             // 524288 fl
    ushort* xpwb = (ushort*)(wsf + 11289600);  // 131072 ushorts; end 11355136 fl
    float*  pprt = wsf + 11355136;             // [4][32][256] = 32768 fl
    float*  xdp  = wsf + 11387904;             // [2][4096][64] = 524288 fl

    // --- fused weight prep (1 dispatch) ---
    hipLaunchKernelGGL(wprep, dim3(8832), dim3(256), 0, stream,
                       ipw, opw, c2w, pw, xpw, ipwb, opwb, w2b, pwTb, xpwb);

    // --- conv stem ---
    hipLaunchKernelGGL(conv1_nhwc, dim3(256), dim3(256), 0, stream, x, c1w, c1b, g1, b1, h1b);
    hipLaunchKernelGGL(conv2_mfma, dim3(128, 4), dim3(256), 0, stream, h1b, w2b, c2b, g2, b2, Apb);
    hipLaunchKernelGGL((mfma_gemm_bt<64, 64, 2>), dim3(64, 4), dim3(256), 0, stream,
                       Apb, 1024, pwTb, 1024, pb, g3, b3, s_, sb, nullptr, 256, 1024);

    // --- mamba blocks ---
    for (int i = 0; i < 4; ++i) {
        const ushort* ipwb_i = ipwb + (size_t)i * 1024 * 256;
        const float*  ipb_i  = ipb + i * 1024;
        const float*  cw_i   = cw + i * 512 * 4;
        const float*  cb_i   = cb + i * 512;
        const ushort* xpwb_i = xpwb + (size_t)i * 64 * 512;
        const float*  dpw_i  = dpw + (size_t)i * 512 * 32;
        const float*  dpb_i  = dpb + i * 512;
        const float*  alog_i = alog + (size_t)i * 512 * 16;
        const float*  dssm_i = dssm + i * 512;
        const ushort* opwb_i = opwb + (size_t)i * 256 * 512;
        const float*  opb_i  = opb + i * 256;
        const float*  lnw_i  = lnw + i * 256;
        const float*  lnb_i  = lnb + i * 256;

        hipLaunchKernelGGL((mfma_gemm_bt<64, 128, 3>), dim3(64, 8), dim3(256), 0, stream,
                           sb, 256, ipwb_i, 256, ipb_i, nullptr, nullptr,
                           nullptr, xib, resb, 0, 256);
        hipLaunchKernelGGL(dwconv, dim3(2048), dim3(256), 0, stream, xib, cw_i, cb_i, xlb);
        hipLaunchKernelGGL(xproj_gemm_sk, dim3(64, 2), dim3(256), 0, stream,
                           xlb, xpwb_i, xdp);
        hipLaunchKernelGGL(scan_part1, dim3(960), dim3(512), 0, stream,
                           xdp, xlb, dpw_i, dpb_i, alog_i, Psum, hFsum);
        hipLaunchKernelGGL(scan_part2, dim3(1024), dim3(512), 0, stream,
                           xdp, xlb, dpw_i, dpb_i, alog_i, dssm_i, resb, ybb, Psum, hFsum);
        hipLaunchKernelGGL((mfma_gemm_bt<64, 64, 0>), dim3(64, 4), dim3(256), 0, stream,
                           ybb, 512, opwb_i, 512, opb_i, nullptr, nullptr,
                           obuf, nullptr, nullptr, 256, 512);
        hipLaunchKernelGGL(ln_res_kernel, dim3(1024), dim3(256), 0, stream,
                           obuf, lnw_i, lnb_i, s_, sb);
    }

    // --- head ---
    hipLaunchKernelGGL(pool_partial, dim3(128), dim3(256), 0, stream, s_, pprt);
    hipLaunchKernelGGL(pool_ln_final, dim3(4), dim3(256), 0, stream, pprt, nw, nb, sln);
    hipLaunchKernelGGL((gemm_kernel<64, 64, 16, 4, 4>), dim3(1, 16), dim3(256), 0, stream,
                       sln, 256, fcw, 256, fcb, out, 1000, 4, 1000, 256, 0);
    hipLaunchKernelGGL(softmax_kernel, dim3(1), dim3(256), 0, stream, out);
}